// Round 1
// baseline (10278.465 us; speedup 1.0000x reference)
//
#include <hip/hip_runtime.h>
#include <math.h>

#define BB 32
#define NNODE 1024
#define BN 32768
#define NE 262144
#define DD 128
#define NT 8
#define NSTEPS 6
#define SORT_CAP (NE + 1024)   // bins padded to 128-edge tiles: <= E + 8*127
#define NTILES 2056            // sum ceil(hist_t/128) <= E/128 + 8

static __device__ __forceinline__ float4 ld4(const float* p) { return *(const float4*)p; }

// ---------------- workspace layout (bytes) ----------------
static constexpr size_t OFF_HCUR = 0;                               // BN*DD f32
static constexpr size_t OFF_A    = OFF_HCUR + (size_t)BN * DD * 4;  // BN*DD f32
static constexpr size_t OFF_BVEC = OFF_A    + (size_t)BN * DD * 4;  // BN*DD f32
static constexpr size_t OFF_CNT  = OFF_BVEC + (size_t)BN * DD * 4;  // BN*NT i32
static constexpr size_t OFF_HB   = OFF_CNT  + (size_t)BN * NT * 4;  // 256 B: hist[0..7], aoff[8..16], cur[20..27]
static constexpr size_t OFF_SSRC = OFF_HB   + 256;                  // SORT_CAP i32
static constexpr size_t OFF_SDST = OFF_SSRC + (size_t)SORT_CAP * 4; // SORT_CAP i32
static constexpr size_t OFF_P1Y  = OFF_SDST + (size_t)SORT_CAP * 4; // 32*128*512 f32 (row pad 510->512)
static constexpr size_t OFF_P1Z  = OFF_P1Y  + (size_t)32 * 128 * 512 * 4; // 32*256*512 f32
static constexpr size_t OFF_QY   = OFF_P1Z  + (size_t)32 * 256 * 512 * 4; // 32*255*128 f32
static constexpr size_t OFF_QZ   = OFF_QY   + (size_t)32 * 255 * 128 * 4; // 32*255*256 f32
static constexpr size_t WS_NEED  = OFF_QZ   + (size_t)32 * 255 * 256 * 4; // ~87 MiB

// ---------------- graph preprocessing ----------------

__global__ void k_hist(const int* __restrict__ et, const int* __restrict__ dst,
                       int* __restrict__ hb, int* __restrict__ cnt)
{
    __shared__ int lh[NT];
    int tid = threadIdx.x;
    if (tid < NT) lh[tid] = 0;
    __syncthreads();
    int base = blockIdx.x * 1024;
    for (int k = 0; k < 4; ++k) {
        int e = base + tid + k * 256;
        int t = et[e];
        atomicAdd(&lh[t], 1);
        atomicAdd(&cnt[dst[e] * NT + t], 1);
    }
    __syncthreads();
    if (tid < NT) atomicAdd(&hb[tid], lh[tid]);
}

__global__ void k_scan(int* hb)
{
    int s = 0;
    for (int t = 0; t < NT; ++t) {
        hb[8 + t] = s;      // aoff
        hb[20 + t] = s;     // cur
        s += ((hb[t] + 127) >> 7) << 7;
    }
    hb[16] = s;             // aoff[8] = padded total
}

__global__ void k_scatter(const int* __restrict__ src, const int* __restrict__ dst,
                          const int* __restrict__ et, int* __restrict__ hb,
                          int* __restrict__ ssrc, int* __restrict__ sdst)
{
    __shared__ int lc[NT], lbase[NT];
    int tid = threadIdx.x;
    if (tid < NT) lc[tid] = 0;
    __syncthreads();
    int base = blockIdx.x * 1024;
    int myt[4], myr[4];
    for (int k = 0; k < 4; ++k) {
        int e = base + tid * 4 + k;
        int t = et[e];
        myt[k] = t;
        myr[k] = atomicAdd(&lc[t], 1);
    }
    __syncthreads();
    if (tid < NT) lbase[tid] = atomicAdd(&hb[20 + tid], lc[tid]);
    __syncthreads();
    for (int k = 0; k < 4; ++k) {
        int e = base + tid * 4 + k;
        int p = lbase[myt[k]] + myr[k];
        ssrc[p] = src[e];
        sdst[p] = dst[e];
    }
}

// bvec[v][o] = sum_t cnt[v][t] * b_msg[t][o]
__global__ void k_bvec(const int* __restrict__ cnt, const float* __restrict__ bmsg,
                       float* __restrict__ bvec)
{
    int q = blockIdx.x * 256 + threadIdx.x;   // BN*32 threads
    int v = q >> 5, o0 = (q & 31) * 4;
    const int* cv = cnt + v * NT;
    float4 acc = make_float4(0.f, 0.f, 0.f, 0.f);
    for (int t = 0; t < NT; ++t) {
        float c = (float)cv[t];
        float4 b = ld4(bmsg + t * DD + o0);
        acc.x += c * b.x; acc.y += c * b.y; acc.z += c * b.z; acc.w += c * b.w;
    }
    *(float4*)(bvec + (size_t)v * DD + o0) = acc;
}

// ---------------- message pass: tile of 128 same-etype edges ----------------
// a[dst[e]][o] += sum_d h[src[e]][d] * W_msg[t][o][d]

__launch_bounds__(256, 1)
__global__ void k_msg(const int* __restrict__ ssrc, const int* __restrict__ sdst,
                      const int* __restrict__ hb, const float* __restrict__ h,
                      const float* __restrict__ Wmsg, float* __restrict__ a)
{
    __shared__ float As[128][132];
    __shared__ float Ws[128][132];
    __shared__ int sdl[128];
    __shared__ int ssl[128];
    int base = blockIdx.x * 128;
    if (base >= hb[16]) return;                 // uniform
    int t = 0;
#pragma unroll
    for (int i = 1; i < NT; ++i) if (base >= hb[8 + i]) t = i;
    int tid = threadIdx.x;
    if (tid < 128) { sdl[tid] = sdst[base + tid]; ssl[tid] = ssrc[base + tid]; }
    __syncthreads();
    const float* Wt = Wmsg + (size_t)t * (DD * DD);
#pragma unroll
    for (int k = 0; k < 16; ++k) {
        int q = tid + k * 256;
        int r = q >> 5, c = (q & 31) << 2;
        int s = ssl[r];                          // pad rows have s=0 (safe), dst=-1
        *(float4*)&As[r][c] = ld4(h + (size_t)s * DD + c);
        *(float4*)&Ws[r][c] = ld4(Wt + r * DD + c);
    }
    __syncthreads();
    int eg = tid >> 4, og = tid & 15;
    float acc[8][8];
#pragma unroll
    for (int j = 0; j < 8; ++j)
#pragma unroll
        for (int i = 0; i < 8; ++i) acc[j][i] = 0.f;
    for (int d0 = 0; d0 < DD; d0 += 4) {
        float4 av[8];
#pragma unroll
        for (int j = 0; j < 8; ++j) av[j] = *(const float4*)&As[eg + 16 * j][d0];
#pragma unroll
        for (int i = 0; i < 8; ++i) {
            float4 wv = *(const float4*)&Ws[og + 16 * i][d0];
#pragma unroll
            for (int j = 0; j < 8; ++j) {
                acc[j][i] += av[j].x * wv.x;
                acc[j][i] += av[j].y * wv.y;
                acc[j][i] += av[j].z * wv.z;
                acc[j][i] += av[j].w * wv.w;
            }
        }
    }
#pragma unroll
    for (int j = 0; j < 8; ++j) {
        int dv = sdl[eg + 16 * j];
        if (dv >= 0) {
            float* ap = a + (size_t)dv * DD;
#pragma unroll
            for (int i = 0; i < 8; ++i) atomicAdd(&ap[og + 16 * i], acc[j][i]);
        }
    }
}

// ---------------- fused GRU cell: h = GRU(a, h), in-place on 16-node tiles ----------------

__launch_bounds__(256)
__global__ void k_gru(float* __restrict__ h, const float* __restrict__ a,
                      const float* __restrict__ wih, const float* __restrict__ whh,
                      const float* __restrict__ bih, const float* __restrict__ bhh)
{
    __shared__ float as[16][132];
    __shared__ float hs[16][132];
    int tid = threadIdx.x;
    int v0 = blockIdx.x * 16;
#pragma unroll
    for (int k = 0; k < 2; ++k) {
        int q = tid + k * 256;
        int r = q >> 5, c = (q & 31) << 2;
        *(float4*)&as[r][c] = ld4(a + (size_t)(v0 + r) * DD + c);
        *(float4*)&hs[r][c] = ld4(h + (size_t)(v0 + r) * DD + c);
    }
    __syncthreads();
    int n = tid >> 4, og = tid & 15;
    float rg[8], zg[8];
#pragma unroll
    for (int p = 0; p < 3; ++p) {
        float ai[8], ah[8];
#pragma unroll
        for (int i = 0; i < 8; ++i) { ai[i] = 0.f; ah[i] = 0.f; }
        for (int d0 = 0; d0 < DD; d0 += 4) {
            float4 av = *(const float4*)&as[n][d0];
            float4 hv = *(const float4*)&hs[n][d0];
#pragma unroll
            for (int i = 0; i < 8; ++i) {
                int o = og + 16 * i;
                float4 wi = ld4(wih + ((size_t)(p * DD + o)) * DD + d0);
                float4 wh = ld4(whh + ((size_t)(p * DD + o)) * DD + d0);
                ai[i] += av.x * wi.x + av.y * wi.y + av.z * wi.z + av.w * wi.w;
                ah[i] += hv.x * wh.x + hv.y * wh.y + hv.z * wh.z + hv.w * wh.w;
            }
        }
#pragma unroll
        for (int i = 0; i < 8; ++i) {
            int o = og + 16 * i;
            float gi = ai[i] + bih[p * DD + o];
            float gh = ah[i] + bhh[p * DD + o];
            if (p == 0)      rg[i] = 1.f / (1.f + expf(-(gi + gh)));
            else if (p == 1) zg[i] = 1.f / (1.f + expf(-(gi + gh)));
            else {
                float nn = tanhf(gi + rg[i] * gh);
                float hold = hs[n][o];
                h[(size_t)(v0 + n) * DD + o] = (1.f - zg[i]) * nn + zg[i] * hold;
            }
        }
    }
}

// ---------------- conv1(k=3)+relu+maxpool(3,2), fused; COUT==CIN ----------------
// P[b][co][j] = relu(max_{dl<3} (bias[co] + sum_{ci,kk} x[b][ci][2j+dl+kk]*w[co][ci][kk]))
// x channels: ci<128 from hf (h_final); ci>=128 from h0 (original input). P rows padded to 512.

template <int CIN>
__launch_bounds__(256)
__global__ void k_conv1(const float* __restrict__ hf, const float* __restrict__ h0,
                        const float* __restrict__ w, const float* __restrict__ bias,
                        float* __restrict__ P)
{
    __shared__ float xs[67][CIN + 1];
    int jt = blockIdx.x, b = blockIdx.y, zz = blockIdx.z;
    int tid = threadIdx.x;
    int j0 = jt * 32;
    int l0 = 2 * j0;
    const int nf4 = 67 * CIN / 4;
    for (int q = tid; q < nf4; q += 256) {
        int r = q / (CIN / 4);
        int c = (q % (CIN / 4)) * 4;
        int l = l0 + r; if (l > NNODE - 1) l = NNODE - 1;   // clamped rows only feed masked-out j
        const float* sp;
        if (CIN == 128 || c < 128) sp = hf + ((size_t)(b * NNODE + l)) * DD + c;
        else                       sp = h0 + ((size_t)(b * NNODE + l)) * DD + (c - 128);
        float4 v = ld4(sp);
        xs[r][c] = v.x; xs[r][c + 1] = v.y; xs[r][c + 2] = v.z; xs[r][c + 3] = v.w;
    }
    __syncthreads();
    int og = tid >> 5, jl = tid & 31;
    int j = j0 + jl;
    float acc[16][3];
#pragma unroll
    for (int cc = 0; cc < 16; ++cc) { acc[cc][0] = 0.f; acc[cc][1] = 0.f; acc[cc][2] = 0.f; }
    for (int ci = 0; ci < CIN; ++ci) {
        float x0 = xs[2 * jl + 0][ci], x1 = xs[2 * jl + 1][ci], x2 = xs[2 * jl + 2][ci],
              x3 = xs[2 * jl + 3][ci], x4 = xs[2 * jl + 4][ci];
#pragma unroll
        for (int cc = 0; cc < 16; ++cc) {
            int co = zz * 128 + og + 8 * cc;
            const float* wp = w + ((size_t)co * CIN + ci) * 3;
            float w0 = wp[0], w1 = wp[1], w2 = wp[2];
            acc[cc][0] += x0 * w0 + x1 * w1 + x2 * w2;
            acc[cc][1] += x1 * w0 + x2 * w1 + x3 * w2;
            acc[cc][2] += x2 * w0 + x3 * w1 + x4 * w2;
        }
    }
    if (j < 510) {
#pragma unroll
        for (int cc = 0; cc < 16; ++cc) {
            int co = zz * 128 + og + 8 * cc;
            float m = fmaxf(acc[cc][0], fmaxf(acc[cc][1], acc[cc][2]));
            P[((size_t)(b * CIN + co)) * 512 + j] = fmaxf(0.f, m + bias[co]);
        }
    }
}

// ---------------- conv2(k=1)+relu+maxpool(2,2), fused; COUT==CIN ----------------
// Q[b][j][co] = relu(max_{dl<2}(bias[co] + sum_ci P[b][ci][2j+dl]*w[co][ci]))

template <int CIN>
__launch_bounds__(256)
__global__ void k_conv2(const float* __restrict__ P, const float* __restrict__ w,
                        const float* __restrict__ bias, float* __restrict__ Q)
{
    __shared__ float xs[CIN][69];
    int jt = blockIdx.x, b = blockIdx.y, zz = blockIdx.z;
    int tid = threadIdx.x;
    int j0 = jt * 32;
    int l0 = 2 * j0;
    const int nf4 = CIN * 17;   // 68 l's per ci
    for (int q = tid; q < nf4; q += 256) {
        int ci = q / 17;
        int c = (q % 17) * 4;
        const float* rowp = P + ((size_t)(b * CIN + ci)) * 512;
        float4 v;
        if (l0 + c + 3 <= 509) v = ld4(rowp + l0 + c);
        else {
            float tmp[4];
            for (int u = 0; u < 4; ++u) { int lu = l0 + c + u; if (lu > 509) lu = 509; tmp[u] = rowp[lu]; }
            v = make_float4(tmp[0], tmp[1], tmp[2], tmp[3]);
        }
        xs[ci][c] = v.x; xs[ci][c + 1] = v.y; xs[ci][c + 2] = v.z; xs[ci][c + 3] = v.w;
    }
    __syncthreads();
    int og = tid >> 5, jl = tid & 31;
    int j = j0 + jl;
    float a0[16], a1[16];
#pragma unroll
    for (int cc = 0; cc < 16; ++cc) { a0[cc] = 0.f; a1[cc] = 0.f; }
    for (int ci = 0; ci < CIN; ++ci) {
        float x0 = xs[ci][2 * jl + 0], x1 = xs[ci][2 * jl + 1];
#pragma unroll
        for (int cc = 0; cc < 16; ++cc) {
            int co = zz * 128 + og + 8 * cc;
            float wv = w[(size_t)co * CIN + ci];
            a0[cc] += x0 * wv; a1[cc] += x1 * wv;
        }
    }
    if (j < 255) {
#pragma unroll
        for (int cc = 0; cc < 16; ++cc) {
            int co = zz * 128 + og + 8 * cc;
            Q[((size_t)(b * 255 + j)) * CIN + co] = fmaxf(0.f, fmaxf(a0[cc], a1[cc]) + bias[co]);
        }
    }
}

// ---------------- final: (QY.wy+by)*(QZ.wz+bz), mean over 255, sigmoid ----------------

__launch_bounds__(256)
__global__ void k_final(const float* __restrict__ QY, const float* __restrict__ QZ,
                        const float* __restrict__ wy, const float* __restrict__ by,
                        const float* __restrict__ wz, const float* __restrict__ bz,
                        float* __restrict__ out)
{
    int b = blockIdx.x, tid = threadIdx.x;
    float p = 0.f;
    if (tid < 255) {
        const float* qy = QY + ((size_t)(b * 255 + tid)) * 128;
        const float* qz = QZ + ((size_t)(b * 255 + tid)) * 256;
        float dy = 0.f, dz = 0.f;
        for (int c = 0; c < 128; c += 4) {
            float4 q = ld4(qy + c), wv = ld4(wy + c);
            dy += q.x * wv.x + q.y * wv.y + q.z * wv.z + q.w * wv.w;
        }
        for (int c = 0; c < 256; c += 4) {
            float4 q = ld4(qz + c), wv = ld4(wz + c);
            dz += q.x * wv.x + q.y * wv.y + q.z * wv.z + q.w * wv.w;
        }
        p = (dy + by[0]) * (dz + bz[0]);
    }
    __shared__ float red[4];
    for (int off = 32; off > 0; off >>= 1) p += __shfl_down(p, off);
    if ((tid & 63) == 0) red[tid >> 6] = p;
    __syncthreads();
    if (tid == 0) {
        float s = red[0] + red[1] + red[2] + red[3];
        out[b] = 1.f / (1.f + expf(-s / 255.f));
    }
}

// ---------------- launch ----------------

extern "C" void kernel_launch(void* const* d_in, const int* in_sizes, int n_in,
                              void* d_out, int out_size, void* d_ws, size_t ws_size,
                              hipStream_t stream)
{
    const float* h_in = (const float*)d_in[0];
    const int* src = (const int*)d_in[1];
    const int* dst = (const int*)d_in[2];
    const int* et  = (const int*)d_in[3];
    const float* Wmsg = (const float*)d_in[4];
    const float* bmsg = (const float*)d_in[5];
    const float* wih = (const float*)d_in[6];
    const float* whh = (const float*)d_in[7];
    const float* bih = (const float*)d_in[8];
    const float* bhh = (const float*)d_in[9];
    const float* c1w = (const float*)d_in[10];
    const float* c1b = (const float*)d_in[11];
    const float* c2w = (const float*)d_in[12];
    const float* c2b = (const float*)d_in[13];
    const float* z1w = (const float*)d_in[14];
    const float* z1b = (const float*)d_in[15];
    const float* z2w = (const float*)d_in[16];
    const float* z2b = (const float*)d_in[17];
    const float* wy  = (const float*)d_in[18];
    const float* by  = (const float*)d_in[19];
    const float* wz  = (const float*)d_in[20];
    const float* bz  = (const float*)d_in[21];
    float* out = (float*)d_out;

    if (ws_size < WS_NEED) return;   // loud failure: output stays poisoned

    char* ws = (char*)d_ws;
    float* hcur = (float*)(ws + OFF_HCUR);
    float* a    = (float*)(ws + OFF_A);
    float* bvec = (float*)(ws + OFF_BVEC);
    int*   cnt  = (int*)(ws + OFF_CNT);
    int*   hb   = (int*)(ws + OFF_HB);
    int*   ssrc = (int*)(ws + OFF_SSRC);
    int*   sdst = (int*)(ws + OFF_SDST);
    float* P1Y  = (float*)(ws + OFF_P1Y);
    float* P1Z  = (float*)(ws + OFF_P1Z);
    float* QY   = (float*)(ws + OFF_QY);
    float* QZ   = (float*)(ws + OFF_QZ);

    hipMemcpyAsync(hcur, h_in, (size_t)BN * DD * 4, hipMemcpyDeviceToDevice, stream);
    hipMemsetAsync(cnt, 0, (size_t)BN * NT * 4, stream);
    hipMemsetAsync(hb, 0, 256, stream);
    hipMemsetAsync(ssrc, 0, (size_t)SORT_CAP * 4, stream);
    hipMemsetAsync(sdst, 0xFF, (size_t)SORT_CAP * 4, stream);

    k_hist<<<256, 256, 0, stream>>>(et, dst, hb, cnt);
    k_scan<<<1, 1, 0, stream>>>(hb);
    k_scatter<<<256, 256, 0, stream>>>(src, dst, et, hb, ssrc, sdst);
    k_bvec<<<4096, 256, 0, stream>>>(cnt, bmsg, bvec);

    for (int s = 0; s < NSTEPS; ++s) {
        hipMemcpyAsync(a, bvec, (size_t)BN * DD * 4, hipMemcpyDeviceToDevice, stream);
        k_msg<<<NTILES, 256, 0, stream>>>(ssrc, sdst, hb, hcur, Wmsg, a);
        k_gru<<<2048, 256, 0, stream>>>(hcur, a, wih, whh, bih, bhh);
    }

    k_conv1<128><<<dim3(16, 32, 1), 256, 0, stream>>>(hcur, h_in, c1w, c1b, P1Y);
    k_conv2<128><<<dim3(8, 32, 1), 256, 0, stream>>>(P1Y, c2w, c2b, QY);
    k_conv1<256><<<dim3(16, 32, 2), 256, 0, stream>>>(hcur, h_in, z1w, z1b, P1Z);
    k_conv2<256><<<dim3(8, 32, 2), 256, 0, stream>>>(P1Z, z2w, z2b, QZ);
    k_final<<<32, 256, 0, stream>>>(QY, QZ, wy, by, wz, bz, out);
}

// Round 2
// 3075.975 us; speedup vs baseline: 3.3415x; 3.3415x over previous
//
#include <hip/hip_runtime.h>
#include <math.h>

#define BB 32
#define NNODE 1024
#define BN 32768
#define NE 262144
#define DD 128
#define NT 8
#define NSTEPS 6
#define SORT_CAP (NE + 1024)   // bins padded to 128-edge tiles
#define NTILES 2056            // sum ceil(hist_t/128) <= E/128 + 8

static __device__ __forceinline__ float4 ld4(const float* p) { return *(const float4*)p; }
static __device__ __forceinline__ float sigmoidf(float x) { return 1.f / (1.f + expf(-x)); }

// ---------------- workspace layout (bytes) ----------------
static constexpr size_t OFF_HCUR = 0;                                // BN*DD f32
static constexpr size_t OFF_A    = OFF_HCUR + (size_t)BN * DD * 4;   // BN*DD f32
static constexpr size_t OFF_CNT  = OFF_A    + (size_t)BN * DD * 4;   // BN*NT i32
static constexpr size_t OFF_HB   = OFF_CNT  + (size_t)BN * NT * 4;   // 256 B
static constexpr size_t OFF_SSRC = OFF_HB   + 256;                   // SORT_CAP i32
static constexpr size_t OFF_SDST = OFF_SSRC + (size_t)SORT_CAP * 4;  // SORT_CAP i32
static constexpr size_t OFF_SH   = OFF_SDST + (size_t)SORT_CAP * 4;  // shared region
// during GRU loop: rz[BN][256] f32 (33.5 MB)
static constexpr size_t OFF_RZ   = OFF_SH;
// after loop: conv scratch
static constexpr size_t OFF_P1Y  = OFF_SH;                            // 32*128*512 f32
static constexpr size_t OFF_P1Z  = OFF_P1Y + (size_t)32 * 128 * 512 * 4; // 32*256*512 f32
static constexpr size_t OFF_QY   = OFF_P1Z + (size_t)32 * 256 * 512 * 4; // 32*255*128 f32
static constexpr size_t OFF_QZ   = OFF_QY  + (size_t)32 * 255 * 128 * 4; // 32*255*256 f32
static constexpr size_t WS_NEED  = OFF_QZ  + (size_t)32 * 255 * 256 * 4; // ~71 MiB

// ---------------- graph preprocessing ----------------

__global__ void k_hist(const int* __restrict__ et, const int* __restrict__ dst,
                       int* __restrict__ hb, int* __restrict__ cnt)
{
    __shared__ int lh[NT];
    int tid = threadIdx.x;
    if (tid < NT) lh[tid] = 0;
    __syncthreads();
    int base = blockIdx.x * 1024;
    for (int k = 0; k < 4; ++k) {
        int e = base + tid + k * 256;
        int t = et[e];
        atomicAdd(&lh[t], 1);
        atomicAdd(&cnt[dst[e] * NT + t], 1);
    }
    __syncthreads();
    if (tid < NT) atomicAdd(&hb[tid], lh[tid]);
}

__global__ void k_scan(int* hb)
{
    int s = 0;
    for (int t = 0; t < NT; ++t) {
        hb[8 + t] = s;      // aoff
        hb[20 + t] = s;     // cur
        s += ((hb[t] + 127) >> 7) << 7;
    }
    hb[16] = s;             // padded total
}

__global__ void k_scatter(const int* __restrict__ src, const int* __restrict__ dst,
                          const int* __restrict__ et, int* __restrict__ hb,
                          int* __restrict__ ssrc, int* __restrict__ sdst)
{
    __shared__ int lc[NT], lbase[NT];
    int tid = threadIdx.x;
    if (tid < NT) lc[tid] = 0;
    __syncthreads();
    int base = blockIdx.x * 1024;
    int myt[4], myr[4];
    for (int k = 0; k < 4; ++k) {
        int e = base + tid * 4 + k;
        int t = et[e];
        myt[k] = t;
        myr[k] = atomicAdd(&lc[t], 1);
    }
    __syncthreads();
    if (tid < NT) lbase[tid] = atomicAdd(&hb[20 + tid], lc[tid]);
    __syncthreads();
    for (int k = 0; k < 4; ++k) {
        int e = base + tid * 4 + k;
        int p = lbase[myt[k]] + myr[k];
        ssrc[p] = src[e];
        sdst[p] = dst[e];
    }
}

// seed a[v][o] = sum_t cnt[v][t] * b_msg[t][o]   (replaces d2d copy of bvec)
__global__ void k_bvec(const int* __restrict__ cnt, const float* __restrict__ bmsg,
                       float* __restrict__ a)
{
    int q = blockIdx.x * 256 + threadIdx.x;   // BN*32 threads
    int v = q >> 5, o0 = (q & 31) * 4;
    const int* cv = cnt + v * NT;
    float4 acc = make_float4(0.f, 0.f, 0.f, 0.f);
    for (int t = 0; t < NT; ++t) {
        float c = (float)cv[t];
        float4 b = ld4(bmsg + t * DD + o0);
        acc.x += c * b.x; acc.y += c * b.y; acc.z += c * b.z; acc.w += c * b.w;
    }
    *(float4*)(a + (size_t)v * DD + o0) = acc;
}

// ---------------- message pass: tile of 128 same-etype edges ----------------
// a[dst[e]][o] += sum_d h[src[e]][d] * W_msg[t][o][d]
// K-chunked (64-wide) staging: 70 KB LDS -> 2 blocks/CU

__launch_bounds__(256, 2)
__global__ void k_msg(const int* __restrict__ ssrc, const int* __restrict__ sdst,
                      const int* __restrict__ hb, const float* __restrict__ h,
                      const float* __restrict__ Wmsg, float* __restrict__ a)
{
    __shared__ float As[128][68];
    __shared__ float Ws[128][68];
    __shared__ int sdl[128];
    __shared__ int ssl[128];
    int base = blockIdx.x * 128;
    if (base >= hb[16]) return;                 // uniform
    int t = 0;
#pragma unroll
    for (int i = 1; i < NT; ++i) if (base >= hb[8 + i]) t = i;
    int tid = threadIdx.x;
    if (tid < 128) { sdl[tid] = sdst[base + tid]; ssl[tid] = ssrc[base + tid]; }
    __syncthreads();
    const float* Wt = Wmsg + (size_t)t * (DD * DD);
    int eg = tid >> 4, og = tid & 15;
    float acc[8][8];
#pragma unroll
    for (int j = 0; j < 8; ++j)
#pragma unroll
        for (int i = 0; i < 8; ++i) acc[j][i] = 0.f;
    for (int d0 = 0; d0 < DD; d0 += 64) {
        if (d0) __syncthreads();
#pragma unroll
        for (int k = 0; k < 8; ++k) {
            int q = tid + k * 256;
            int r = q >> 4, c = (q & 15) << 2;
            int s = ssl[r];                      // pad rows: s=0 (safe), dst=-1
            *(float4*)&As[r][c] = ld4(h + (size_t)s * DD + d0 + c);
            *(float4*)&Ws[r][c] = ld4(Wt + (size_t)r * DD + d0 + c);
        }
        __syncthreads();
#pragma unroll
        for (int dd = 0; dd < 64; dd += 4) {
            float4 av[8];
#pragma unroll
            for (int j = 0; j < 8; ++j) av[j] = *(const float4*)&As[eg + 16 * j][dd];
#pragma unroll
            for (int i = 0; i < 8; ++i) {
                float4 wv = *(const float4*)&Ws[og + 16 * i][dd];
#pragma unroll
                for (int j = 0; j < 8; ++j) {
                    acc[j][i] += av[j].x * wv.x;
                    acc[j][i] += av[j].y * wv.y;
                    acc[j][i] += av[j].z * wv.z;
                    acc[j][i] += av[j].w * wv.w;
                }
            }
        }
    }
#pragma unroll
    for (int j = 0; j < 8; ++j) {
        int dv = sdl[eg + 16 * j];
        if (dv >= 0) {
            float* ap = a + (size_t)dv * DD;
#pragma unroll
            for (int i = 0; i < 8; ++i) atomicAdd(&ap[og + 16 * i], acc[j][i]);
        }
    }
}

// ---------------- GRU r,z gates: rz = sigma([a|h]·[wih_rz|whh_rz]^T + bih+bhh) ----------------
// M-tile 64 nodes, N-tile 128 (blockIdx.y in {0,1} selects r or z rows), K=256 in 4 chunks.

__launch_bounds__(256, 3)
__global__ void k_grurz(const float* __restrict__ a, const float* __restrict__ h,
                        const float* __restrict__ wih, const float* __restrict__ whh,
                        const float* __restrict__ bih, const float* __restrict__ bhh,
                        float* __restrict__ rz)
{
    __shared__ float As[64][68];
    __shared__ float Bs[128][68];
    int m0 = blockIdx.x * 64, n0 = blockIdx.y * 128;
    int tid = threadIdx.x;
    int eg = tid >> 4, og = tid & 15;
    float acc[4][8];
#pragma unroll
    for (int j = 0; j < 4; ++j)
#pragma unroll
        for (int i = 0; i < 8; ++i) acc[j][i] = 0.f;
    for (int pass = 0; pass < 2; ++pass) {
        const float* X = pass ? h : a;
        const float* W = (pass ? whh : wih) + (size_t)n0 * DD;
        for (int d0 = 0; d0 < DD; d0 += 64) {
            if (pass || d0) __syncthreads();
#pragma unroll
            for (int k = 0; k < 4; ++k) {       // As: 64x64 = 1024 f4
                int q = tid + k * 256;
                int r = q >> 4, c = (q & 15) << 2;
                *(float4*)&As[r][c] = ld4(X + (size_t)(m0 + r) * DD + d0 + c);
            }
#pragma unroll
            for (int k = 0; k < 8; ++k) {       // Bs: 128x64 = 2048 f4
                int q = tid + k * 256;
                int r = q >> 4, c = (q & 15) << 2;
                *(float4*)&Bs[r][c] = ld4(W + (size_t)r * DD + d0 + c);
            }
            __syncthreads();
#pragma unroll
            for (int dd = 0; dd < 64; dd += 4) {
                float4 av[4];
#pragma unroll
                for (int j = 0; j < 4; ++j) av[j] = *(const float4*)&As[eg + 16 * j][dd];
#pragma unroll
                for (int i = 0; i < 8; ++i) {
                    float4 wv = *(const float4*)&Bs[og + 16 * i][dd];
#pragma unroll
                    for (int j = 0; j < 4; ++j) {
                        acc[j][i] += av[j].x * wv.x;
                        acc[j][i] += av[j].y * wv.y;
                        acc[j][i] += av[j].z * wv.z;
                        acc[j][i] += av[j].w * wv.w;
                    }
                }
            }
        }
    }
#pragma unroll
    for (int j = 0; j < 4; ++j) {
        int v = m0 + eg + 16 * j;
#pragma unroll
        for (int i = 0; i < 8; ++i) {
            int cl = og + 16 * i;
            float pre = acc[j][i] + bih[n0 + cl] + bhh[n0 + cl];
            rz[(size_t)v * 256 + n0 + cl] = sigmoidf(pre);
        }
    }
}

// ---------------- GRU n gate + combine: h = (1-z)*tanh(i_n + r*h_n) + z*h ----------------
// Two chained K=128 GEMMs (a·wih_n^T, h·whh_n^T), fused epilogue writes hcur in place.

__launch_bounds__(256, 3)
__global__ void k_grun(const float* __restrict__ a, float* __restrict__ h,
                       const float* __restrict__ wih, const float* __restrict__ whh,
                       const float* __restrict__ bih, const float* __restrict__ bhh,
                       const float* __restrict__ rz)
{
    __shared__ float As[64][68];
    __shared__ float Bs[128][68];
    int m0 = blockIdx.x * 64;
    int tid = threadIdx.x;
    int eg = tid >> 4, og = tid & 15;
    float acci[4][8], acch[4][8];
#pragma unroll
    for (int j = 0; j < 4; ++j)
#pragma unroll
        for (int i = 0; i < 8; ++i) { acci[j][i] = 0.f; acch[j][i] = 0.f; }

    // pass 0: a x wih_n
    for (int d0 = 0; d0 < DD; d0 += 64) {
        if (d0) __syncthreads();
#pragma unroll
        for (int k = 0; k < 4; ++k) {
            int q = tid + k * 256;
            int r = q >> 4, c = (q & 15) << 2;
            *(float4*)&As[r][c] = ld4(a + (size_t)(m0 + r) * DD + d0 + c);
        }
#pragma unroll
        for (int k = 0; k < 8; ++k) {
            int q = tid + k * 256;
            int r = q >> 4, c = (q & 15) << 2;
            *(float4*)&Bs[r][c] = ld4(wih + (size_t)(256 + r) * DD + d0 + c);
        }
        __syncthreads();
#pragma unroll
        for (int dd = 0; dd < 64; dd += 4) {
            float4 av[4];
#pragma unroll
            for (int j = 0; j < 4; ++j) av[j] = *(const float4*)&As[eg + 16 * j][dd];
#pragma unroll
            for (int i = 0; i < 8; ++i) {
                float4 wv = *(const float4*)&Bs[og + 16 * i][dd];
#pragma unroll
                for (int j = 0; j < 4; ++j) {
                    acci[j][i] += av[j].x * wv.x;
                    acci[j][i] += av[j].y * wv.y;
                    acci[j][i] += av[j].z * wv.z;
                    acci[j][i] += av[j].w * wv.w;
                }
            }
        }
    }
    // pass 1: h x whh_n
    for (int d0 = 0; d0 < DD; d0 += 64) {
        __syncthreads();
#pragma unroll
        for (int k = 0; k < 4; ++k) {
            int q = tid + k * 256;
            int r = q >> 4, c = (q & 15) << 2;
            *(float4*)&As[r][c] = ld4(h + (size_t)(m0 + r) * DD + d0 + c);
        }
#pragma unroll
        for (int k = 0; k < 8; ++k) {
            int q = tid + k * 256;
            int r = q >> 4, c = (q & 15) << 2;
            *(float4*)&Bs[r][c] = ld4(whh + (size_t)(256 + r) * DD + d0 + c);
        }
        __syncthreads();
#pragma unroll
        for (int dd = 0; dd < 64; dd += 4) {
            float4 av[4];
#pragma unroll
            for (int j = 0; j < 4; ++j) av[j] = *(const float4*)&As[eg + 16 * j][dd];
#pragma unroll
            for (int i = 0; i < 8; ++i) {
                float4 wv = *(const float4*)&Bs[og + 16 * i][dd];
#pragma unroll
                for (int j = 0; j < 4; ++j) {
                    acch[j][i] += av[j].x * wv.x;
                    acch[j][i] += av[j].y * wv.y;
                    acch[j][i] += av[j].z * wv.z;
                    acch[j][i] += av[j].w * wv.w;
                }
            }
        }
    }
    // epilogue: r,z from rz; h_old from global (thread-owned slots only)
#pragma unroll
    for (int j = 0; j < 4; ++j) {
        int v = m0 + eg + 16 * j;
#pragma unroll
        for (int i = 0; i < 8; ++i) {
            int o = og + 16 * i;
            float r = rz[(size_t)v * 256 + o];
            float z = rz[(size_t)v * 256 + 128 + o];
            float nn = tanhf(acci[j][i] + bih[256 + o] + r * (acch[j][i] + bhh[256 + o]));
            float hold = h[(size_t)v * DD + o];
            h[(size_t)v * DD + o] = (1.f - z) * nn + z * hold;
        }
    }
}

// ---------------- conv1(k=3)+relu+maxpool(3,2), fused; COUT==CIN ----------------

template <int CIN>
__launch_bounds__(256)
__global__ void k_conv1(const float* __restrict__ hf, const float* __restrict__ h0,
                        const float* __restrict__ w, const float* __restrict__ bias,
                        float* __restrict__ P)
{
    __shared__ float xs[67][CIN + 1];
    int jt = blockIdx.x, b = blockIdx.y, zz = blockIdx.z;
    int tid = threadIdx.x;
    int j0 = jt * 32;
    int l0 = 2 * j0;
    const int nf4 = 67 * CIN / 4;
    for (int q = tid; q < nf4; q += 256) {
        int r = q / (CIN / 4);
        int c = (q % (CIN / 4)) * 4;
        int l = l0 + r; if (l > NNODE - 1) l = NNODE - 1;
        const float* sp;
        if (CIN == 128 || c < 128) sp = hf + ((size_t)(b * NNODE + l)) * DD + c;
        else                       sp = h0 + ((size_t)(b * NNODE + l)) * DD + (c - 128);
        float4 v = ld4(sp);
        xs[r][c] = v.x; xs[r][c + 1] = v.y; xs[r][c + 2] = v.z; xs[r][c + 3] = v.w;
    }
    __syncthreads();
    int og = tid >> 5, jl = tid & 31;
    int j = j0 + jl;
    float acc[16][3];
#pragma unroll
    for (int cc = 0; cc < 16; ++cc) { acc[cc][0] = 0.f; acc[cc][1] = 0.f; acc[cc][2] = 0.f; }
    for (int ci = 0; ci < CIN; ++ci) {
        float x0 = xs[2 * jl + 0][ci], x1 = xs[2 * jl + 1][ci], x2 = xs[2 * jl + 2][ci],
              x3 = xs[2 * jl + 3][ci], x4 = xs[2 * jl + 4][ci];
#pragma unroll
        for (int cc = 0; cc < 16; ++cc) {
            int co = zz * 128 + og + 8 * cc;
            const float* wp = w + ((size_t)co * CIN + ci) * 3;
            float w0 = wp[0], w1 = wp[1], w2 = wp[2];
            acc[cc][0] += x0 * w0 + x1 * w1 + x2 * w2;
            acc[cc][1] += x1 * w0 + x2 * w1 + x3 * w2;
            acc[cc][2] += x2 * w0 + x3 * w1 + x4 * w2;
        }
    }
    if (j < 510) {
#pragma unroll
        for (int cc = 0; cc < 16; ++cc) {
            int co = zz * 128 + og + 8 * cc;
            float m = fmaxf(acc[cc][0], fmaxf(acc[cc][1], acc[cc][2]));
            P[((size_t)(b * CIN + co)) * 512 + j] = fmaxf(0.f, m + bias[co]);
        }
    }
}

// ---------------- conv2(k=1)+relu+maxpool(2,2), fused; COUT==CIN ----------------

template <int CIN>
__launch_bounds__(256)
__global__ void k_conv2(const float* __restrict__ P, const float* __restrict__ w,
                        const float* __restrict__ bias, float* __restrict__ Q)
{
    __shared__ float xs[CIN][69];
    int jt = blockIdx.x, b = blockIdx.y, zz = blockIdx.z;
    int tid = threadIdx.x;
    int j0 = jt * 32;
    int l0 = 2 * j0;
    const int nf4 = CIN * 17;
    for (int q = tid; q < nf4; q += 256) {
        int ci = q / 17;
        int c = (q % 17) * 4;
        const float* rowp = P + ((size_t)(b * CIN + ci)) * 512;
        float4 v;
        if (l0 + c + 3 <= 509) v = ld4(rowp + l0 + c);
        else {
            float tmp[4];
            for (int u = 0; u < 4; ++u) { int lu = l0 + c + u; if (lu > 509) lu = 509; tmp[u] = rowp[lu]; }
            v = make_float4(tmp[0], tmp[1], tmp[2], tmp[3]);
        }
        xs[ci][c] = v.x; xs[ci][c + 1] = v.y; xs[ci][c + 2] = v.z; xs[ci][c + 3] = v.w;
    }
    __syncthreads();
    int og = tid >> 5, jl = tid & 31;
    int j = j0 + jl;
    float a0[16], a1[16];
#pragma unroll
    for (int cc = 0; cc < 16; ++cc) { a0[cc] = 0.f; a1[cc] = 0.f; }
    for (int ci = 0; ci < CIN; ++ci) {
        float x0 = xs[ci][2 * jl + 0], x1 = xs[ci][2 * jl + 1];
#pragma unroll
        for (int cc = 0; cc < 16; ++cc) {
            int co = zz * 128 + og + 8 * cc;
            float wv = w[(size_t)co * CIN + ci];
            a0[cc] += x0 * wv; a1[cc] += x1 * wv;
        }
    }
    if (j < 255) {
#pragma unroll
        for (int cc = 0; cc < 16; ++cc) {
            int co = zz * 128 + og + 8 * cc;
            Q[((size_t)(b * 255 + j)) * CIN + co] = fmaxf(0.f, fmaxf(a0[cc], a1[cc]) + bias[co]);
        }
    }
}

// ---------------- final reduction ----------------

__launch_bounds__(256)
__global__ void k_final(const float* __restrict__ QY, const float* __restrict__ QZ,
                        const float* __restrict__ wy, const float* __restrict__ by,
                        const float* __restrict__ wz, const float* __restrict__ bz,
                        float* __restrict__ out)
{
    int b = blockIdx.x, tid = threadIdx.x;
    float p = 0.f;
    if (tid < 255) {
        const float* qy = QY + ((size_t)(b * 255 + tid)) * 128;
        const float* qz = QZ + ((size_t)(b * 255 + tid)) * 256;
        float dy = 0.f, dz = 0.f;
        for (int c = 0; c < 128; c += 4) {
            float4 q = ld4(qy + c), wv = ld4(wy + c);
            dy += q.x * wv.x + q.y * wv.y + q.z * wv.z + q.w * wv.w;
        }
        for (int c = 0; c < 256; c += 4) {
            float4 q = ld4(qz + c), wv = ld4(wz + c);
            dz += q.x * wv.x + q.y * wv.y + q.z * wv.z + q.w * wv.w;
        }
        p = (dy + by[0]) * (dz + bz[0]);
    }
    __shared__ float red[4];
    for (int off = 32; off > 0; off >>= 1) p += __shfl_down(p, off);
    if ((tid & 63) == 0) red[tid >> 6] = p;
    __syncthreads();
    if (tid == 0) {
        float s = red[0] + red[1] + red[2] + red[3];
        out[b] = 1.f / (1.f + expf(-s / 255.f));
    }
}

// ---------------- launch ----------------

extern "C" void kernel_launch(void* const* d_in, const int* in_sizes, int n_in,
                              void* d_out, int out_size, void* d_ws, size_t ws_size,
                              hipStream_t stream)
{
    const float* h_in = (const float*)d_in[0];
    const int* src = (const int*)d_in[1];
    const int* dst = (const int*)d_in[2];
    const int* et  = (const int*)d_in[3];
    const float* Wmsg = (const float*)d_in[4];
    const float* bmsg = (const float*)d_in[5];
    const float* wih = (const float*)d_in[6];
    const float* whh = (const float*)d_in[7];
    const float* bih = (const float*)d_in[8];
    const float* bhh = (const float*)d_in[9];
    const float* c1w = (const float*)d_in[10];
    const float* c1b = (const float*)d_in[11];
    const float* c2w = (const float*)d_in[12];
    const float* c2b = (const float*)d_in[13];
    const float* z1w = (const float*)d_in[14];
    const float* z1b = (const float*)d_in[15];
    const float* z2w = (const float*)d_in[16];
    const float* z2b = (const float*)d_in[17];
    const float* wy  = (const float*)d_in[18];
    const float* by  = (const float*)d_in[19];
    const float* wz  = (const float*)d_in[20];
    const float* bz  = (const float*)d_in[21];
    float* out = (float*)d_out;

    if (ws_size < WS_NEED) return;   // loud failure: output stays poisoned

    char* ws = (char*)d_ws;
    float* hcur = (float*)(ws + OFF_HCUR);
    float* a    = (float*)(ws + OFF_A);
    int*   cnt  = (int*)(ws + OFF_CNT);
    int*   hb   = (int*)(ws + OFF_HB);
    int*   ssrc = (int*)(ws + OFF_SSRC);
    int*   sdst = (int*)(ws + OFF_SDST);
    float* rz   = (float*)(ws + OFF_RZ);
    float* P1Y  = (float*)(ws + OFF_P1Y);
    float* P1Z  = (float*)(ws + OFF_P1Z);
    float* QY   = (float*)(ws + OFF_QY);
    float* QZ   = (float*)(ws + OFF_QZ);

    hipMemcpyAsync(hcur, h_in, (size_t)BN * DD * 4, hipMemcpyDeviceToDevice, stream);
    hipMemsetAsync(cnt, 0, (size_t)BN * NT * 4, stream);
    hipMemsetAsync(hb, 0, 256, stream);
    hipMemsetAsync(ssrc, 0, (size_t)SORT_CAP * 4, stream);
    hipMemsetAsync(sdst, 0xFF, (size_t)SORT_CAP * 4, stream);

    k_hist<<<256, 256, 0, stream>>>(et, dst, hb, cnt);
    k_scan<<<1, 1, 0, stream>>>(hb);
    k_scatter<<<256, 256, 0, stream>>>(src, dst, et, hb, ssrc, sdst);

    for (int s = 0; s < NSTEPS; ++s) {
        k_bvec<<<4096, 256, 0, stream>>>(cnt, bmsg, a);        // seed a with bias counts
        k_msg<<<NTILES, 256, 0, stream>>>(ssrc, sdst, hb, hcur, Wmsg, a);
        k_grurz<<<dim3(512, 2), 256, 0, stream>>>(a, hcur, wih, whh, bih, bhh, rz);
        k_grun<<<512, 256, 0, stream>>>(a, hcur, wih, whh, bih, bhh, rz);
    }

    k_conv1<128><<<dim3(16, 32, 1), 256, 0, stream>>>(hcur, h_in, c1w, c1b, P1Y);
    k_conv2<128><<<dim3(8, 32, 1), 256, 0, stream>>>(P1Y, c2w, c2b, QY);
    k_conv1<256><<<dim3(16, 32, 2), 256, 0, stream>>>(hcur, h_in, z1w, z1b, P1Z);
    k_conv2<256><<<dim3(8, 32, 2), 256, 0, stream>>>(P1Z, z2w, z2b, QZ);
    k_final<<<32, 256, 0, stream>>>(QY, QZ, wy, by, wz, bz, out);
}

// Round 3
// 1679.565 us; speedup vs baseline: 6.1197x; 1.8314x over previous
//
#include <hip/hip_runtime.h>
#include <math.h>

#define BB 32
#define NNODE 1024
#define BN 32768
#define NE 262144
#define DD 128
#define NT 8
#define NSTEPS 6
#define SORT_CAP (NE + 1024)   // bins padded to 128-edge tiles
#define NTILES 2056            // sum ceil(hist_t/128) <= E/128 + 8

typedef __attribute__((ext_vector_type(8))) short bf16x8;
typedef __attribute__((ext_vector_type(4))) float f32x4;

static __device__ __forceinline__ float4 ld4(const float* p) { return *(const float4*)p; }
static __device__ __forceinline__ float sigmoidf_(float x) { return 1.f / (1.f + expf(-x)); }
// f32 -> bf16 round-to-nearest-even
static __device__ __forceinline__ unsigned f2b(float f) {
    unsigned u = __float_as_uint(f);
    return (u + 0x7FFFu + ((u >> 16) & 1u)) >> 16;
}
static __device__ __forceinline__ float b2f(unsigned short b) {
    return __uint_as_float(((unsigned)b) << 16);
}
static __device__ __forceinline__ unsigned pk(float a, float b) {
    return f2b(a) | (f2b(b) << 16);
}

// ---------------- workspace layout (bytes) ----------------
static constexpr size_t OFF_HCUR = 0;                                 // BN*DD f32
static constexpr size_t OFF_A    = OFF_HCUR + (size_t)BN * DD * 4;    // BN*DD f32
static constexpr size_t OFF_HBF  = OFF_A    + (size_t)BN * DD * 4;    // BN*DD bf16
static constexpr size_t OFF_CNT  = OFF_HBF  + (size_t)BN * DD * 2;    // BN*NT i32
static constexpr size_t OFF_HB   = OFF_CNT  + (size_t)BN * NT * 4;    // 256 B
static constexpr size_t OFF_SSRC = OFF_HB   + 256;
static constexpr size_t OFF_SDST = OFF_SSRC + (size_t)SORT_CAP * 4;
static constexpr size_t OFF_WMB  = OFF_SDST + (size_t)SORT_CAP * 4;   // 8*128*128 bf16
static constexpr size_t OFF_WIHB = OFF_WMB  + (size_t)NT * DD * DD * 2;
static constexpr size_t OFF_WHHB = OFF_WIHB + (size_t)3 * DD * DD * 2;
static constexpr size_t OFF_SH   = OFF_WHHB + (size_t)3 * DD * DD * 2;
// during GRU loop: rz[BN][256] bf16 (16 MB)
static constexpr size_t OFF_RZ   = OFF_SH;
// after loop: conv scratch (aliases rz region)
static constexpr size_t OFF_P1Y  = OFF_SH;                                // 32*128*512 f32
static constexpr size_t OFF_P1Z  = OFF_P1Y + (size_t)32 * 128 * 512 * 4; // 32*256*512 f32
static constexpr size_t OFF_QY   = OFF_P1Z + (size_t)32 * 256 * 512 * 4; // 32*255*128 f32
static constexpr size_t OFF_QZ   = OFF_QY  + (size_t)32 * 255 * 128 * 4; // 32*255*256 f32
static constexpr size_t WS_NEED  = OFF_QZ  + (size_t)32 * 255 * 256 * 4; // ~79.4 MiB

// ---------------- generic f32 -> bf16 converter ----------------
__global__ void k_cvt(const float* __restrict__ s, unsigned short* __restrict__ d, int n4)
{
    int i = blockIdx.x * 256 + threadIdx.x;
    if (i < n4) {
        float4 v = ((const float4*)s)[i];
        ((uint2*)d)[i] = make_uint2(pk(v.x, v.y), pk(v.z, v.w));
    }
}

// ---------------- graph preprocessing ----------------

__global__ void k_hist(const int* __restrict__ et, const int* __restrict__ dst,
                       int* __restrict__ hb, int* __restrict__ cnt)
{
    __shared__ int lh[NT];
    int tid = threadIdx.x;
    if (tid < NT) lh[tid] = 0;
    __syncthreads();
    int base = blockIdx.x * 1024;
    for (int k = 0; k < 4; ++k) {
        int e = base + tid + k * 256;
        int t = et[e];
        atomicAdd(&lh[t], 1);
        atomicAdd(&cnt[dst[e] * NT + t], 1);
    }
    __syncthreads();
    if (tid < NT) atomicAdd(&hb[tid], lh[tid]);
}

__global__ void k_scan(int* hb)
{
    int s = 0;
    for (int t = 0; t < NT; ++t) {
        hb[8 + t] = s;
        hb[20 + t] = s;
        s += ((hb[t] + 127) >> 7) << 7;
    }
    hb[16] = s;
}

__global__ void k_scatter(const int* __restrict__ src, const int* __restrict__ dst,
                          const int* __restrict__ et, int* __restrict__ hb,
                          int* __restrict__ ssrc, int* __restrict__ sdst)
{
    __shared__ int lc[NT], lbase[NT];
    int tid = threadIdx.x;
    if (tid < NT) lc[tid] = 0;
    __syncthreads();
    int base = blockIdx.x * 1024;
    int myt[4], myr[4];
    for (int k = 0; k < 4; ++k) {
        int e = base + tid * 4 + k;
        int t = et[e];
        myt[k] = t;
        myr[k] = atomicAdd(&lc[t], 1);
    }
    __syncthreads();
    if (tid < NT) lbase[tid] = atomicAdd(&hb[20 + tid], lc[tid]);
    __syncthreads();
    for (int k = 0; k < 4; ++k) {
        int e = base + tid * 4 + k;
        int p = lbase[myt[k]] + myr[k];
        ssrc[p] = src[e];
        sdst[p] = dst[e];
    }
}

// seed a[v][o] = sum_t cnt[v][t] * b_msg[t][o]
__global__ void k_bvec(const int* __restrict__ cnt, const float* __restrict__ bmsg,
                       float* __restrict__ a)
{
    int q = blockIdx.x * 256 + threadIdx.x;
    int v = q >> 5, o0 = (q & 31) * 4;
    const int* cv = cnt + v * NT;
    float4 acc = make_float4(0.f, 0.f, 0.f, 0.f);
    for (int t = 0; t < NT; ++t) {
        float c = (float)cv[t];
        float4 b = ld4(bmsg + t * DD + o0);
        acc.x += c * b.x; acc.y += c * b.y; acc.z += c * b.z; acc.w += c * b.w;
    }
    *(float4*)(a + (size_t)v * DD + o0) = acc;
}

// ---------------- MFMA message pass: 128 same-etype edges x 128 outputs ----------------
// a[dst[e]][o] += sum_d hbf[src[e]][d] * Wmsg_bf[t][o][d]

__launch_bounds__(256, 2)
__global__ void k_msg(const int* __restrict__ ssrc, const int* __restrict__ sdst,
                      const int* __restrict__ hb, const unsigned short* __restrict__ hbf,
                      const unsigned short* __restrict__ wmb, float* __restrict__ a)
{
    __shared__ __align__(16) unsigned short As[128 * 128];
    __shared__ __align__(16) unsigned short Ws[128 * 128];
    __shared__ int sdl[128], ssl[128];
    int base = blockIdx.x * 128;
    if (base >= hb[16]) return;                 // uniform
    int t = 0;
#pragma unroll
    for (int i = 1; i < NT; ++i) if (base >= hb[8 + i]) t = i;
    int tid = threadIdx.x;
    if (tid < 128) { sdl[tid] = sdst[base + tid]; ssl[tid] = ssrc[base + tid]; }
    __syncthreads();
    {
        int r = tid >> 1, half = tid & 1;
        const uint4* hp = (const uint4*)(hbf + (size_t)ssl[r] * DD + half * 64);
        const uint4* wp = (const uint4*)(wmb + (size_t)t * DD * DD + (size_t)r * DD + half * 64);
        unsigned boff = r * 256 + half * 128;
        unsigned sw = (r & 7) << 4;
#pragma unroll
        for (int c = 0; c < 8; ++c) {
            unsigned byte = (boff + c * 16) ^ sw;
            *(uint4*)((char*)As + byte) = hp[c];
            *(uint4*)((char*)Ws + byte) = wp[c];
        }
    }
    __syncthreads();
    int lane = tid & 63, wv = tid >> 6;
    int wm = (wv >> 1) * 64, wn = (wv & 1) * 64;
    int lr = lane & 15, lk = lane >> 4;
    f32x4 acc[4][4];
#pragma unroll
    for (int i = 0; i < 4; ++i)
#pragma unroll
        for (int j = 0; j < 4; ++j) acc[i][j] = (f32x4){0.f, 0.f, 0.f, 0.f};
#pragma unroll
    for (int kc = 0; kc < 4; ++kc) {
        int cb = kc * 64 + lk * 16;
        bf16x8 af[4], bfv[4];
#pragma unroll
        for (int mi = 0; mi < 4; ++mi) {
            int row = wm + mi * 16 + lr;
            af[mi] = *(const bf16x8*)((const char*)As + ((row * 256 + cb) ^ ((row & 7) << 4)));
        }
#pragma unroll
        for (int ni = 0; ni < 4; ++ni) {
            int row = wn + ni * 16 + lr;
            bfv[ni] = *(const bf16x8*)((const char*)Ws + ((row * 256 + cb) ^ ((row & 7) << 4)));
        }
#pragma unroll
        for (int mi = 0; mi < 4; ++mi)
#pragma unroll
            for (int ni = 0; ni < 4; ++ni)
                acc[mi][ni] = __builtin_amdgcn_mfma_f32_16x16x32_bf16(af[mi], bfv[ni], acc[mi][ni], 0, 0, 0);
    }
#pragma unroll
    for (int mi = 0; mi < 4; ++mi) {
#pragma unroll
        for (int rg = 0; rg < 4; ++rg) {
            int er = wm + mi * 16 + lk * 4 + rg;
            int dv = sdl[er];
            if (dv >= 0) {
                float* ap = a + (size_t)dv * DD + wn + lr;
#pragma unroll
                for (int ni = 0; ni < 4; ++ni)
                    atomicAdd(ap + ni * 16, acc[mi][ni][rg]);
            }
        }
    }
}

// ---------------- MFMA GRU r,z: rz[v][g*128+o] = sigma(a.wih_g + h.whh_g + b) ----------------

__launch_bounds__(256, 2)
__global__ void k_grurz(const float* __restrict__ a, const unsigned short* __restrict__ hbf,
                        const unsigned short* __restrict__ wihb, const unsigned short* __restrict__ whhb,
                        const float* __restrict__ bih, const float* __restrict__ bhh,
                        unsigned short* __restrict__ rz)
{
    __shared__ __align__(16) unsigned short Xs[128 * 128];
    __shared__ __align__(16) unsigned short Ws2[128 * 128];
    int m0 = blockIdx.x * 128;
    int g  = blockIdx.y;                      // 0 = r, 1 = z
    int tid = threadIdx.x;
    int lane = tid & 63, wv = tid >> 6;
    int wm = (wv >> 1) * 64, wn = (wv & 1) * 64;
    int lr = lane & 15, lk = lane >> 4;
    f32x4 acc[4][4];
#pragma unroll
    for (int i = 0; i < 4; ++i)
#pragma unroll
        for (int j = 0; j < 4; ++j) acc[i][j] = (f32x4){0.f, 0.f, 0.f, 0.f};

    int r = tid >> 1, half = tid & 1;
    unsigned boff = r * 256 + half * 128;
    unsigned sw = (r & 7) << 4;
    for (int pass = 0; pass < 2; ++pass) {
        if (pass) __syncthreads();            // protect restage (WAR)
        if (pass == 0) {
            const float4* sp = (const float4*)(a + (size_t)(m0 + r) * DD + half * 64);
#pragma unroll
            for (int c = 0; c < 8; ++c) {
                float4 v0 = sp[2 * c], v1 = sp[2 * c + 1];
                *(uint4*)((char*)Xs + ((boff + c * 16) ^ sw)) =
                    make_uint4(pk(v0.x, v0.y), pk(v0.z, v0.w), pk(v1.x, v1.y), pk(v1.z, v1.w));
            }
        } else {
            const uint4* sp = (const uint4*)(hbf + (size_t)(m0 + r) * DD + half * 64);
#pragma unroll
            for (int c = 0; c < 8; ++c)
                *(uint4*)((char*)Xs + ((boff + c * 16) ^ sw)) = sp[c];
        }
        const uint4* wp = (const uint4*)((pass ? whhb : wihb) + (size_t)(g * DD + r) * DD + half * 64);
#pragma unroll
        for (int c = 0; c < 8; ++c)
            *(uint4*)((char*)Ws2 + ((boff + c * 16) ^ sw)) = wp[c];
        __syncthreads();
#pragma unroll
        for (int kc = 0; kc < 4; ++kc) {
            int cb = kc * 64 + lk * 16;
            bf16x8 af[4], bfv[4];
#pragma unroll
            for (int mi = 0; mi < 4; ++mi) {
                int row = wm + mi * 16 + lr;
                af[mi] = *(const bf16x8*)((const char*)Xs + ((row * 256 + cb) ^ ((row & 7) << 4)));
            }
#pragma unroll
            for (int ni = 0; ni < 4; ++ni) {
                int row = wn + ni * 16 + lr;
                bfv[ni] = *(const bf16x8*)((const char*)Ws2 + ((row * 256 + cb) ^ ((row & 7) << 4)));
            }
#pragma unroll
            for (int mi = 0; mi < 4; ++mi)
#pragma unroll
                for (int ni = 0; ni < 4; ++ni)
                    acc[mi][ni] = __builtin_amdgcn_mfma_f32_16x16x32_bf16(af[mi], bfv[ni], acc[mi][ni], 0, 0, 0);
        }
    }
#pragma unroll
    for (int ni = 0; ni < 4; ++ni) {
        int col = wn + ni * 16 + lr;
        float bsum = bih[g * DD + col] + bhh[g * DD + col];
#pragma unroll
        for (int mi = 0; mi < 4; ++mi)
#pragma unroll
            for (int rg = 0; rg < 4; ++rg) {
                int v = m0 + wm + mi * 16 + lk * 4 + rg;
                rz[(size_t)v * 256 + g * DD + col] =
                    (unsigned short)f2b(sigmoidf_(acc[mi][ni][rg] + bsum));
            }
    }
}

// ---------------- MFMA GRU n + combine: h = (1-z)*tanh(i_n + b + r*(h_n + b)) + z*h ----------------

__launch_bounds__(256, 2)
__global__ void k_grun(const float* __restrict__ a, float* __restrict__ h,
                       unsigned short* __restrict__ hbf,
                       const unsigned short* __restrict__ wihb, const unsigned short* __restrict__ whhb,
                       const float* __restrict__ bih, const float* __restrict__ bhh,
                       const unsigned short* __restrict__ rz)
{
    __shared__ __align__(16) unsigned short Xs[128 * 128];
    __shared__ __align__(16) unsigned short Ws2[128 * 128];
    int m0 = blockIdx.x * 128;
    int tid = threadIdx.x;
    int lane = tid & 63, wv = tid >> 6;
    int wm = (wv >> 1) * 64, wn = (wv & 1) * 64;
    int lr = lane & 15, lk = lane >> 4;
    f32x4 acci[4][4], acch[4][4];
#pragma unroll
    for (int i = 0; i < 4; ++i)
#pragma unroll
        for (int j = 0; j < 4; ++j) {
            acci[i][j] = (f32x4){0.f, 0.f, 0.f, 0.f};
            acch[i][j] = (f32x4){0.f, 0.f, 0.f, 0.f};
        }

    int r = tid >> 1, half = tid & 1;
    unsigned boff = r * 256 + half * 128;
    unsigned sw = (r & 7) << 4;
    for (int pass = 0; pass < 2; ++pass) {
        if (pass) __syncthreads();
        if (pass == 0) {
            const float4* sp = (const float4*)(a + (size_t)(m0 + r) * DD + half * 64);
#pragma unroll
            for (int c = 0; c < 8; ++c) {
                float4 v0 = sp[2 * c], v1 = sp[2 * c + 1];
                *(uint4*)((char*)Xs + ((boff + c * 16) ^ sw)) =
                    make_uint4(pk(v0.x, v0.y), pk(v0.z, v0.w), pk(v1.x, v1.y), pk(v1.z, v1.w));
            }
        } else {
            const uint4* sp = (const uint4*)(hbf + (size_t)(m0 + r) * DD + half * 64);
#pragma unroll
            for (int c = 0; c < 8; ++c)
                *(uint4*)((char*)Xs + ((boff + c * 16) ^ sw)) = sp[c];
        }
        const uint4* wp = (const uint4*)((pass ? whhb : wihb) + (size_t)(2 * DD + r) * DD + half * 64);
#pragma unroll
        for (int c = 0; c < 8; ++c)
            *(uint4*)((char*)Ws2 + ((boff + c * 16) ^ sw)) = wp[c];
        __syncthreads();
#pragma unroll
        for (int kc = 0; kc < 4; ++kc) {
            int cb = kc * 64 + lk * 16;
            bf16x8 af[4], bfv[4];
#pragma unroll
            for (int mi = 0; mi < 4; ++mi) {
                int row = wm + mi * 16 + lr;
                af[mi] = *(const bf16x8*)((const char*)Xs + ((row * 256 + cb) ^ ((row & 7) << 4)));
            }
#pragma unroll
            for (int ni = 0; ni < 4; ++ni) {
                int row = wn + ni * 16 + lr;
                bfv[ni] = *(const bf16x8*)((const char*)Ws2 + ((row * 256 + cb) ^ ((row & 7) << 4)));
            }
            if (pass == 0) {
#pragma unroll
                for (int mi = 0; mi < 4; ++mi)
#pragma unroll
                    for (int ni = 0; ni < 4; ++ni)
                        acci[mi][ni] = __builtin_amdgcn_mfma_f32_16x16x32_bf16(af[mi], bfv[ni], acci[mi][ni], 0, 0, 0);
            } else {
#pragma unroll
                for (int mi = 0; mi < 4; ++mi)
#pragma unroll
                    for (int ni = 0; ni < 4; ++ni)
                        acch[mi][ni] = __builtin_amdgcn_mfma_f32_16x16x32_bf16(af[mi], bfv[ni], acch[mi][ni], 0, 0, 0);
            }
        }
    }
#pragma unroll
    for (int ni = 0; ni < 4; ++ni) {
        int col = wn + ni * 16 + lr;
        float bin = bih[2 * DD + col], bhn = bhh[2 * DD + col];
#pragma unroll
        for (int mi = 0; mi < 4; ++mi)
#pragma unroll
            for (int rg = 0; rg < 4; ++rg) {
                int v = m0 + wm + mi * 16 + lk * 4 + rg;
                float rr = b2f(rz[(size_t)v * 256 + col]);
                float zz = b2f(rz[(size_t)v * 256 + 128 + col]);
                float nn = tanhf(acci[mi][ni][rg] + bin + rr * (acch[mi][ni][rg] + bhn));
                float hold = h[(size_t)v * DD + col];
                float hnew = (1.f - zz) * nn + zz * hold;
                h[(size_t)v * DD + col] = hnew;
                hbf[(size_t)v * DD + col] = (unsigned short)f2b(hnew);
            }
    }
}

// ---------------- conv1(k=3)+relu+maxpool(3,2), LDS-staged weights ----------------

template <int CIN>
__launch_bounds__(256, 2)
__global__ void k_conv1(const float* __restrict__ hf, const float* __restrict__ h0,
                        const float* __restrict__ w, const float* __restrict__ bias,
                        float* __restrict__ P)
{
    __shared__ float xs[67][33];
    __shared__ float ws1[128][32][3];
    int jt = blockIdx.x, b = blockIdx.y, zz = blockIdx.z;
    int tid = threadIdx.x;
    int j0 = jt * 32, l0 = 2 * j0;
    int og = tid >> 5, jl = tid & 31;
    float acc[16][3];
#pragma unroll
    for (int cc = 0; cc < 16; ++cc) { acc[cc][0] = 0.f; acc[cc][1] = 0.f; acc[cc][2] = 0.f; }
    for (int ci0 = 0; ci0 < CIN; ci0 += 32) {
        __syncthreads();
        for (int q = tid; q < 536; q += 256) {            // 67 rows x 32 ci
            int rr = q >> 3, c = (q & 7) << 2;
            int l = l0 + rr; if (l > NNODE - 1) l = NNODE - 1;
            int ci = ci0 + c;
            const float* sp = (CIN == 128 || ci < 128)
                ? hf + ((size_t)(b * NNODE + l)) * DD + ci
                : h0 + ((size_t)(b * NNODE + l)) * DD + (ci - 128);
            float4 v = ld4(sp);
            xs[rr][c] = v.x; xs[rr][c + 1] = v.y; xs[rr][c + 2] = v.z; xs[rr][c + 3] = v.w;
        }
        for (int q = tid; q < 4096; q += 256) {           // 128 co x 32 ci x 3
            int co = q >> 5, ci = q & 31;
            const float* wp = w + ((size_t)(zz * 128 + co) * CIN + (ci0 + ci)) * 3;
            ws1[co][ci][0] = wp[0]; ws1[co][ci][1] = wp[1]; ws1[co][ci][2] = wp[2];
        }
        __syncthreads();
        for (int ci = 0; ci < 32; ++ci) {
            float x0 = xs[2 * jl + 0][ci], x1 = xs[2 * jl + 1][ci], x2 = xs[2 * jl + 2][ci],
                  x3 = xs[2 * jl + 3][ci], x4 = xs[2 * jl + 4][ci];
#pragma unroll
            for (int cc = 0; cc < 16; ++cc) {
                int co = og + 8 * cc;
                float w0 = ws1[co][ci][0], w1 = ws1[co][ci][1], w2 = ws1[co][ci][2];
                acc[cc][0] += x0 * w0 + x1 * w1 + x2 * w2;
                acc[cc][1] += x1 * w0 + x2 * w1 + x3 * w2;
                acc[cc][2] += x2 * w0 + x3 * w1 + x4 * w2;
            }
        }
    }
    int j = j0 + jl;
    if (j < 510) {
#pragma unroll
        for (int cc = 0; cc < 16; ++cc) {
            int co = zz * 128 + og + 8 * cc;
            float m = fmaxf(acc[cc][0], fmaxf(acc[cc][1], acc[cc][2]));
            P[((size_t)(b * CIN + co)) * 512 + j] = fmaxf(0.f, m + bias[co]);
        }
    }
}

// ---------------- conv2(k=1)+relu+maxpool(2,2), LDS-staged weights ----------------

template <int CIN>
__launch_bounds__(256, 2)
__global__ void k_conv2(const float* __restrict__ P, const float* __restrict__ w,
                        const float* __restrict__ bias, float* __restrict__ Q)
{
    __shared__ float xs[64][69];
    __shared__ float w2[128][65];
    int jt = blockIdx.x, b = blockIdx.y, zz = blockIdx.z;
    int tid = threadIdx.x;
    int j0 = jt * 32, l0 = 2 * j0;
    int og = tid >> 5, jl = tid & 31;
    float a0[16], a1[16];
#pragma unroll
    for (int cc = 0; cc < 16; ++cc) { a0[cc] = 0.f; a1[cc] = 0.f; }
    for (int ci0 = 0; ci0 < CIN; ci0 += 64) {
        __syncthreads();
        for (int q = tid; q < 64 * 17; q += 256) {
            int ci = q / 17, c = (q % 17) * 4;
            const float* rowp = P + ((size_t)(b * CIN + ci0 + ci)) * 512;
            float4 v;
            if (l0 + c + 3 <= 509) v = ld4(rowp + l0 + c);
            else {
                float tmp[4];
                for (int u = 0; u < 4; ++u) { int lu = l0 + c + u; if (lu > 509) lu = 509; tmp[u] = rowp[lu]; }
                v = make_float4(tmp[0], tmp[1], tmp[2], tmp[3]);
            }
            xs[ci][c] = v.x; xs[ci][c + 1] = v.y; xs[ci][c + 2] = v.z; xs[ci][c + 3] = v.w;
        }
        for (int q = tid; q < 128 * 16; q += 256) {
            int co = q >> 4, c = (q & 15) << 2;
            float4 v = ld4(w + (size_t)(zz * 128 + co) * CIN + ci0 + c);
            w2[co][c] = v.x; w2[co][c + 1] = v.y; w2[co][c + 2] = v.z; w2[co][c + 3] = v.w;
        }
        __syncthreads();
        for (int ci = 0; ci < 64; ++ci) {
            float x0 = xs[ci][2 * jl + 0], x1 = xs[ci][2 * jl + 1];
#pragma unroll
            for (int cc = 0; cc < 16; ++cc) {
                float wv = w2[og + 8 * cc][ci];
                a0[cc] += x0 * wv; a1[cc] += x1 * wv;
            }
        }
    }
    int j = j0 + jl;
    if (j < 255) {
#pragma unroll
        for (int cc = 0; cc < 16; ++cc) {
            int co = zz * 128 + og + 8 * cc;
            Q[((size_t)(b * 255 + j)) * CIN + co] = fmaxf(0.f, fmaxf(a0[cc], a1[cc]) + bias[co]);
        }
    }
}

// ---------------- final reduction ----------------

__launch_bounds__(256)
__global__ void k_final(const float* __restrict__ QY, const float* __restrict__ QZ,
                        const float* __restrict__ wy, const float* __restrict__ by,
                        const float* __restrict__ wz, const float* __restrict__ bz,
                        float* __restrict__ out)
{
    int b = blockIdx.x, tid = threadIdx.x;
    float p = 0.f;
    if (tid < 255) {
        const float* qy = QY + ((size_t)(b * 255 + tid)) * 128;
        const float* qz = QZ + ((size_t)(b * 255 + tid)) * 256;
        float dy = 0.f, dz = 0.f;
        for (int c = 0; c < 128; c += 4) {
            float4 q = ld4(qy + c), wv = ld4(wy + c);
            dy += q.x * wv.x + q.y * wv.y + q.z * wv.z + q.w * wv.w;
        }
        for (int c = 0; c < 256; c += 4) {
            float4 q = ld4(qz + c), wv = ld4(wz + c);
            dz += q.x * wv.x + q.y * wv.y + q.z * wv.z + q.w * wv.w;
        }
        p = (dy + by[0]) * (dz + bz[0]);
    }
    __shared__ float red[4];
    for (int off = 32; off > 0; off >>= 1) p += __shfl_down(p, off);
    if ((tid & 63) == 0) red[tid >> 6] = p;
    __syncthreads();
    if (tid == 0) {
        float s = red[0] + red[1] + red[2] + red[3];
        out[b] = 1.f / (1.f + expf(-s / 255.f));
    }
}

// ---------------- launch ----------------

extern "C" void kernel_launch(void* const* d_in, const int* in_sizes, int n_in,
                              void* d_out, int out_size, void* d_ws, size_t ws_size,
                              hipStream_t stream)
{
    const float* h_in = (const float*)d_in[0];
    const int* src = (const int*)d_in[1];
    const int* dst = (const int*)d_in[2];
    const int* et  = (const int*)d_in[3];
    const float* Wmsg = (const float*)d_in[4];
    const float* bmsg = (const float*)d_in[5];
    const float* wih = (const float*)d_in[6];
    const float* whh = (const float*)d_in[7];
    const float* bih = (const float*)d_in[8];
    const float* bhh = (const float*)d_in[9];
    const float* c1w = (const float*)d_in[10];
    const float* c1b = (const float*)d_in[11];
    const float* c2w = (const float*)d_in[12];
    const float* c2b = (const float*)d_in[13];
    const float* z1w = (const float*)d_in[14];
    const float* z1b = (const float*)d_in[15];
    const float* z2w = (const float*)d_in[16];
    const float* z2b = (const float*)d_in[17];
    const float* wy  = (const float*)d_in[18];
    const float* by  = (const float*)d_in[19];
    const float* wz  = (const float*)d_in[20];
    const float* bz  = (const float*)d_in[21];
    float* out = (float*)d_out;

    if (ws_size < WS_NEED) return;   // loud failure: output stays poisoned

    char* ws = (char*)d_ws;
    float* hcur = (float*)(ws + OFF_HCUR);
    float* a    = (float*)(ws + OFF_A);
    unsigned short* hbf  = (unsigned short*)(ws + OFF_HBF);
    int*   cnt  = (int*)(ws + OFF_CNT);
    int*   hb   = (int*)(ws + OFF_HB);
    int*   ssrc = (int*)(ws + OFF_SSRC);
    int*   sdst = (int*)(ws + OFF_SDST);
    unsigned short* wmb  = (unsigned short*)(ws + OFF_WMB);
    unsigned short* wihb = (unsigned short*)(ws + OFF_WIHB);
    unsigned short* whhb = (unsigned short*)(ws + OFF_WHHB);
    unsigned short* rz   = (unsigned short*)(ws + OFF_RZ);
    float* P1Y  = (float*)(ws + OFF_P1Y);
    float* P1Z  = (float*)(ws + OFF_P1Z);
    float* QY   = (float*)(ws + OFF_QY);
    float* QZ   = (float*)(ws + OFF_QZ);

    hipMemcpyAsync(hcur, h_in, (size_t)BN * DD * 4, hipMemcpyDeviceToDevice, stream);
    hipMemsetAsync(cnt, 0, (size_t)BN * NT * 4, stream);
    hipMemsetAsync(hb, 0, 256, stream);
    hipMemsetAsync(ssrc, 0, (size_t)SORT_CAP * 4, stream);
    hipMemsetAsync(sdst, 0xFF, (size_t)SORT_CAP * 4, stream);

    k_cvt<<<(BN * DD / 4 + 255) / 256, 256, 0, stream>>>(h_in, hbf, BN * DD / 4);
    k_cvt<<<(NT * DD * DD / 4 + 255) / 256, 256, 0, stream>>>(Wmsg, wmb, NT * DD * DD / 4);
    k_cvt<<<(3 * DD * DD / 4 + 255) / 256, 256, 0, stream>>>(wih, wihb, 3 * DD * DD / 4);
    k_cvt<<<(3 * DD * DD / 4 + 255) / 256, 256, 0, stream>>>(whh, whhb, 3 * DD * DD / 4);

    k_hist<<<256, 256, 0, stream>>>(et, dst, hb, cnt);
    k_scan<<<1, 1, 0, stream>>>(hb);
    k_scatter<<<256, 256, 0, stream>>>(src, dst, et, hb, ssrc, sdst);

    for (int s = 0; s < NSTEPS; ++s) {
        k_bvec<<<4096, 256, 0, stream>>>(cnt, bmsg, a);
        k_msg<<<NTILES, 256, 0, stream>>>(ssrc, sdst, hb, hbf, wmb, a);
        k_grurz<<<dim3(BN / 128, 2), 256, 0, stream>>>(a, hbf, wihb, whhb, bih, bhh, rz);
        k_grun<<<BN / 128, 256, 0, stream>>>(a, hcur, hbf, wihb, whhb, bih, bhh, rz);
    }

    k_conv1<128><<<dim3(16, 32, 1), 256, 0, stream>>>(hcur, h_in, c1w, c1b, P1Y);
    k_conv2<128><<<dim3(8, 32, 1), 256, 0, stream>>>(P1Y, c2w, c2b, QY);
    k_conv1<256><<<dim3(16, 32, 2), 256, 0, stream>>>(hcur, h_in, z1w, z1b, P1Z);
    k_conv2<256><<<dim3(8, 32, 2), 256, 0, stream>>>(P1Z, z2w, z2b, QZ);
    k_final<<<32, 256, 0, stream>>>(QY, QZ, wy, by, wz, bz, out);
}

// Round 4
// 1219.624 us; speedup vs baseline: 8.4276x; 1.3771x over previous
//
#include <hip/hip_runtime.h>
#include <math.h>

#define BB 32
#define NNODE 1024
#define BN 32768
#define NE 262144
#define DD 128
#define NT 8
#define NSTEPS 6
#define SORT_CAP (NE + 1024)   // bins padded to 128-edge tiles
#define NTILES 2056            // sum ceil(hist_t/128) <= E/128 + 8

typedef __attribute__((ext_vector_type(8))) short bf16x8;
typedef __attribute__((ext_vector_type(4))) float f32x4;

static __device__ __forceinline__ float4 ld4(const float* p) { return *(const float4*)p; }
static __device__ __forceinline__ float sigmoidf_(float x) { return 1.f / (1.f + expf(-x)); }
// f32 -> bf16 round-to-nearest-even
static __device__ __forceinline__ unsigned f2b(float f) {
    unsigned u = __float_as_uint(f);
    return (u + 0x7FFFu + ((u >> 16) & 1u)) >> 16;
}
static __device__ __forceinline__ float b2f(unsigned short b) {
    return __uint_as_float(((unsigned)b) << 16);
}
static __device__ __forceinline__ unsigned pk(float a, float b) {
    return f2b(a) | (f2b(b) << 16);
}
// elementwise u16 max of packed pairs (valid ordering for non-negative bf16)
static __device__ __forceinline__ unsigned bmax2(unsigned a, unsigned b) {
    unsigned ah = a & 0xFFFF0000u, bh = b & 0xFFFF0000u;
    unsigned al = a & 0x0000FFFFu, bl = b & 0x0000FFFFu;
    return (ah > bh ? ah : bh) | (al > bl ? al : bl);
}
static __device__ __forceinline__ uint4 bmax4(uint4 a, uint4 b) {
    return make_uint4(bmax2(a.x, b.x), bmax2(a.y, b.y), bmax2(a.z, b.z), bmax2(a.w, b.w));
}

// ---------------- workspace layout (bytes) ----------------
static constexpr size_t OFF_HCUR = 0;                                  // BN*DD f32
static constexpr size_t OFF_HBF  = OFF_HCUR + (size_t)BN * DD * 4;     // BN*DD bf16
static constexpr size_t OFF_CNT  = OFF_HBF  + (size_t)BN * DD * 2;     // BN*NT i32
static constexpr size_t OFF_HB   = OFF_CNT  + (size_t)BN * NT * 4;     // 256 B
static constexpr size_t OFF_SSRC = OFF_HB   + 256;
static constexpr size_t OFF_SDST = OFF_SSRC + (size_t)SORT_CAP * 4;
static constexpr size_t OFF_WMB  = OFF_SDST + (size_t)SORT_CAP * 4;    // 8*128*128 bf16
static constexpr size_t OFF_WIHB = OFF_WMB  + (size_t)NT * DD * DD * 2;
static constexpr size_t OFF_WHHB = OFF_WIHB + (size_t)3 * DD * DD * 2;
static constexpr size_t OFF_W1PY = OFF_WHHB + (size_t)3 * DD * DD * 2; // 3*128*128 bf16
static constexpr size_t OFF_W1PZ = OFF_W1PY + (size_t)3 * 128 * 128 * 2; // 3*256*256 bf16
static constexpr size_t OFF_W2YB = OFF_W1PZ + (size_t)3 * 256 * 256 * 2; // 128*128 bf16
static constexpr size_t OFF_W2ZB = OFF_W2YB + (size_t)128 * 128 * 2;     // 256*256 bf16
static constexpr size_t OFF_UN   = OFF_W2ZB + (size_t)256 * 256 * 2;   // union region
// GGNN phase:
static constexpr size_t OFF_A    = OFF_UN;                             // BN*DD f32 (16.78M)
static constexpr size_t OFF_RZ   = OFF_UN + (size_t)BN * DD * 4;       // BN*256 bf16 (16.78M)
// conv phase (after GGNN; aliases A/RZ):
static constexpr size_t OFF_U1Y  = OFF_UN;                              // 32*1024*128 bf16
static constexpr size_t OFF_U1Z  = OFF_U1Y + (size_t)32 * 1024 * 128 * 2; // 32*1024*256 bf16
static constexpr size_t OFF_QY   = OFF_U1Z + (size_t)32 * 1024 * 256 * 2; // 32*255*128 f32
static constexpr size_t OFF_QZ   = OFF_QY  + (size_t)32 * 255 * 128 * 4;  // 32*255*256 f32
static constexpr size_t WS_NEED  = OFF_QZ  + (size_t)32 * 255 * 256 * 4;  // ~67 MiB

// ---------------- generic f32 -> bf16 converter ----------------
__global__ void k_cvt(const float* __restrict__ s, unsigned short* __restrict__ d, int n4)
{
    int i = blockIdx.x * 256 + threadIdx.x;
    if (i < n4) {
        float4 v = ((const float4*)s)[i];
        ((uint2*)d)[i] = make_uint2(pk(v.x, v.y), pk(v.z, v.w));
    }
}

// pack conv1 weights: wp[k][co][ci] = bf16(w[co][ci][k])
__global__ void k_packw1(const float* __restrict__ w, unsigned short* __restrict__ wp, int C)
{
    int idx = blockIdx.x * 256 + threadIdx.x;
    if (idx < 3 * C * C) {
        int k = idx / (C * C), rem = idx % (C * C);
        wp[idx] = (unsigned short)f2b(w[(size_t)rem * 3 + k]);
    }
}

// ---------------- graph preprocessing ----------------

__global__ void k_hist(const int* __restrict__ et, const int* __restrict__ dst,
                       int* __restrict__ hb, int* __restrict__ cnt)
{
    __shared__ int lh[NT];
    int tid = threadIdx.x;
    if (tid < NT) lh[tid] = 0;
    __syncthreads();
    int base = blockIdx.x * 1024;
    for (int k = 0; k < 4; ++k) {
        int e = base + tid + k * 256;
        int t = et[e];
        atomicAdd(&lh[t], 1);
        atomicAdd(&cnt[dst[e] * NT + t], 1);
    }
    __syncthreads();
    if (tid < NT) atomicAdd(&hb[tid], lh[tid]);
}

__global__ void k_scan(int* hb)
{
    int s = 0;
    for (int t = 0; t < NT; ++t) {
        hb[8 + t] = s;
        hb[20 + t] = s;
        s += ((hb[t] + 127) >> 7) << 7;
    }
    hb[16] = s;
}

__global__ void k_scatter(const int* __restrict__ src, const int* __restrict__ dst,
                          const int* __restrict__ et, int* __restrict__ hb,
                          int* __restrict__ ssrc, int* __restrict__ sdst)
{
    __shared__ int lc[NT], lbase[NT];
    int tid = threadIdx.x;
    if (tid < NT) lc[tid] = 0;
    __syncthreads();
    int base = blockIdx.x * 1024;
    int myt[4], myr[4];
    for (int k = 0; k < 4; ++k) {
        int e = base + tid * 4 + k;
        int t = et[e];
        myt[k] = t;
        myr[k] = atomicAdd(&lc[t], 1);
    }
    __syncthreads();
    if (tid < NT) lbase[tid] = atomicAdd(&hb[20 + tid], lc[tid]);
    __syncthreads();
    for (int k = 0; k < 4; ++k) {
        int e = base + tid * 4 + k;
        int p = lbase[myt[k]] + myr[k];
        ssrc[p] = src[e];
        sdst[p] = dst[e];
    }
}

// seed a[v][o] = sum_t cnt[v][t] * b_msg[t][o]
__global__ void k_bvec(const int* __restrict__ cnt, const float* __restrict__ bmsg,
                       float* __restrict__ a)
{
    int q = blockIdx.x * 256 + threadIdx.x;
    int v = q >> 5, o0 = (q & 31) * 4;
    const int* cv = cnt + v * NT;
    float4 acc = make_float4(0.f, 0.f, 0.f, 0.f);
    for (int t = 0; t < NT; ++t) {
        float c = (float)cv[t];
        float4 b = ld4(bmsg + t * DD + o0);
        acc.x += c * b.x; acc.y += c * b.y; acc.z += c * b.z; acc.w += c * b.w;
    }
    *(float4*)(a + (size_t)v * DD + o0) = acc;
}

// ---------------- MFMA message pass: 128 same-etype edges x 128 outputs ----------------

__launch_bounds__(256, 2)
__global__ void k_msg(const int* __restrict__ ssrc, const int* __restrict__ sdst,
                      const int* __restrict__ hb, const unsigned short* __restrict__ hbf,
                      const unsigned short* __restrict__ wmb, float* __restrict__ a)
{
    __shared__ __align__(16) unsigned short As[128 * 128];
    __shared__ __align__(16) unsigned short Ws[128 * 128];
    __shared__ int sdl[128], ssl[128];
    int base = blockIdx.x * 128;
    if (base >= hb[16]) return;                 // uniform
    int t = 0;
#pragma unroll
    for (int i = 1; i < NT; ++i) if (base >= hb[8 + i]) t = i;
    int tid = threadIdx.x;
    if (tid < 128) { sdl[tid] = sdst[base + tid]; ssl[tid] = ssrc[base + tid]; }
    __syncthreads();
    {
        int r = tid >> 1, half = tid & 1;
        const uint4* hp = (const uint4*)(hbf + (size_t)ssl[r] * DD + half * 64);
        const uint4* wp = (const uint4*)(wmb + (size_t)t * DD * DD + (size_t)r * DD + half * 64);
        unsigned boff = r * 256 + half * 128;
        unsigned sw = (r & 7) << 4;
#pragma unroll
        for (int c = 0; c < 8; ++c) {
            unsigned byte = (boff + c * 16) ^ sw;
            *(uint4*)((char*)As + byte) = hp[c];
            *(uint4*)((char*)Ws + byte) = wp[c];
        }
    }
    __syncthreads();
    int lane = tid & 63, wv = tid >> 6;
    int wm = (wv >> 1) * 64, wn = (wv & 1) * 64;
    int lr = lane & 15, lk = lane >> 4;
    f32x4 acc[4][4];
#pragma unroll
    for (int i = 0; i < 4; ++i)
#pragma unroll
        for (int j = 0; j < 4; ++j) acc[i][j] = (f32x4){0.f, 0.f, 0.f, 0.f};
#pragma unroll
    for (int kc = 0; kc < 4; ++kc) {
        int cb = kc * 64 + lk * 16;
        bf16x8 af[4], bfv[4];
#pragma unroll
        for (int mi = 0; mi < 4; ++mi) {
            int row = wm + mi * 16 + lr;
            af[mi] = *(const bf16x8*)((const char*)As + ((row * 256 + cb) ^ ((row & 7) << 4)));
        }
#pragma unroll
        for (int ni = 0; ni < 4; ++ni) {
            int row = wn + ni * 16 + lr;
            bfv[ni] = *(const bf16x8*)((const char*)Ws + ((row * 256 + cb) ^ ((row & 7) << 4)));
        }
#pragma unroll
        for (int mi = 0; mi < 4; ++mi)
#pragma unroll
            for (int ni = 0; ni < 4; ++ni)
                acc[mi][ni] = __builtin_amdgcn_mfma_f32_16x16x32_bf16(af[mi], bfv[ni], acc[mi][ni], 0, 0, 0);
    }
#pragma unroll
    for (int mi = 0; mi < 4; ++mi) {
#pragma unroll
        for (int rg = 0; rg < 4; ++rg) {
            int er = wm + mi * 16 + lk * 4 + rg;
            int dv = sdl[er];
            if (dv >= 0) {
                float* ap = a + (size_t)dv * DD + wn + lr;
#pragma unroll
                for (int ni = 0; ni < 4; ++ni)
                    atomicAdd(ap + ni * 16, acc[mi][ni][rg]);
            }
        }
    }
}

// ---------------- MFMA GRU r,z ----------------

__launch_bounds__(256, 2)
__global__ void k_grurz(const float* __restrict__ a, const unsigned short* __restrict__ hbf,
                        const unsigned short* __restrict__ wihb, const unsigned short* __restrict__ whhb,
                        const float* __restrict__ bih, const float* __restrict__ bhh,
                        unsigned short* __restrict__ rz)
{
    __shared__ __align__(16) unsigned short Xs[128 * 128];
    __shared__ __align__(16) unsigned short Ws2[128 * 128];
    int m0 = blockIdx.x * 128;
    int g  = blockIdx.y;                      // 0 = r, 1 = z
    int tid = threadIdx.x;
    int lane = tid & 63, wv = tid >> 6;
    int wm = (wv >> 1) * 64, wn = (wv & 1) * 64;
    int lr = lane & 15, lk = lane >> 4;
    f32x4 acc[4][4];
#pragma unroll
    for (int i = 0; i < 4; ++i)
#pragma unroll
        for (int j = 0; j < 4; ++j) acc[i][j] = (f32x4){0.f, 0.f, 0.f, 0.f};

    int r = tid >> 1, half = tid & 1;
    unsigned boff = r * 256 + half * 128;
    unsigned sw = (r & 7) << 4;
    for (int pass = 0; pass < 2; ++pass) {
        if (pass) __syncthreads();
        if (pass == 0) {
            const float4* sp = (const float4*)(a + (size_t)(m0 + r) * DD + half * 64);
#pragma unroll
            for (int c = 0; c < 8; ++c) {
                float4 v0 = sp[2 * c], v1 = sp[2 * c + 1];
                *(uint4*)((char*)Xs + ((boff + c * 16) ^ sw)) =
                    make_uint4(pk(v0.x, v0.y), pk(v0.z, v0.w), pk(v1.x, v1.y), pk(v1.z, v1.w));
            }
        } else {
            const uint4* sp = (const uint4*)(hbf + (size_t)(m0 + r) * DD + half * 64);
#pragma unroll
            for (int c = 0; c < 8; ++c)
                *(uint4*)((char*)Xs + ((boff + c * 16) ^ sw)) = sp[c];
        }
        const uint4* wp = (const uint4*)((pass ? whhb : wihb) + (size_t)(g * DD + r) * DD + half * 64);
#pragma unroll
        for (int c = 0; c < 8; ++c)
            *(uint4*)((char*)Ws2 + ((boff + c * 16) ^ sw)) = wp[c];
        __syncthreads();
#pragma unroll
        for (int kc = 0; kc < 4; ++kc) {
            int cb = kc * 64 + lk * 16;
            bf16x8 af[4], bfv[4];
#pragma unroll
            for (int mi = 0; mi < 4; ++mi) {
                int row = wm + mi * 16 + lr;
                af[mi] = *(const bf16x8*)((const char*)Xs + ((row * 256 + cb) ^ ((row & 7) << 4)));
            }
#pragma unroll
            for (int ni = 0; ni < 4; ++ni) {
                int row = wn + ni * 16 + lr;
                bfv[ni] = *(const bf16x8*)((const char*)Ws2 + ((row * 256 + cb) ^ ((row & 7) << 4)));
            }
#pragma unroll
            for (int mi = 0; mi < 4; ++mi)
#pragma unroll
                for (int ni = 0; ni < 4; ++ni)
                    acc[mi][ni] = __builtin_amdgcn_mfma_f32_16x16x32_bf16(af[mi], bfv[ni], acc[mi][ni], 0, 0, 0);
        }
    }
#pragma unroll
    for (int ni = 0; ni < 4; ++ni) {
        int col = wn + ni * 16 + lr;
        float bsum = bih[g * DD + col] + bhh[g * DD + col];
#pragma unroll
        for (int mi = 0; mi < 4; ++mi)
#pragma unroll
            for (int rg = 0; rg < 4; ++rg) {
                int v = m0 + wm + mi * 16 + lk * 4 + rg;
                rz[(size_t)v * 256 + g * DD + col] =
                    (unsigned short)f2b(sigmoidf_(acc[mi][ni][rg] + bsum));
            }
    }
}

// ---------------- MFMA GRU n + combine ----------------

__launch_bounds__(256, 2)
__global__ void k_grun(const float* __restrict__ a, float* __restrict__ h,
                       unsigned short* __restrict__ hbf,
                       const unsigned short* __restrict__ wihb, const unsigned short* __restrict__ whhb,
                       const float* __restrict__ bih, const float* __restrict__ bhh,
                       const unsigned short* __restrict__ rz)
{
    __shared__ __align__(16) unsigned short Xs[128 * 128];
    __shared__ __align__(16) unsigned short Ws2[128 * 128];
    int m0 = blockIdx.x * 128;
    int tid = threadIdx.x;
    int lane = tid & 63, wv = tid >> 6;
    int wm = (wv >> 1) * 64, wn = (wv & 1) * 64;
    int lr = lane & 15, lk = lane >> 4;
    f32x4 acci[4][4], acch[4][4];
#pragma unroll
    for (int i = 0; i < 4; ++i)
#pragma unroll
        for (int j = 0; j < 4; ++j) {
            acci[i][j] = (f32x4){0.f, 0.f, 0.f, 0.f};
            acch[i][j] = (f32x4){0.f, 0.f, 0.f, 0.f};
        }

    int r = tid >> 1, half = tid & 1;
    unsigned boff = r * 256 + half * 128;
    unsigned sw = (r & 7) << 4;
    for (int pass = 0; pass < 2; ++pass) {
        if (pass) __syncthreads();
        if (pass == 0) {
            const float4* sp = (const float4*)(a + (size_t)(m0 + r) * DD + half * 64);
#pragma unroll
            for (int c = 0; c < 8; ++c) {
                float4 v0 = sp[2 * c], v1 = sp[2 * c + 1];
                *(uint4*)((char*)Xs + ((boff + c * 16) ^ sw)) =
                    make_uint4(pk(v0.x, v0.y), pk(v0.z, v0.w), pk(v1.x, v1.y), pk(v1.z, v1.w));
            }
        } else {
            const uint4* sp = (const uint4*)(hbf + (size_t)(m0 + r) * DD + half * 64);
#pragma unroll
            for (int c = 0; c < 8; ++c)
                *(uint4*)((char*)Xs + ((boff + c * 16) ^ sw)) = sp[c];
        }
        const uint4* wp = (const uint4*)((pass ? whhb : wihb) + (size_t)(2 * DD + r) * DD + half * 64);
#pragma unroll
        for (int c = 0; c < 8; ++c)
            *(uint4*)((char*)Ws2 + ((boff + c * 16) ^ sw)) = wp[c];
        __syncthreads();
#pragma unroll
        for (int kc = 0; kc < 4; ++kc) {
            int cb = kc * 64 + lk * 16;
            bf16x8 af[4], bfv[4];
#pragma unroll
            for (int mi = 0; mi < 4; ++mi) {
                int row = wm + mi * 16 + lr;
                af[mi] = *(const bf16x8*)((const char*)Xs + ((row * 256 + cb) ^ ((row & 7) << 4)));
            }
#pragma unroll
            for (int ni = 0; ni < 4; ++ni) {
                int row = wn + ni * 16 + lr;
                bfv[ni] = *(const bf16x8*)((const char*)Ws2 + ((row * 256 + cb) ^ ((row & 7) << 4)));
            }
            if (pass == 0) {
#pragma unroll
                for (int mi = 0; mi < 4; ++mi)
#pragma unroll
                    for (int ni = 0; ni < 4; ++ni)
                        acci[mi][ni] = __builtin_amdgcn_mfma_f32_16x16x32_bf16(af[mi], bfv[ni], acci[mi][ni], 0, 0, 0);
            } else {
#pragma unroll
                for (int mi = 0; mi < 4; ++mi)
#pragma unroll
                    for (int ni = 0; ni < 4; ++ni)
                        acch[mi][ni] = __builtin_amdgcn_mfma_f32_16x16x32_bf16(af[mi], bfv[ni], acch[mi][ni], 0, 0, 0);
            }
        }
    }
#pragma unroll
    for (int ni = 0; ni < 4; ++ni) {
        int col = wn + ni * 16 + lr;
        float bin = bih[2 * DD + col], bhn = bhh[2 * DD + col];
#pragma unroll
        for (int mi = 0; mi < 4; ++mi)
#pragma unroll
            for (int rg = 0; rg < 4; ++rg) {
                int v = m0 + wm + mi * 16 + lk * 4 + rg;
                float rr = b2f(rz[(size_t)v * 256 + col]);
                float zz = b2f(rz[(size_t)v * 256 + 128 + col]);
                float nn = tanhf(acci[mi][ni][rg] + bin + rr * (acch[mi][ni][rg] + bhn));
                float hold = h[(size_t)v * DD + col];
                float hnew = (1.f - zz) * nn + zz * hold;
                h[(size_t)v * DD + col] = hnew;
                hbf[(size_t)v * DD + col] = (unsigned short)f2b(hnew);
            }
    }
}

// ---------------- MFMA conv1(k=3): U1[b][pos][co] = relu(conv+b), unpooled, bf16 ----------------
// A[j][ci](tap k) = x[b][j+k][ci]; W_k[co][ci] = w1p[k][co][ci]. K looped over (k, 64-ci chunks).

template <int CIN>
__launch_bounds__(256, 2)
__global__ void k_conv1m(const unsigned short* __restrict__ hbf, const float* __restrict__ h0,
                         const unsigned short* __restrict__ w1p, const float* __restrict__ bias,
                         unsigned short* __restrict__ U1)
{
    __shared__ __align__(16) unsigned short As[128 * 64];
    __shared__ __align__(16) unsigned short Ws[128 * 64];
    int p0 = blockIdx.x * 128, b = blockIdx.y, n0 = blockIdx.z * 128;
    int tid = threadIdx.x;
    int lane = tid & 63, wv = tid >> 6;
    int wm = (wv >> 1) * 64, wn = (wv & 1) * 64;
    int lr = lane & 15, lk = lane >> 4;
    f32x4 acc[4][4];
#pragma unroll
    for (int i = 0; i < 4; ++i)
#pragma unroll
        for (int j = 0; j < 4; ++j) acc[i][j] = (f32x4){0.f, 0.f, 0.f, 0.f};

    int r = tid >> 1, half = tid & 1;
    unsigned boff = r * 128 + half * 64;       // bytes, 128B rows
    unsigned sw = (r & 7) << 4;
#pragma unroll
    for (int k = 0; k < 3; ++k) {
        for (int c0 = 0; c0 < CIN; c0 += 64) {
            __syncthreads();
            {
                int row = p0 + k + r; if (row > NNODE - 1) row = NNODE - 1;  // clamped rows feed masked pos only
                int ci = c0 + half * 32;
                if (CIN == 128 || ci < 128) {
                    const uint4* sp = (const uint4*)(hbf + ((size_t)(b * NNODE + row)) * DD + ci);
#pragma unroll
                    for (int c = 0; c < 4; ++c)
                        *(uint4*)((char*)As + ((boff + c * 16) ^ sw)) = sp[c];
                } else {
                    const float4* sp = (const float4*)(h0 + ((size_t)(b * NNODE + row)) * DD + (ci - 128));
#pragma unroll
                    for (int c = 0; c < 4; ++c) {
                        float4 v0 = sp[2 * c], v1 = sp[2 * c + 1];
                        *(uint4*)((char*)As + ((boff + c * 16) ^ sw)) =
                            make_uint4(pk(v0.x, v0.y), pk(v0.z, v0.w), pk(v1.x, v1.y), pk(v1.z, v1.w));
                    }
                }
            }
            {
                const uint4* wp = (const uint4*)(w1p + ((size_t)k * CIN + n0 + r) * CIN + c0 + half * 32);
#pragma unroll
                for (int c = 0; c < 4; ++c)
                    *(uint4*)((char*)Ws + ((boff + c * 16) ^ sw)) = wp[c];
            }
            __syncthreads();
#pragma unroll
            for (int kc = 0; kc < 2; ++kc) {
                int cb = kc * 64 + lk * 16;
                bf16x8 af[4], bfv[4];
#pragma unroll
                for (int mi = 0; mi < 4; ++mi) {
                    int row = wm + mi * 16 + lr;
                    af[mi] = *(const bf16x8*)((const char*)As + ((row * 128 + cb) ^ ((row & 7) << 4)));
                }
#pragma unroll
                for (int ni = 0; ni < 4; ++ni) {
                    int row = wn + ni * 16 + lr;
                    bfv[ni] = *(const bf16x8*)((const char*)Ws + ((row * 128 + cb) ^ ((row & 7) << 4)));
                }
#pragma unroll
                for (int mi = 0; mi < 4; ++mi)
#pragma unroll
                    for (int ni = 0; ni < 4; ++ni)
                        acc[mi][ni] = __builtin_amdgcn_mfma_f32_16x16x32_bf16(af[mi], bfv[ni], acc[mi][ni], 0, 0, 0);
            }
        }
    }
#pragma unroll
    for (int ni = 0; ni < 4; ++ni) {
        int co = n0 + wn + ni * 16 + lr;
        float bs = bias[co];
#pragma unroll
        for (int mi = 0; mi < 4; ++mi)
#pragma unroll
            for (int rg = 0; rg < 4; ++rg) {
                int pos = p0 + wm + mi * 16 + lk * 4 + rg;
                if (pos < NNODE - 2) {
                    float v = fmaxf(0.f, acc[mi][ni][rg] + bs);
                    U1[((size_t)b * NNODE + pos) * CIN + co] = (unsigned short)f2b(v);
                }
            }
    }
}

// ---------------- MFMA conv2(k=1): A = pool3(U1) staged on the fly; epilogue pool2 ----------------

template <int CIN>
__launch_bounds__(256, 2)
__global__ void k_conv2m(const unsigned short* __restrict__ U1, const unsigned short* __restrict__ w2b,
                         const float* __restrict__ bias, float* __restrict__ Q)
{
    __shared__ __align__(16) unsigned short As[128 * 64];
    __shared__ __align__(16) unsigned short Ws[128 * 64];
    int m0 = blockIdx.x * 128, b = blockIdx.y, n0 = blockIdx.z * 128;
    int tid = threadIdx.x;
    int lane = tid & 63, wv = tid >> 6;
    int wm = (wv >> 1) * 64, wn = (wv & 1) * 64;
    int lr = lane & 15, lk = lane >> 4;
    f32x4 acc[4][4];
#pragma unroll
    for (int i = 0; i < 4; ++i)
#pragma unroll
        for (int j = 0; j < 4; ++j) acc[i][j] = (f32x4){0.f, 0.f, 0.f, 0.f};

    int r = tid >> 1, half = tid & 1;
    unsigned boff = r * 128 + half * 64;
    unsigned sw = (r & 7) << 4;
    for (int c0 = 0; c0 < CIN; c0 += 64) {
        __syncthreads();
        {
            // pooled[r][ci] = max over d<3 of U1[b][2(m0+r)+d][ci]  (rows clamped; OOB rows feed masked pos)
            int pr = 2 * (m0 + r);
            int r0 = pr, r1 = pr + 1, r2 = pr + 2;
            if (r2 > NNODE - 1) r2 = NNODE - 1;
            if (r1 > NNODE - 1) r1 = NNODE - 1;
            int ci = c0 + half * 32;
            const unsigned short* bp = U1 + (size_t)b * NNODE * CIN + ci;
            const uint4* p0q = (const uint4*)(bp + (size_t)r0 * CIN);
            const uint4* p1q = (const uint4*)(bp + (size_t)r1 * CIN);
            const uint4* p2q = (const uint4*)(bp + (size_t)r2 * CIN);
#pragma unroll
            for (int c = 0; c < 4; ++c) {
                uint4 m = bmax4(bmax4(p0q[c], p1q[c]), p2q[c]);
                *(uint4*)((char*)As + ((boff + c * 16) ^ sw)) = m;
            }
        }
        {
            const uint4* wp = (const uint4*)(w2b + (size_t)(n0 + r) * CIN + c0 + half * 32);
#pragma unroll
            for (int c = 0; c < 4; ++c)
                *(uint4*)((char*)Ws + ((boff + c * 16) ^ sw)) = wp[c];
        }
        __syncthreads();
#pragma unroll
        for (int kc = 0; kc < 2; ++kc) {
            int cb = kc * 64 + lk * 16;
            bf16x8 af[4], bfv[4];
#pragma unroll
            for (int mi = 0; mi < 4; ++mi) {
                int row = wm + mi * 16 + lr;
                af[mi] = *(const bf16x8*)((const char*)As + ((row * 128 + cb) ^ ((row & 7) << 4)));
            }
#pragma unroll
            for (int ni = 0; ni < 4; ++ni) {
                int row = wn + ni * 16 + lr;
                bfv[ni] = *(const bf16x8*)((const char*)Ws + ((row * 128 + cb) ^ ((row & 7) << 4)));
            }
#pragma unroll
            for (int mi = 0; mi < 4; ++mi)
#pragma unroll
                for (int ni = 0; ni < 4; ++ni)
                    acc[mi][ni] = __builtin_amdgcn_mfma_f32_16x16x32_bf16(af[mi], bfv[ni], acc[mi][ni], 0, 0, 0);
        }
    }
    // epilogue: bias+relu, pool(2,2) in-register (lane holds 4 consecutive positions, start even)
#pragma unroll
    for (int ni = 0; ni < 4; ++ni) {
        int co = n0 + wn + ni * 16 + lr;
        float bs = bias[co];
#pragma unroll
        for (int mi = 0; mi < 4; ++mi) {
            int l0 = m0 + wm + mi * 16 + lk * 4;
            float v0 = fmaxf(0.f, acc[mi][ni][0] + bs);
            float v1 = fmaxf(0.f, acc[mi][ni][1] + bs);
            float v2 = fmaxf(0.f, acc[mi][ni][2] + bs);
            float v3 = fmaxf(0.f, acc[mi][ni][3] + bs);
            int jq = l0 >> 1;
            if (jq < 255)     Q[((size_t)b * 255 + jq) * CIN + co]     = fmaxf(v0, v1);
            if (jq + 1 < 255) Q[((size_t)b * 255 + jq + 1) * CIN + co] = fmaxf(v2, v3);
        }
    }
}

// ---------------- final reduction ----------------

__launch_bounds__(256)
__global__ void k_final(const float* __restrict__ QY, const float* __restrict__ QZ,
                        const float* __restrict__ wy, const float* __restrict__ by,
                        const float* __restrict__ wz, const float* __restrict__ bz,
                        float* __restrict__ out)
{
    int b = blockIdx.x, tid = threadIdx.x;
    float p = 0.f;
    if (tid < 255) {
        const float* qy = QY + ((size_t)(b * 255 + tid)) * 128;
        const float* qz = QZ + ((size_t)(b * 255 + tid)) * 256;
        float dy = 0.f, dz = 0.f;
        for (int c = 0; c < 128; c += 4) {
            float4 q = ld4(qy + c), wv = ld4(wy + c);
            dy += q.x * wv.x + q.y * wv.y + q.z * wv.z + q.w * wv.w;
        }
        for (int c = 0; c < 256; c += 4) {
            float4 q = ld4(qz + c), wv = ld4(wz + c);
            dz += q.x * wv.x + q.y * wv.y + q.z * wv.z + q.w * wv.w;
        }
        p = (dy + by[0]) * (dz + bz[0]);
    }
    __shared__ float red[4];
    for (int off = 32; off > 0; off >>= 1) p += __shfl_down(p, off);
    if ((tid & 63) == 0) red[tid >> 6] = p;
    __syncthreads();
    if (tid == 0) {
        float s = red[0] + red[1] + red[2] + red[3];
        out[b] = 1.f / (1.f + expf(-s / 255.f));
    }
}

// ---------------- launch ----------------

extern "C" void kernel_launch(void* const* d_in, const int* in_sizes, int n_in,
                              void* d_out, int out_size, void* d_ws, size_t ws_size,
                              hipStream_t stream)
{
    const float* h_in = (const float*)d_in[0];
    const int* src = (const int*)d_in[1];
    const int* dst = (const int*)d_in[2];
    const int* et  = (const int*)d_in[3];
    const float* Wmsg = (const float*)d_in[4];
    const float* bmsg = (const float*)d_in[5];
    const float* wih = (const float*)d_in[6];
    const float* whh = (const float*)d_in[7];
    const float* bih = (const float*)d_in[8];
    const float* bhh = (const float*)d_in[9];
    const float* c1w = (const float*)d_in[10];
    const float* c1b = (const float*)d_in[11];
    const float* c2w = (const float*)d_in[12];
    const float* c2b = (const float*)d_in[13];
    const float* z1w = (const float*)d_in[14];
    const float* z1b = (const float*)d_in[15];
    const float* z2w = (const float*)d_in[16];
    const float* z2b = (const float*)d_in[17];
    const float* wy  = (const float*)d_in[18];
    const float* by  = (const float*)d_in[19];
    const float* wz  = (const float*)d_in[20];
    const float* bz  = (const float*)d_in[21];
    float* out = (float*)d_out;

    if (ws_size < WS_NEED) return;   // loud failure: output stays poisoned

    char* ws = (char*)d_ws;
    float* hcur = (float*)(ws + OFF_HCUR);
    unsigned short* hbf  = (unsigned short*)(ws + OFF_HBF);
    int*   cnt  = (int*)(ws + OFF_CNT);
    int*   hb   = (int*)(ws + OFF_HB);
    int*   ssrc = (int*)(ws + OFF_SSRC);
    int*   sdst = (int*)(ws + OFF_SDST);
    unsigned short* wmb  = (unsigned short*)(ws + OFF_WMB);
    unsigned short* wihb = (unsigned short*)(ws + OFF_WIHB);
    unsigned short* whhb = (unsigned short*)(ws + OFF_WHHB);
    unsigned short* w1py = (unsigned short*)(ws + OFF_W1PY);
    unsigned short* w1pz = (unsigned short*)(ws + OFF_W1PZ);
    unsigned short* w2yb = (unsigned short*)(ws + OFF_W2YB);
    unsigned short* w2zb = (unsigned short*)(ws + OFF_W2ZB);
    float* a  = (float*)(ws + OFF_A);
    unsigned short* rz = (unsigned short*)(ws + OFF_RZ);
    unsigned short* U1Y = (unsigned short*)(ws + OFF_U1Y);
    unsigned short* U1Z = (unsigned short*)(ws + OFF_U1Z);
    float* QY   = (float*)(ws + OFF_QY);
    float* QZ   = (float*)(ws + OFF_QZ);

    hipMemcpyAsync(hcur, h_in, (size_t)BN * DD * 4, hipMemcpyDeviceToDevice, stream);
    hipMemsetAsync(cnt, 0, (size_t)BN * NT * 4, stream);
    hipMemsetAsync(hb, 0, 256, stream);
    hipMemsetAsync(ssrc, 0, (size_t)SORT_CAP * 4, stream);
    hipMemsetAsync(sdst, 0xFF, (size_t)SORT_CAP * 4, stream);

    k_cvt<<<(BN * DD / 4 + 255) / 256, 256, 0, stream>>>(h_in, hbf, BN * DD / 4);
    k_cvt<<<(NT * DD * DD / 4 + 255) / 256, 256, 0, stream>>>(Wmsg, wmb, NT * DD * DD / 4);
    k_cvt<<<(3 * DD * DD / 4 + 255) / 256, 256, 0, stream>>>(wih, wihb, 3 * DD * DD / 4);
    k_cvt<<<(3 * DD * DD / 4 + 255) / 256, 256, 0, stream>>>(whh, whhb, 3 * DD * DD / 4);
    k_cvt<<<(128 * 128 / 4 + 255) / 256, 256, 0, stream>>>(c2w, w2yb, 128 * 128 / 4);
    k_cvt<<<(256 * 256 / 4 + 255) / 256, 256, 0, stream>>>(z2w, w2zb, 256 * 256 / 4);
    k_packw1<<<(3 * 128 * 128 + 255) / 256, 256, 0, stream>>>(c1w, w1py, 128);
    k_packw1<<<(3 * 256 * 256 + 255) / 256, 256, 0, stream>>>(z1w, w1pz, 256);

    k_hist<<<256, 256, 0, stream>>>(et, dst, hb, cnt);
    k_scan<<<1, 1, 0, stream>>>(hb);
    k_scatter<<<256, 256, 0, stream>>>(src, dst, et, hb, ssrc, sdst);

    for (int s = 0; s < NSTEPS; ++s) {
        k_bvec<<<4096, 256, 0, stream>>>(cnt, bmsg, a);
        k_msg<<<NTILES, 256, 0, stream>>>(ssrc, sdst, hb, hbf, wmb, a);
        k_grurz<<<dim3(BN / 128, 2), 256, 0, stream>>>(a, hbf, wihb, whhb, bih, bhh, rz);
        k_grun<<<BN / 128, 256, 0, stream>>>(a, hcur, hbf, wihb, whhb, bih, bhh, rz);
    }

    k_conv1m<128><<<dim3(8, 32, 1), 256, 0, stream>>>(hbf, h_in, w1py, c1b, U1Y);
    k_conv2m<128><<<dim3(4, 32, 1), 256, 0, stream>>>(U1Y, w2yb, c2b, QY);
    k_conv1m<256><<<dim3(8, 32, 2), 256, 0, stream>>>(hbf, h_in, w1pz, z1b, U1Z);
    k_conv2m<256><<<dim3(4, 32, 2), 256, 0, stream>>>(U1Z, w2zb, z2b, QZ);
    k_final<<<32, 256, 0, stream>>>(QY, QZ, wy, by, wz, bz, out);
}

// Round 5
// 947.511 us; speedup vs baseline: 10.8479x; 1.2872x over previous
//
#include <hip/hip_runtime.h>
#include <math.h>

#define BB 32
#define NNODE 1024
#define BN 32768
#define NE 262144
#define DD 128
#define NT 8
#define NSTEPS 6
#define NBIN 16                      // (dst-half)*8 + etype
#define SORT_CAP (NE + 2048)         // bins padded to 128-edge tiles
#define NTILES_H 2064                // safe upper bound on tiles per half
#define M_CAP (NE / 2 + 16384)       // rows in message buffer (per half)

typedef __attribute__((ext_vector_type(8))) short bf16x8;
typedef __attribute__((ext_vector_type(4))) float f32x4;

static __device__ __forceinline__ float4 ld4(const float* p) { return *(const float4*)p; }
static __device__ __forceinline__ float sigmoidf_(float x) { return 1.f / (1.f + expf(-x)); }
// f32 -> bf16 round-to-nearest-even
static __device__ __forceinline__ unsigned f2b(float f) {
    unsigned u = __float_as_uint(f);
    return (u + 0x7FFFu + ((u >> 16) & 1u)) >> 16;
}
static __device__ __forceinline__ float b2f(unsigned short b) {
    return __uint_as_float(((unsigned)b) << 16);
}
static __device__ __forceinline__ unsigned pk(float a, float b) {
    return f2b(a) | (f2b(b) << 16);
}
// elementwise u16 max of packed pairs (valid ordering for non-negative bf16)
static __device__ __forceinline__ unsigned bmax2(unsigned a, unsigned b) {
    unsigned ah = a & 0xFFFF0000u, bh = b & 0xFFFF0000u;
    unsigned al = a & 0x0000FFFFu, bl = b & 0x0000FFFFu;
    return (ah > bh ? ah : bh) | (al > bl ? al : bl);
}
static __device__ __forceinline__ uint4 bmax4(uint4 a, uint4 b) {
    return make_uint4(bmax2(a.x, b.x), bmax2(a.y, b.y), bmax2(a.z, b.z), bmax2(a.w, b.w));
}

// ---------------- workspace layout (bytes) ----------------
static constexpr size_t OFF_HCUR = 0;                                   // BN*DD f32
static constexpr size_t OFF_HBF  = OFF_HCUR + (size_t)BN * DD * 4;      // BN*DD bf16
static constexpr size_t OFF_CNT  = OFF_HBF  + (size_t)BN * DD * 2;      // BN*NT i32
static constexpr size_t OFF_DEG  = OFF_CNT  + (size_t)BN * NT * 4;      // BN i32
static constexpr size_t OFF_DOFF = OFF_DEG  + (size_t)BN * 4;           // BN i32
static constexpr size_t OFF_DCUR = OFF_DOFF + (size_t)BN * 4;           // BN i32
static constexpr size_t OFF_HB   = OFF_DCUR + (size_t)BN * 4;           // 256 B
static constexpr size_t OFF_SSRC = OFF_HB   + 256;                      // SORT_CAP i32
static constexpr size_t OFF_SDST = OFF_SSRC + (size_t)SORT_CAP * 4;
static constexpr size_t OFF_SQ   = OFF_SDST + (size_t)SORT_CAP * 4;
static constexpr size_t OFF_WMB  = OFF_SQ   + (size_t)SORT_CAP * 4;     // 8*128*128 bf16
static constexpr size_t OFF_WIHB = OFF_WMB  + (size_t)NT * DD * DD * 2;
static constexpr size_t OFF_WHHB = OFF_WIHB + (size_t)3 * DD * DD * 2;
static constexpr size_t OFF_W1PY = OFF_WHHB + (size_t)3 * DD * DD * 2;  // 3*128*128 bf16
static constexpr size_t OFF_W1PZ = OFF_W1PY + (size_t)3 * 128 * 128 * 2;// 3*256*256 bf16
static constexpr size_t OFF_W2YB = OFF_W1PZ + (size_t)3 * 256 * 256 * 2;// 128*128 bf16
static constexpr size_t OFF_W2ZB = OFF_W2YB + (size_t)128 * 128 * 2;    // 256*256 bf16
static constexpr size_t OFF_ABF  = OFF_W2ZB + (size_t)256 * 256 * 2;    // BN*DD bf16
static constexpr size_t OFF_UN   = OFF_ABF  + (size_t)BN * DD * 2;      // union region
// GGNN phase:   m[M_CAP][128] bf16 (37.75 MB); rz[BN][256] bf16 aliases m start (16.8 MB)
static constexpr size_t OFF_M    = OFF_UN;
static constexpr size_t OFF_RZ   = OFF_UN;
// conv phase (after GGNN; aliases m/rz):
static constexpr size_t OFF_U1Y  = OFF_UN;                                 // 32*1024*128 bf16
static constexpr size_t OFF_U1Z  = OFF_U1Y + (size_t)32 * 1024 * 128 * 2;  // 32*1024*256 bf16
static constexpr size_t OFF_QY   = OFF_U1Z + (size_t)32 * 1024 * 256 * 2;  // 32*255*128 f32
static constexpr size_t OFF_QZ   = OFF_QY  + (size_t)32 * 255 * 128 * 4;   // 32*255*256 f32
static constexpr size_t CONV_SZ  = (size_t)32 * 1024 * 128 * 2 + (size_t)32 * 1024 * 256 * 2
                                 + (size_t)32 * 255 * 128 * 4 + (size_t)32 * 255 * 256 * 4;
static constexpr size_t M_SZ     = (size_t)M_CAP * 128 * 2;
static constexpr size_t UN_SZ    = (M_SZ > CONV_SZ ? M_SZ : CONV_SZ);
static constexpr size_t WS_NEED  = OFF_UN + UN_SZ;                         // ~77 MiB

// ---------------- generic f32 -> bf16 converter ----------------
__global__ void k_cvt(const float* __restrict__ s, unsigned short* __restrict__ d, int n4)
{
    int i = blockIdx.x * 256 + threadIdx.x;
    if (i < n4) {
        float4 v = ((const float4*)s)[i];
        ((uint2*)d)[i] = make_uint2(pk(v.x, v.y), pk(v.z, v.w));
    }
}

// pack conv1 weights: wp[k][co][ci] = bf16(w[co][ci][k])
__global__ void k_packw1(const float* __restrict__ w, unsigned short* __restrict__ wp, int C)
{
    int idx = blockIdx.x * 256 + threadIdx.x;
    if (idx < 3 * C * C) {
        int k = idx / (C * C), rem = idx % (C * C);
        wp[idx] = (unsigned short)f2b(w[(size_t)rem * 3 + k]);
    }
}

// ---------------- graph preprocessing ----------------
// hb layout: [0..15] hist, [16..32] aoff (17 entries), [33..48] cur

__global__ void k_hist(const int* __restrict__ et, const int* __restrict__ dst,
                       int* __restrict__ hb, int* __restrict__ cnt)
{
    __shared__ int lh[NBIN];
    int tid = threadIdx.x;
    if (tid < NBIN) lh[tid] = 0;
    __syncthreads();
    int base = blockIdx.x * 1024;
    for (int k = 0; k < 4; ++k) {
        int e = base + tid + k * 256;
        int t = et[e], d = dst[e];
        atomicAdd(&lh[((d >> 14) << 3) | t], 1);
        atomicAdd(&cnt[d * NT + t], 1);
    }
    __syncthreads();
    if (tid < NBIN) atomicAdd(&hb[tid], lh[tid]);
}

__global__ void k_scan(int* hb)
{
    int s = 0;
    for (int t = 0; t < NBIN; ++t) {
        hb[16 + t] = s;
        hb[33 + t] = s;
        s += ((hb[t] + 127) >> 7) << 7;
    }
    hb[32] = s;
}

// deg[v] = sum_t cnt[v][t]; doff = exclusive scan of deg, made local to each dst-half
__global__ void k_degscan(const int* __restrict__ cnt, int* __restrict__ deg,
                          int* __restrict__ doff, int* __restrict__ dcur)
{
    __shared__ int ps[1024];
    __shared__ int shalf;
    int tid = threadIdx.x;            // 1024 threads, 32 nodes each
    int base = tid * 32;
    int local[32];
    int s = 0;
    for (int i = 0; i < 32; ++i) {
        const int* cv = cnt + (size_t)(base + i) * NT;
        int d = 0;
        for (int t = 0; t < NT; ++t) d += cv[t];
        deg[base + i] = d;
        local[i] = s;
        s += d;
    }
    ps[tid] = s;
    __syncthreads();
    for (int off = 1; off < 1024; off <<= 1) {
        int v = 0;
        if (tid >= off) v = ps[tid - off];
        __syncthreads();
        ps[tid] += v;
        __syncthreads();
    }
    if (tid == 511) shalf = ps[511];
    __syncthreads();
    int ex = ps[tid] - s;
    int sub = (base >= BN / 2) ? shalf : 0;
    for (int i = 0; i < 32; ++i) {
        int o = ex + local[i] - sub;
        doff[base + i] = o;
        dcur[base + i] = o;
    }
}

__global__ void k_scatter(const int* __restrict__ src, const int* __restrict__ dst,
                          const int* __restrict__ et, int* __restrict__ hb,
                          int* __restrict__ dcur,
                          int* __restrict__ ssrc, int* __restrict__ sdst, int* __restrict__ sq)
{
    __shared__ int lc[NBIN], lbase[NBIN];
    int tid = threadIdx.x;
    if (tid < NBIN) lc[tid] = 0;
    __syncthreads();
    int base = blockIdx.x * 1024;
    int myk[4], myr[4];
    for (int k = 0; k < 4; ++k) {
        int e = base + tid * 4 + k;
        int kk = ((dst[e] >> 14) << 3) | et[e];
        myk[k] = kk;
        myr[k] = atomicAdd(&lc[kk], 1);
    }
    __syncthreads();
    if (tid < NBIN) lbase[tid] = atomicAdd(&hb[33 + tid], lc[tid]);
    __syncthreads();
    for (int k = 0; k < 4; ++k) {
        int e = base + tid * 4 + k;
        int p = lbase[myk[k]] + myr[k];
        int d = dst[e];
        ssrc[p] = src[e];
        sdst[p] = d;
        sq[p] = atomicAdd(&dcur[d], 1);       // dst-sorted (half-local) position
    }
}

// ---------------- MFMA message pass: 128 same-etype edges -> m rows (no atomics) ----------------
// m[sq[e]][o] = bf16( sum_d hbf[src[e]][d] * Wmsg_bf[t][o][d] )

__launch_bounds__(256, 2)
__global__ void k_msg(const int* __restrict__ ssrc, const int* __restrict__ sdst,
                      const int* __restrict__ sq, const int* __restrict__ hb,
                      const unsigned short* __restrict__ hbf,
                      const unsigned short* __restrict__ wmb,
                      unsigned short* __restrict__ m, int half)
{
    __shared__ __align__(16) unsigned short As[128 * 128];
    __shared__ __align__(16) unsigned short Ws[128 * 128];
    __shared__ int sdl[128], ssl[128], sql[128];
    int hstart = hb[16 + 8 * half], hend = hb[16 + 8 * half + 8];
    int base = hstart + blockIdx.x * 128;
    if (base >= hend) return;                 // uniform
    int t = 0;
#pragma unroll
    for (int i = 1; i < 8; ++i) if (base >= hb[16 + 8 * half + i]) t = i;
    int tid = threadIdx.x;
    if (tid < 128) { sdl[tid] = sdst[base + tid]; ssl[tid] = ssrc[base + tid]; sql[tid] = sq[base + tid]; }
    __syncthreads();
    {
        int r = tid >> 1, halfc = tid & 1;
        const uint4* hp = (const uint4*)(hbf + (size_t)ssl[r] * DD + halfc * 64);
        const uint4* wp = (const uint4*)(wmb + (size_t)t * DD * DD + (size_t)r * DD + halfc * 64);
        unsigned boff = r * 256 + halfc * 128;
        unsigned sw = (r & 7) << 4;
#pragma unroll
        for (int c = 0; c < 8; ++c) {
            unsigned byte = (boff + c * 16) ^ sw;
            *(uint4*)((char*)As + byte) = hp[c];
            *(uint4*)((char*)Ws + byte) = wp[c];
        }
    }
    __syncthreads();
    int lane = tid & 63, wv = tid >> 6;
    int wm = (wv >> 1) * 64, wn = (wv & 1) * 64;
    int lr = lane & 15, lk = lane >> 4;
    f32x4 acc[4][4];
#pragma unroll
    for (int i = 0; i < 4; ++i)
#pragma unroll
        for (int j = 0; j < 4; ++j) acc[i][j] = (f32x4){0.f, 0.f, 0.f, 0.f};
#pragma unroll
    for (int kc = 0; kc < 4; ++kc) {
        int cb = kc * 64 + lk * 16;
        bf16x8 af[4], bfv[4];
#pragma unroll
        for (int mi = 0; mi < 4; ++mi) {
            int row = wm + mi * 16 + lr;
            af[mi] = *(const bf16x8*)((const char*)As + ((row * 256 + cb) ^ ((row & 7) << 4)));
        }
#pragma unroll
        for (int ni = 0; ni < 4; ++ni) {
            int row = wn + ni * 16 + lr;
            bfv[ni] = *(const bf16x8*)((const char*)Ws + ((row * 256 + cb) ^ ((row & 7) << 4)));
        }
#pragma unroll
        for (int mi = 0; mi < 4; ++mi)
#pragma unroll
            for (int ni = 0; ni < 4; ++ni)
                acc[mi][ni] = __builtin_amdgcn_mfma_f32_16x16x32_bf16(af[mi], bfv[ni], acc[mi][ni], 0, 0, 0);
    }
    // epilogue: pack bf16 rows into As (swizzled), then coalesced row writes to m[sq]
    __syncthreads();
#pragma unroll
    for (int mi = 0; mi < 4; ++mi)
#pragma unroll
        for (int ni = 0; ni < 4; ++ni)
#pragma unroll
            for (int rg = 0; rg < 4; ++rg) {
                int er = wm + mi * 16 + lk * 4 + rg;
                int col = wn + ni * 16 + lr;
                unsigned byte = ((unsigned)(er * 256 + col * 2)) ^ ((er & 7) << 4);
                *(unsigned short*)((char*)As + byte) = (unsigned short)f2b(acc[mi][ni][rg]);
            }
    __syncthreads();
    int orow = tid >> 4, ochunk = tid & 15;
#pragma unroll
    for (int pass = 0; pass < 8; ++pass) {
        int row = pass * 16 + orow;
        if (sdl[row] >= 0) {
            uint4 v = *(const uint4*)((const char*)As + (((unsigned)(row * 256 + ochunk * 16)) ^ ((row & 7) << 4)));
            *(uint4*)(m + (size_t)sql[row] * 128 + ochunk * 8) = v;
        }
    }
}

// ---------------- segment-sum: abf[v] = bf16( bias_seed(v) + sum of its message rows ) ----------------

__launch_bounds__(256)
__global__ void k_agg(const unsigned short* __restrict__ m, const int* __restrict__ deg,
                      const int* __restrict__ doff, const int* __restrict__ cnt,
                      const float* __restrict__ bmsg, unsigned short* __restrict__ abf, int half)
{
    __shared__ float bm[NT * DD];
    int tid = threadIdx.x;
    *(float4*)&bm[tid * 4] = ld4(bmsg + tid * 4);   // 256*4 = 1024 = 8*128
    __syncthreads();
    int wv = tid >> 6, lane = tid & 63;
    int v = half * (BN / 2) + blockIdx.x * 4 + wv;
    const int* cv = cnt + (size_t)v * NT;
    float a0 = 0.f, a1 = 0.f;
#pragma unroll
    for (int t = 0; t < NT; ++t) {
        float c = (float)cv[t];
        a0 += c * bm[t * DD + 2 * lane];
        a1 += c * bm[t * DD + 2 * lane + 1];
    }
    int d = deg[v], off = doff[v];
    const unsigned* mr = (const unsigned*)m;
    for (int e = 0; e < d; ++e) {
        unsigned w = mr[(size_t)(off + e) * 64 + lane];
        a0 += b2f((unsigned short)(w & 0xFFFF));
        a1 += b2f((unsigned short)(w >> 16));
    }
    ((unsigned*)abf)[(size_t)v * 64 + lane] = pk(a0, a1);
}

// ---------------- MFMA GRU r,z ----------------

__launch_bounds__(256, 2)
__global__ void k_grurz(const unsigned short* __restrict__ abf, const unsigned short* __restrict__ hbf,
                        const unsigned short* __restrict__ wihb, const unsigned short* __restrict__ whhb,
                        const float* __restrict__ bih, const float* __restrict__ bhh,
                        unsigned short* __restrict__ rz)
{
    __shared__ __align__(16) unsigned short Xs[128 * 128];
    __shared__ __align__(16) unsigned short Ws2[128 * 128];
    int m0 = blockIdx.x * 128;
    int g  = blockIdx.y;                      // 0 = r, 1 = z
    int tid = threadIdx.x;
    int lane = tid & 63, wv = tid >> 6;
    int wm = (wv >> 1) * 64, wn = (wv & 1) * 64;
    int lr = lane & 15, lk = lane >> 4;
    f32x4 acc[4][4];
#pragma unroll
    for (int i = 0; i < 4; ++i)
#pragma unroll
        for (int j = 0; j < 4; ++j) acc[i][j] = (f32x4){0.f, 0.f, 0.f, 0.f};

    int r = tid >> 1, halfc = tid & 1;
    unsigned boff = r * 256 + halfc * 128;
    unsigned sw = (r & 7) << 4;
    for (int pass = 0; pass < 2; ++pass) {
        if (pass) __syncthreads();
        {
            const unsigned short* X = pass ? hbf : abf;
            const uint4* sp = (const uint4*)(X + (size_t)(m0 + r) * DD + halfc * 64);
#pragma unroll
            for (int c = 0; c < 8; ++c)
                *(uint4*)((char*)Xs + ((boff + c * 16) ^ sw)) = sp[c];
        }
        const uint4* wp = (const uint4*)((pass ? whhb : wihb) + (size_t)(g * DD + r) * DD + halfc * 64);
#pragma unroll
        for (int c = 0; c < 8; ++c)
            *(uint4*)((char*)Ws2 + ((boff + c * 16) ^ sw)) = wp[c];
        __syncthreads();
#pragma unroll
        for (int kc = 0; kc < 4; ++kc) {
            int cb = kc * 64 + lk * 16;
            bf16x8 af[4], bfv[4];
#pragma unroll
            for (int mi = 0; mi < 4; ++mi) {
                int row = wm + mi * 16 + lr;
                af[mi] = *(const bf16x8*)((const char*)Xs + ((row * 256 + cb) ^ ((row & 7) << 4)));
            }
#pragma unroll
            for (int ni = 0; ni < 4; ++ni) {
                int row = wn + ni * 16 + lr;
                bfv[ni] = *(const bf16x8*)((const char*)Ws2 + ((row * 256 + cb) ^ ((row & 7) << 4)));
            }
#pragma unroll
            for (int mi = 0; mi < 4; ++mi)
#pragma unroll
                for (int ni = 0; ni < 4; ++ni)
                    acc[mi][ni] = __builtin_amdgcn_mfma_f32_16x16x32_bf16(af[mi], bfv[ni], acc[mi][ni], 0, 0, 0);
        }
    }
#pragma unroll
    for (int ni = 0; ni < 4; ++ni) {
        int col = wn + ni * 16 + lr;
        float bsum = bih[g * DD + col] + bhh[g * DD + col];
#pragma unroll
        for (int mi = 0; mi < 4; ++mi)
#pragma unroll
            for (int rg = 0; rg < 4; ++rg) {
                int v = m0 + wm + mi * 16 + lk * 4 + rg;
                rz[(size_t)v * 256 + g * DD + col] =
                    (unsigned short)f2b(sigmoidf_(acc[mi][ni][rg] + bsum));
            }
    }
}

// ---------------- MFMA GRU n + combine ----------------

__launch_bounds__(256, 2)
__global__ void k_grun(const unsigned short* __restrict__ abf, float* __restrict__ h,
                       unsigned short* __restrict__ hbf,
                       const unsigned short* __restrict__ wihb, const unsigned short* __restrict__ whhb,
                       const float* __restrict__ bih, const float* __restrict__ bhh,
                       const unsigned short* __restrict__ rz)
{
    __shared__ __align__(16) unsigned short Xs[128 * 128];
    __shared__ __align__(16) unsigned short Ws2[128 * 128];
    int m0 = blockIdx.x * 128;
    int tid = threadIdx.x;
    int lane = tid & 63, wv = tid >> 6;
    int wm = (wv >> 1) * 64, wn = (wv & 1) * 64;
    int lr = lane & 15, lk = lane >> 4;
    f32x4 acci[4][4], acch[4][4];
#pragma unroll
    for (int i = 0; i < 4; ++i)
#pragma unroll
        for (int j = 0; j < 4; ++j) {
            acci[i][j] = (f32x4){0.f, 0.f, 0.f, 0.f};
            acch[i][j] = (f32x4){0.f, 0.f, 0.f, 0.f};
        }

    int r = tid >> 1, halfc = tid & 1;
    unsigned boff = r * 256 + halfc * 128;
    unsigned sw = (r & 7) << 4;
    for (int pass = 0; pass < 2; ++pass) {
        if (pass) __syncthreads();
        {
            const unsigned short* X = pass ? hbf : abf;
            const uint4* sp = (const uint4*)(X + (size_t)(m0 + r) * DD + halfc * 64);
#pragma unroll
            for (int c = 0; c < 8; ++c)
                *(uint4*)((char*)Xs + ((boff + c * 16) ^ sw)) = sp[c];
        }
        const uint4* wp = (const uint4*)((pass ? whhb : wihb) + (size_t)(2 * DD + r) * DD + halfc * 64);
#pragma unroll
        for (int c = 0; c < 8; ++c)
            *(uint4*)((char*)Ws2 + ((boff + c * 16) ^ sw)) = wp[c];
        __syncthreads();
#pragma unroll
        for (int kc = 0; kc < 4; ++kc) {
            int cb = kc * 64 + lk * 16;
            bf16x8 af[4], bfv[4];
#pragma unroll
            for (int mi = 0; mi < 4; ++mi) {
                int row = wm + mi * 16 + lr;
                af[mi] = *(const bf16x8*)((const char*)Xs + ((row * 256 + cb) ^ ((row & 7) << 4)));
            }
#pragma unroll
            for (int ni = 0; ni < 4; ++ni) {
                int row = wn + ni * 16 + lr;
                bfv[ni] = *(const bf16x8*)((const char*)Ws2 + ((row * 256 + cb) ^ ((row & 7) << 4)));
            }
            if (pass == 0) {
#pragma unroll
                for (int mi = 0; mi < 4; ++mi)
#pragma unroll
                    for (int ni = 0; ni < 4; ++ni)
                        acci[mi][ni] = __builtin_amdgcn_mfma_f32_16x16x32_bf16(af[mi], bfv[ni], acci[mi][ni], 0, 0, 0);
            } else {
#pragma unroll
                for (int mi = 0; mi < 4; ++mi)
#pragma unroll
                    for (int ni = 0; ni < 4; ++ni)
                        acch[mi][ni] = __builtin_amdgcn_mfma_f32_16x16x32_bf16(af[mi], bfv[ni], acch[mi][ni], 0, 0, 0);
            }
        }
    }
#pragma unroll
    for (int ni = 0; ni < 4; ++ni) {
        int col = wn + ni * 16 + lr;
        float bin = bih[2 * DD + col], bhn = bhh[2 * DD + col];
#pragma unroll
        for (int mi = 0; mi < 4; ++mi)
#pragma unroll
            for (int rg = 0; rg < 4; ++rg) {
                int v = m0 + wm + mi * 16 + lk * 4 + rg;
                float rr = b2f(rz[(size_t)v * 256 + col]);
                float zz = b2f(rz[(size_t)v * 256 + 128 + col]);
                float nn = tanhf(acci[mi][ni][rg] + bin + rr * (acch[mi][ni][rg] + bhn));
                float hold = h[(size_t)v * DD + col];
                float hnew = (1.f - zz) * nn + zz * hold;
                h[(size_t)v * DD + col] = hnew;
                hbf[(size_t)v * DD + col] = (unsigned short)f2b(hnew);
            }
    }
}

// ---------------- MFMA conv1(k=3): U1[b][pos][co] = relu(conv+b), unpooled, bf16 ----------------

template <int CIN>
__launch_bounds__(256, 2)
__global__ void k_conv1m(const unsigned short* __restrict__ hbf, const float* __restrict__ h0,
                         const unsigned short* __restrict__ w1p, const float* __restrict__ bias,
                         unsigned short* __restrict__ U1)
{
    __shared__ __align__(16) unsigned short As[128 * 64];
    __shared__ __align__(16) unsigned short Ws[128 * 64];
    int p0 = blockIdx.x * 128, b = blockIdx.y, n0 = blockIdx.z * 128;
    int tid = threadIdx.x;
    int lane = tid & 63, wv = tid >> 6;
    int wm = (wv >> 1) * 64, wn = (wv & 1) * 64;
    int lr = lane & 15, lk = lane >> 4;
    f32x4 acc[4][4];
#pragma unroll
    for (int i = 0; i < 4; ++i)
#pragma unroll
        for (int j = 0; j < 4; ++j) acc[i][j] = (f32x4){0.f, 0.f, 0.f, 0.f};

    int r = tid >> 1, halfc = tid & 1;
    unsigned boff = r * 128 + halfc * 64;
    unsigned sw = (r & 7) << 4;
#pragma unroll
    for (int k = 0; k < 3; ++k) {
        for (int c0 = 0; c0 < CIN; c0 += 64) {
            __syncthreads();
            {
                int row = p0 + k + r; if (row > NNODE - 1) row = NNODE - 1;
                int ci = c0 + halfc * 32;
                if (CIN == 128 || ci < 128) {
                    const uint4* sp = (const uint4*)(hbf + ((size_t)(b * NNODE + row)) * DD + ci);
#pragma unroll
                    for (int c = 0; c < 4; ++c)
                        *(uint4*)((char*)As + ((boff + c * 16) ^ sw)) = sp[c];
                } else {
                    const float4* sp = (const float4*)(h0 + ((size_t)(b * NNODE + row)) * DD + (ci - 128));
#pragma unroll
                    for (int c = 0; c < 4; ++c) {
                        float4 v0 = sp[2 * c], v1 = sp[2 * c + 1];
                        *(uint4*)((char*)As + ((boff + c * 16) ^ sw)) =
                            make_uint4(pk(v0.x, v0.y), pk(v0.z, v0.w), pk(v1.x, v1.y), pk(v1.z, v1.w));
                    }
                }
            }
            {
                const uint4* wp = (const uint4*)(w1p + ((size_t)k * CIN + n0 + r) * CIN + c0 + halfc * 32);
#pragma unroll
                for (int c = 0; c < 4; ++c)
                    *(uint4*)((char*)Ws + ((boff + c * 16) ^ sw)) = wp[c];
            }
            __syncthreads();
#pragma unroll
            for (int kc = 0; kc < 2; ++kc) {
                int cb = kc * 64 + lk * 16;
                bf16x8 af[4], bfv[4];
#pragma unroll
                for (int mi = 0; mi < 4; ++mi) {
                    int row = wm + mi * 16 + lr;
                    af[mi] = *(const bf16x8*)((const char*)As + ((row * 128 + cb) ^ ((row & 7) << 4)));
                }
#pragma unroll
                for (int ni = 0; ni < 4; ++ni) {
                    int row = wn + ni * 16 + lr;
                    bfv[ni] = *(const bf16x8*)((const char*)Ws + ((row * 128 + cb) ^ ((row & 7) << 4)));
                }
#pragma unroll
                for (int mi = 0; mi < 4; ++mi)
#pragma unroll
                    for (int ni = 0; ni < 4; ++ni)
                        acc[mi][ni] = __builtin_amdgcn_mfma_f32_16x16x32_bf16(af[mi], bfv[ni], acc[mi][ni], 0, 0, 0);
            }
        }
    }
#pragma unroll
    for (int ni = 0; ni < 4; ++ni) {
        int co = n0 + wn + ni * 16 + lr;
        float bs = bias[co];
#pragma unroll
        for (int mi = 0; mi < 4; ++mi)
#pragma unroll
            for (int rg = 0; rg < 4; ++rg) {
                int pos = p0 + wm + mi * 16 + lk * 4 + rg;
                if (pos < NNODE - 2) {
                    float v = fmaxf(0.f, acc[mi][ni][rg] + bs);
                    U1[((size_t)b * NNODE + pos) * CIN + co] = (unsigned short)f2b(v);
                }
            }
    }
}

// ---------------- MFMA conv2(k=1): A = pool3(U1) on the fly; epilogue pool2 ----------------

template <int CIN>
__launch_bounds__(256, 2)
__global__ void k_conv2m(const unsigned short* __restrict__ U1, const unsigned short* __restrict__ w2b,
                         const float* __restrict__ bias, float* __restrict__ Q)
{
    __shared__ __align__(16) unsigned short As[128 * 64];
    __shared__ __align__(16) unsigned short Ws[128 * 64];
    int m0 = blockIdx.x * 128, b = blockIdx.y, n0 = blockIdx.z * 128;
    int tid = threadIdx.x;
    int lane = tid & 63, wv = tid >> 6;
    int wm = (wv >> 1) * 64, wn = (wv & 1) * 64;
    int lr = lane & 15, lk = lane >> 4;
    f32x4 acc[4][4];
#pragma unroll
    for (int i = 0; i < 4; ++i)
#pragma unroll
        for (int j = 0; j < 4; ++j) acc[i][j] = (f32x4){0.f, 0.f, 0.f, 0.f};

    int r = tid >> 1, halfc = tid & 1;
    unsigned boff = r * 128 + halfc * 64;
    unsigned sw = (r & 7) << 4;
    for (int c0 = 0; c0 < CIN; c0 += 64) {
        __syncthreads();
        {
            int pr = 2 * (m0 + r);
            int r0 = pr, r1 = pr + 1, r2 = pr + 2;
            if (r2 > NNODE - 1) r2 = NNODE - 1;
            if (r1 > NNODE - 1) r1 = NNODE - 1;
            int ci = c0 + halfc * 32;
            const unsigned short* bp = U1 + (size_t)b * NNODE * CIN + ci;
            const uint4* p0q = (const uint4*)(bp + (size_t)r0 * CIN);
            const uint4* p1q = (const uint4*)(bp + (size_t)r1 * CIN);
            const uint4* p2q = (const uint4*)(bp + (size_t)r2 * CIN);
#pragma unroll
            for (int c = 0; c < 4; ++c) {
                uint4 mm = bmax4(bmax4(p0q[c], p1q[c]), p2q[c]);
                *(uint4*)((char*)As + ((boff + c * 16) ^ sw)) = mm;
            }
        }
        {
            const uint4* wp = (const uint4*)(w2b + (size_t)(n0 + r) * CIN + c0 + halfc * 32);
#pragma unroll
            for (int c = 0; c < 4; ++c)
                *(uint4*)((char*)Ws + ((boff + c * 16) ^ sw)) = wp[c];
        }
        __syncthreads();
#pragma unroll
        for (int kc = 0; kc < 2; ++kc) {
            int cb = kc * 64 + lk * 16;
            bf16x8 af[4], bfv[4];
#pragma unroll
            for (int mi = 0; mi < 4; ++mi) {
                int row = wm + mi * 16 + lr;
                af[mi] = *(const bf16x8*)((const char*)As + ((row * 128 + cb) ^ ((row & 7) << 4)));
            }
#pragma unroll
            for (int ni = 0; ni < 4; ++ni) {
                int row = wn + ni * 16 + lr;
                bfv[ni] = *(const bf16x8*)((const char*)Ws + ((row * 128 + cb) ^ ((row & 7) << 4)));
            }
#pragma unroll
            for (int mi = 0; mi < 4; ++mi)
#pragma unroll
                for (int ni = 0; ni < 4; ++ni)
                    acc[mi][ni] = __builtin_amdgcn_mfma_f32_16x16x32_bf16(af[mi], bfv[ni], acc[mi][ni], 0, 0, 0);
        }
    }
#pragma unroll
    for (int ni = 0; ni < 4; ++ni) {
        int co = n0 + wn + ni * 16 + lr;
        float bs = bias[co];
#pragma unroll
        for (int mi = 0; mi < 4; ++mi) {
            int l0 = m0 + wm + mi * 16 + lk * 4;
            float v0 = fmaxf(0.f, acc[mi][ni][0] + bs);
            float v1 = fmaxf(0.f, acc[mi][ni][1] + bs);
            float v2 = fmaxf(0.f, acc[mi][ni][2] + bs);
            float v3 = fmaxf(0.f, acc[mi][ni][3] + bs);
            int jq = l0 >> 1;
            if (jq < 255)     Q[((size_t)b * 255 + jq) * CIN + co]     = fmaxf(v0, v1);
            if (jq + 1 < 255) Q[((size_t)b * 255 + jq + 1) * CIN + co] = fmaxf(v2, v3);
        }
    }
}

// ---------------- final reduction ----------------

__launch_bounds__(256)
__global__ void k_final(const float* __restrict__ QY, const float* __restrict__ QZ,
                        const float* __restrict__ wy, const float* __restrict__ by,
                        const float* __restrict__ wz, const float* __restrict__ bz,
                        float* __restrict__ out)
{
    int b = blockIdx.x, tid = threadIdx.x;
    float p = 0.f;
    if (tid < 255) {
        const float* qy = QY + ((size_t)(b * 255 + tid)) * 128;
        const float* qz = QZ + ((size_t)(b * 255 + tid)) * 256;
        float dy = 0.f, dz = 0.f;
        for (int c = 0; c < 128; c += 4) {
            float4 q = ld4(qy + c), wv = ld4(wy + c);
            dy += q.x * wv.x + q.y * wv.y + q.z * wv.z + q.w * wv.w;
        }
        for (int c = 0; c < 256; c += 4) {
            float4 q = ld4(qz + c), wv = ld4(wz + c);
            dz += q.x * wv.x + q.y * wv.y + q.z * wv.z + q.w * wv.w;
        }
        p = (dy + by[0]) * (dz + bz[0]);
    }
    __shared__ float red[4];
    for (int off = 32; off > 0; off >>= 1) p += __shfl_down(p, off);
    if ((tid & 63) == 0) red[tid >> 6] = p;
    __syncthreads();
    if (tid == 0) {
        float s = red[0] + red[1] + red[2] + red[3];
        out[b] = 1.f / (1.f + expf(-s / 255.f));
    }
}

// ---------------- launch ----------------

extern "C" void kernel_launch(void* const* d_in, const int* in_sizes, int n_in,
                              void* d_out, int out_size, void* d_ws, size_t ws_size,
                              hipStream_t stream)
{
    const float* h_in = (const float*)d_in[0];
    const int* src = (const int*)d_in[1];
    const int* dst = (const int*)d_in[2];
    const int* et  = (const int*)d_in[3];
    const float* Wmsg = (const float*)d_in[4];
    const float* bmsg = (const float*)d_in[5];
    const float* wih = (const float*)d_in[6];
    const float* whh = (const float*)d_in[7];
    const float* bih = (const float*)d_in[8];
    const float* bhh = (const float*)d_in[9];
    const float* c1w = (const float*)d_in[10];
    const float* c1b = (const float*)d_in[11];
    const float* c2w = (const float*)d_in[12];
    const float* c2b = (const float*)d_in[13];
    const float* z1w = (const float*)d_in[14];
    const float* z1b = (const float*)d_in[15];
    const float* z2w = (const float*)d_in[16];
    const float* z2b = (const float*)d_in[17];
    const float* wy  = (const float*)d_in[18];
    const float* by  = (const float*)d_in[19];
    const float* wz  = (const float*)d_in[20];
    const float* bz  = (const float*)d_in[21];
    float* out = (float*)d_out;

    if (ws_size < WS_NEED) return;   // loud failure: output stays poisoned

    char* ws = (char*)d_ws;
    float* hcur = (float*)(ws + OFF_HCUR);
    unsigned short* hbf  = (unsigned short*)(ws + OFF_HBF);
    int*   cnt  = (int*)(ws + OFF_CNT);
    int*   deg  = (int*)(ws + OFF_DEG);
    int*   doff = (int*)(ws + OFF_DOFF);
    int*   dcur = (int*)(ws + OFF_DCUR);
    int*   hb   = (int*)(ws + OFF_HB);
    int*   ssrc = (int*)(ws + OFF_SSRC);
    int*   sdst = (int*)(ws + OFF_SDST);
    int*   sq   = (int*)(ws + OFF_SQ);
    unsigned short* wmb  = (unsigned short*)(ws + OFF_WMB);
    unsigned short* wihb = (unsigned short*)(ws + OFF_WIHB);
    unsigned short* whhb = (unsigned short*)(ws + OFF_WHHB);
    unsigned short* w1py = (unsigned short*)(ws + OFF_W1PY);
    unsigned short* w1pz = (unsigned short*)(ws + OFF_W1PZ);
    unsigned short* w2yb = (unsigned short*)(ws + OFF_W2YB);
    unsigned short* w2zb = (unsigned short*)(ws + OFF_W2ZB);
    unsigned short* abf  = (unsigned short*)(ws + OFF_ABF);
    unsigned short* mbuf = (unsigned short*)(ws + OFF_M);
    unsigned short* rz   = (unsigned short*)(ws + OFF_RZ);
    unsigned short* U1Y  = (unsigned short*)(ws + OFF_U1Y);
    unsigned short* U1Z  = (unsigned short*)(ws + OFF_U1Z);
    float* QY   = (float*)(ws + OFF_QY);
    float* QZ   = (float*)(ws + OFF_QZ);

    hipMemcpyAsync(hcur, h_in, (size_t)BN * DD * 4, hipMemcpyDeviceToDevice, stream);
    hipMemsetAsync(cnt, 0, (size_t)BN * NT * 4, stream);
    hipMemsetAsync(hb, 0, 256, stream);
    hipMemsetAsync(ssrc, 0, (size_t)SORT_CAP * 4, stream);
    hipMemsetAsync(sdst, 0xFF, (size_t)SORT_CAP * 4, stream);

    k_cvt<<<(BN * DD / 4 + 255) / 256, 256, 0, stream>>>(h_in, hbf, BN * DD / 4);
    k_cvt<<<(NT * DD * DD / 4 + 255) / 256, 256, 0, stream>>>(Wmsg, wmb, NT * DD * DD / 4);
    k_cvt<<<(3 * DD * DD / 4 + 255) / 256, 256, 0, stream>>>(wih, wihb, 3 * DD * DD / 4);
    k_cvt<<<(3 * DD * DD / 4 + 255) / 256, 256, 0, stream>>>(whh, whhb, 3 * DD * DD / 4);
    k_cvt<<<(128 * 128 / 4 + 255) / 256, 256, 0, stream>>>(c2w, w2yb, 128 * 128 / 4);
    k_cvt<<<(256 * 256 / 4 + 255) / 256, 256, 0, stream>>>(z2w, w2zb, 256 * 256 / 4);
    k_packw1<<<(3 * 128 * 128 + 255) / 256, 256, 0, stream>>>(c1w, w1py, 128);
    k_packw1<<<(3 * 256 * 256 + 255) / 256, 256, 0, stream>>>(z1w, w1pz, 256);

    k_hist<<<256, 256, 0, stream>>>(et, dst, hb, cnt);
    k_scan<<<1, 1, 0, stream>>>(hb);
    k_degscan<<<1, 1024, 0, stream>>>(cnt, deg, doff, dcur);
    k_scatter<<<256, 256, 0, stream>>>(src, dst, et, hb, dcur, ssrc, sdst, sq);

    for (int s = 0; s < NSTEPS; ++s) {
        for (int half = 0; half < 2; ++half) {
            k_msg<<<NTILES_H, 256, 0, stream>>>(ssrc, sdst, sq, hb, hbf, wmb, mbuf, half);
            k_agg<<<BN / 2 / 4, 256, 0, stream>>>(mbuf, deg, doff, cnt, bmsg, abf, half);
        }
        k_grurz<<<dim3(BN / 128, 2), 256, 0, stream>>>(abf, hbf, wihb, whhb, bih, bhh, rz);
        k_grun<<<BN / 128, 256, 0, stream>>>(abf, hcur, hbf, wihb, whhb, bih, bhh, rz);
    }

    k_conv1m<128><<<dim3(8, 32, 1), 256, 0, stream>>>(hbf, h_in, w1py, c1b, U1Y);
    k_conv2m<128><<<dim3(4, 32, 1), 256, 0, stream>>>(U1Y, w2yb, c2b, QY);
    k_conv1m<256><<<dim3(8, 32, 2), 256, 0, stream>>>(hbf, h_in, w1pz, z1b, U1Z);
    k_conv2m<256><<<dim3(4, 32, 2), 256, 0, stream>>>(U1Z, w2zb, z2b, QZ);
    k_final<<<32, 256, 0, stream>>>(QY, QZ, wy, by, wz, bz, out);
}

// Round 6
// 725.548 us; speedup vs baseline: 14.1665x; 1.3059x over previous
//
#include <hip/hip_runtime.h>
#include <math.h>

#define BB 32
#define NNODE 1024
#define BN 32768
#define NE 262144
#define DD 128
#define NT 8
#define NSTEPS 6
#define NBIN 16                      // (dst-half)*8 + etype
#define SORT_CAP (NE + 2048)         // bins padded to 128-edge tiles
#define NTILES_H 1152                // >= max tiles per half (131072/128 + slack)
#define M_CAP (NE / 2 + 16384)       // rows in message buffer (per half)

typedef __attribute__((ext_vector_type(8))) short bf16x8;
typedef __attribute__((ext_vector_type(4))) float f32x4;

static __device__ __forceinline__ float4 ld4(const float* p) { return *(const float4*)p; }
static __device__ __forceinline__ float sigmoidf_(float x) { return 1.f / (1.f + expf(-x)); }
// f32 -> bf16 round-to-nearest-even
static __device__ __forceinline__ unsigned f2b(float f) {
    unsigned u = __float_as_uint(f);
    return (u + 0x7FFFu + ((u >> 16) & 1u)) >> 16;
}
static __device__ __forceinline__ float b2f(unsigned short b) {
    return __uint_as_float(((unsigned)b) << 16);
}
static __device__ __forceinline__ unsigned pk(float a, float b) {
    return f2b(a) | (f2b(b) << 16);
}
// elementwise u16 max of packed pairs (valid ordering for non-negative bf16)
static __device__ __forceinline__ unsigned bmax2(unsigned a, unsigned b) {
    unsigned ah = a & 0xFFFF0000u, bh = b & 0xFFFF0000u;
    unsigned al = a & 0x0000FFFFu, bl = b & 0x0000FFFFu;
    return (ah > bh ? ah : bh) | (al > bl ? al : bl);
}
static __device__ __forceinline__ uint4 bmax4(uint4 a, uint4 b) {
    return make_uint4(bmax2(a.x, b.x), bmax2(a.y, b.y), bmax2(a.z, b.z), bmax2(a.w, b.w));
}

// ---------------- workspace layout (bytes) ----------------
static constexpr size_t OFF_HCUR = 0;                                   // BN*DD f32
static constexpr size_t OFF_HBF  = OFF_HCUR + (size_t)BN * DD * 4;      // BN*DD bf16
static constexpr size_t OFF_CNT  = OFF_HBF  + (size_t)BN * DD * 2;      // BN*NT i32
static constexpr size_t OFF_DEG  = OFF_CNT  + (size_t)BN * NT * 4;      // BN i32
static constexpr size_t OFF_DOFF = OFF_DEG  + (size_t)BN * 4;           // BN i32
static constexpr size_t OFF_DCUR = OFF_DOFF + (size_t)BN * 4;           // BN i32
static constexpr size_t OFF_DBLK = OFF_DCUR + (size_t)BN * 4;           // 512 B
static constexpr size_t OFF_HB   = OFF_DBLK + 512;                      // 256 B
static constexpr size_t OFF_SSRC = OFF_HB   + 256;                      // SORT_CAP i32
static constexpr size_t OFF_SDST = OFF_SSRC + (size_t)SORT_CAP * 4;
static constexpr size_t OFF_SQ   = OFF_SDST + (size_t)SORT_CAP * 4;
static constexpr size_t OFF_WMB  = OFF_SQ   + (size_t)SORT_CAP * 4;     // 8*128*128 bf16
static constexpr size_t OFF_WIHB = OFF_WMB  + (size_t)NT * DD * DD * 2;
static constexpr size_t OFF_WHHB = OFF_WIHB + (size_t)3 * DD * DD * 2;
static constexpr size_t OFF_W1PY = OFF_WHHB + (size_t)3 * DD * DD * 2;  // 3*128*128 bf16
static constexpr size_t OFF_W1PZ = OFF_W1PY + (size_t)3 * 128 * 128 * 2;// 3*256*256 bf16
static constexpr size_t OFF_W2YB = OFF_W1PZ + (size_t)3 * 256 * 256 * 2;// 128*128 bf16
static constexpr size_t OFF_W2ZB = OFF_W2YB + (size_t)128 * 128 * 2;    // 256*256 bf16
static constexpr size_t OFF_ABF  = OFF_W2ZB + (size_t)256 * 256 * 2;    // BN*DD bf16
static constexpr size_t OFF_UN   = OFF_ABF  + (size_t)BN * DD * 2;      // union region
// GGNN phase:   m[M_CAP][128] bf16 (37.75 MB)
static constexpr size_t OFF_M    = OFF_UN;
// conv phase (after GGNN; aliases m):
static constexpr size_t OFF_U1Y  = OFF_UN;                                 // 32*1024*128 bf16
static constexpr size_t OFF_U1Z  = OFF_U1Y + (size_t)32 * 1024 * 128 * 2;  // 32*1024*256 bf16
static constexpr size_t OFF_QY   = OFF_U1Z + (size_t)32 * 1024 * 256 * 2;  // 32*255*128 f32
static constexpr size_t OFF_QZ   = OFF_QY  + (size_t)32 * 255 * 128 * 4;   // 32*255*256 f32
static constexpr size_t CONV_SZ  = (size_t)32 * 1024 * 128 * 2 + (size_t)32 * 1024 * 256 * 2
                                 + (size_t)32 * 255 * 128 * 4 + (size_t)32 * 255 * 256 * 4;
static constexpr size_t M_SZ     = (size_t)M_CAP * 128 * 2;
static constexpr size_t UN_SZ    = (M_SZ > CONV_SZ ? M_SZ : CONV_SZ);
static constexpr size_t WS_NEED  = OFF_UN + UN_SZ;                         // ~77 MiB

// ---------------- mega prep kernel: copies/converts/zeros everything ----------------
// block ranges: [0,4096) hcur+hbf | [4096,4224) wmb | [4224,4272) wihb | [4272,4320) whhb
// [4320,4336) w2yb | [4336,4400) w2zb | [4400,4592) w1py | [4592,5360) w1pz
// [5360,5616) cnt=0 | [5616,5617) hb=0 | [5617,5875) ssrc=0 | [5875,6133) sdst=-1
#define PREP_BLOCKS 6133
__global__ void k_prep(const float* __restrict__ h_in, float* __restrict__ hcur,
                       unsigned short* __restrict__ hbf,
                       const float* __restrict__ Wmsg, unsigned short* __restrict__ wmb,
                       const float* __restrict__ wih, unsigned short* __restrict__ wihb,
                       const float* __restrict__ whh, unsigned short* __restrict__ whhb,
                       const float* __restrict__ c2w, unsigned short* __restrict__ w2yb,
                       const float* __restrict__ z2w, unsigned short* __restrict__ w2zb,
                       const float* __restrict__ c1w, unsigned short* __restrict__ w1py,
                       const float* __restrict__ z1w, unsigned short* __restrict__ w1pz,
                       int* __restrict__ cnt, int* __restrict__ hb,
                       int* __restrict__ ssrc, int* __restrict__ sdst)
{
    int blk = blockIdx.x, tid = threadIdx.x;
    if (blk < 4096) {
        int i = blk * 256 + tid;
        float4 v = ((const float4*)h_in)[i];
        ((float4*)hcur)[i] = v;
        ((uint2*)hbf)[i] = make_uint2(pk(v.x, v.y), pk(v.z, v.w));
    } else if (blk < 4224) {
        int i = (blk - 4096) * 256 + tid;
        float4 v = ((const float4*)Wmsg)[i];
        ((uint2*)wmb)[i] = make_uint2(pk(v.x, v.y), pk(v.z, v.w));
    } else if (blk < 4272) {
        int i = (blk - 4224) * 256 + tid;
        float4 v = ((const float4*)wih)[i];
        ((uint2*)wihb)[i] = make_uint2(pk(v.x, v.y), pk(v.z, v.w));
    } else if (blk < 4320) {
        int i = (blk - 4272) * 256 + tid;
        float4 v = ((const float4*)whh)[i];
        ((uint2*)whhb)[i] = make_uint2(pk(v.x, v.y), pk(v.z, v.w));
    } else if (blk < 4336) {
        int i = (blk - 4320) * 256 + tid;
        float4 v = ((const float4*)c2w)[i];
        ((uint2*)w2yb)[i] = make_uint2(pk(v.x, v.y), pk(v.z, v.w));
    } else if (blk < 4400) {
        int i = (blk - 4336) * 256 + tid;
        float4 v = ((const float4*)z2w)[i];
        ((uint2*)w2zb)[i] = make_uint2(pk(v.x, v.y), pk(v.z, v.w));
    } else if (blk < 4592) {
        int g = (blk - 4400) * 256 + tid;          // < 3*128*128
        int k = g >> 14, rem = g & 16383;
        w1py[g] = (unsigned short)f2b(c1w[(size_t)rem * 3 + k]);
    } else if (blk < 5360) {
        int g = (blk - 4592) * 256 + tid;          // < 3*256*256
        int k = g >> 16, rem = g & 65535;
        w1pz[g] = (unsigned short)f2b(z1w[(size_t)rem * 3 + k]);
    } else if (blk < 5616) {
        ((uint4*)cnt)[(blk - 5360) * 256 + tid] = make_uint4(0, 0, 0, 0);
    } else if (blk < 5617) {
        if (tid < 64) hb[tid] = 0;
    } else if (blk < 5875) {
        ((uint4*)ssrc)[(blk - 5617) * 256 + tid] = make_uint4(0, 0, 0, 0);
    } else {
        ((uint4*)sdst)[(blk - 5875) * 256 + tid] = make_uint4(~0u, ~0u, ~0u, ~0u);
    }
}

// ---------------- graph preprocessing ----------------
// hb layout: [0..15] hist, [16..32] aoff (17 entries), [33..48] cur

__global__ void k_hist(const int* __restrict__ et, const int* __restrict__ dst,
                       int* __restrict__ hb, int* __restrict__ cnt)
{
    __shared__ int lh[NBIN];
    int tid = threadIdx.x;
    if (tid < NBIN) lh[tid] = 0;
    __syncthreads();
    int base = blockIdx.x * 1024;
    for (int k = 0; k < 4; ++k) {
        int e = base + tid + k * 256;
        int t = et[e], d = dst[e];
        atomicAdd(&lh[((d >> 14) << 3) | t], 1);
        atomicAdd(&cnt[d * NT + t], 1);
    }
    __syncthreads();
    if (tid < NBIN) atomicAdd(&hb[tid], lh[tid]);
}

// per-node degree + block-local exclusive scan; dblk[blk] = block total
__global__ void k_degA(const int* __restrict__ cnt, int* __restrict__ deg,
                       int* __restrict__ doff, int* __restrict__ dblk)
{
    __shared__ int ps[256];
    int tid = threadIdx.x;
    int v = blockIdx.x * 256 + tid;
    const int* cv = cnt + (size_t)v * NT;
    int d = 0;
#pragma unroll
    for (int t = 0; t < NT; ++t) d += cv[t];
    deg[v] = d;
    ps[tid] = d;
    __syncthreads();
    for (int off = 1; off < 256; off <<= 1) {
        int x = 0;
        if (tid >= off) x = ps[tid - off];
        __syncthreads();
        ps[tid] += x;
        __syncthreads();
    }
    doff[v] = ps[tid] - d;
    if (tid == 255) dblk[blockIdx.x] = ps[255];
}

// 1 small block: bin-offset scan (16 bins) + block-base scan (128, half reset at 64)
__global__ void k_scan2(int* __restrict__ hb, int* __restrict__ dblk)
{
    __shared__ int s[128];
    int tid = threadIdx.x;            // 128 threads
    s[tid] = dblk[tid];
    __syncthreads();
    if (tid == 0) {
        int acc = 0;
        for (int t = 0; t < NBIN; ++t) {
            hb[16 + t] = acc;
            hb[33 + t] = acc;
            acc += ((hb[t] + 127) >> 7) << 7;
        }
        hb[32] = acc;
        int run = 0;
        for (int i = 0; i < 128; ++i) {
            if (i == 64) run = 0;     // half-local m positions
            int x = s[i]; s[i] = run; run += x;
        }
    }
    __syncthreads();
    dblk[tid] = s[tid];
}

__global__ void k_degB(int* __restrict__ doff, int* __restrict__ dcur,
                       const int* __restrict__ dblk)
{
    int v = blockIdx.x * 256 + threadIdx.x;
    int o = doff[v] + dblk[blockIdx.x];
    doff[v] = o;
    dcur[v] = o;
}

__global__ void k_scatter(const int* __restrict__ src, const int* __restrict__ dst,
                          const int* __restrict__ et, int* __restrict__ hb,
                          int* __restrict__ dcur,
                          int* __restrict__ ssrc, int* __restrict__ sdst, int* __restrict__ sq)
{
    __shared__ int lc[NBIN], lbase[NBIN];
    int tid = threadIdx.x;
    if (tid < NBIN) lc[tid] = 0;
    __syncthreads();
    int base = blockIdx.x * 1024;
    int myk[4], myr[4];
    for (int k = 0; k < 4; ++k) {
        int e = base + tid * 4 + k;
        int kk = ((dst[e] >> 14) << 3) | et[e];
        myk[k] = kk;
        myr[k] = atomicAdd(&lc[kk], 1);
    }
    __syncthreads();
    if (tid < NBIN) lbase[tid] = atomicAdd(&hb[33 + tid], lc[tid]);
    __syncthreads();
    for (int k = 0; k < 4; ++k) {
        int e = base + tid * 4 + k;
        int p = lbase[myk[k]] + myr[k];
        int d = dst[e];
        ssrc[p] = src[e];
        sdst[p] = d;
        sq[p] = atomicAdd(&dcur[d], 1);       // dst-sorted (half-local) position
    }
}

// ---------------- MFMA message pass: 128 same-etype edges -> m rows (no atomics) ----------------

__launch_bounds__(256, 2)
__global__ void k_msg(const int* __restrict__ ssrc, const int* __restrict__ sdst,
                      const int* __restrict__ sq, const int* __restrict__ hb,
                      const unsigned short* __restrict__ hbf,
                      const unsigned short* __restrict__ wmb,
                      unsigned short* __restrict__ m, int half)
{
    __shared__ __align__(16) unsigned short As[128 * 128];
    __shared__ __align__(16) unsigned short Ws[128 * 128];
    __shared__ int sdl[128], ssl[128], sql[128];
    int hstart = hb[16 + 8 * half], hend = hb[16 + 8 * half + 8];
    int base = hstart + blockIdx.x * 128;
    if (base >= hend) return;                 // uniform
    int t = 0;
#pragma unroll
    for (int i = 1; i < 8; ++i) if (base >= hb[16 + 8 * half + i]) t = i;
    int tid = threadIdx.x;
    if (tid < 128) { sdl[tid] = sdst[base + tid]; ssl[tid] = ssrc[base + tid]; sql[tid] = sq[base + tid]; }
    __syncthreads();
    {
        int r = tid >> 1, halfc = tid & 1;
        const uint4* hp = (const uint4*)(hbf + (size_t)ssl[r] * DD + halfc * 64);
        const uint4* wp = (const uint4*)(wmb + (size_t)t * DD * DD + (size_t)r * DD + halfc * 64);
        unsigned boff = r * 256 + halfc * 128;
        unsigned sw = (r & 7) << 4;
#pragma unroll
        for (int c = 0; c < 8; ++c) {
            unsigned byte = (boff + c * 16) ^ sw;
            *(uint4*)((char*)As + byte) = hp[c];
            *(uint4*)((char*)Ws + byte) = wp[c];
        }
    }
    __syncthreads();
    int lane = tid & 63, wv = tid >> 6;
    int wm = (wv >> 1) * 64, wn = (wv & 1) * 64;
    int lr = lane & 15, lk = lane >> 4;
    f32x4 acc[4][4];
#pragma unroll
    for (int i = 0; i < 4; ++i)
#pragma unroll
        for (int j = 0; j < 4; ++j) acc[i][j] = (f32x4){0.f, 0.f, 0.f, 0.f};
#pragma unroll
    for (int kc = 0; kc < 4; ++kc) {
        int cb = kc * 64 + lk * 16;
        bf16x8 af[4], bfv[4];
#pragma unroll
        for (int mi = 0; mi < 4; ++mi) {
            int row = wm + mi * 16 + lr;
            af[mi] = *(const bf16x8*)((const char*)As + ((row * 256 + cb) ^ ((row & 7) << 4)));
        }
#pragma unroll
        for (int ni = 0; ni < 4; ++ni) {
            int row = wn + ni * 16 + lr;
            bfv[ni] = *(const bf16x8*)((const char*)Ws + ((row * 256 + cb) ^ ((row & 7) << 4)));
        }
#pragma unroll
        for (int mi = 0; mi < 4; ++mi)
#pragma unroll
            for (int ni = 0; ni < 4; ++ni)
                acc[mi][ni] = __builtin_amdgcn_mfma_f32_16x16x32_bf16(af[mi], bfv[ni], acc[mi][ni], 0, 0, 0);
    }
    // epilogue: pack bf16 rows into As (swizzled), then coalesced row writes to m[sq]
    __syncthreads();
#pragma unroll
    for (int mi = 0; mi < 4; ++mi)
#pragma unroll
        for (int ni = 0; ni < 4; ++ni)
#pragma unroll
            for (int rg = 0; rg < 4; ++rg) {
                int er = wm + mi * 16 + lk * 4 + rg;
                int col = wn + ni * 16 + lr;
                unsigned byte = ((unsigned)(er * 256 + col * 2)) ^ ((er & 7) << 4);
                *(unsigned short*)((char*)As + byte) = (unsigned short)f2b(acc[mi][ni][rg]);
            }
    __syncthreads();
    int orow = tid >> 4, ochunk = tid & 15;
#pragma unroll
    for (int pass = 0; pass < 8; ++pass) {
        int row = pass * 16 + orow;
        if (sdl[row] >= 0) {
            uint4 v = *(const uint4*)((const char*)As + (((unsigned)(row * 256 + ochunk * 16)) ^ ((row & 7) << 4)));
            *(uint4*)(m + (size_t)sql[row] * 128 + ochunk * 8) = v;
        }
    }
}

// ---------------- segment-sum: abf[v] = bf16( bias_seed(v) + sum of its message rows ) ----------------

__launch_bounds__(256)
__global__ void k_agg(const unsigned short* __restrict__ m, const int* __restrict__ deg,
                      const int* __restrict__ doff, const int* __restrict__ cnt,
                      const float* __restrict__ bmsg, unsigned short* __restrict__ abf, int half)
{
    __shared__ float bm[NT * DD];
    int tid = threadIdx.x;
    *(float4*)&bm[tid * 4] = ld4(bmsg + tid * 4);   // 256*4 = 1024 = 8*128
    __syncthreads();
    int wv = tid >> 6, lane = tid & 63;
    int v = half * (BN / 2) + blockIdx.x * 4 + wv;
    const int* cv = cnt + (size_t)v * NT;
    float a0 = 0.f, a1 = 0.f;
#pragma unroll
    for (int t = 0; t < NT; ++t) {
        float c = (float)cv[t];
        a0 += c * bm[t * DD + 2 * lane];
        a1 += c * bm[t * DD + 2 * lane + 1];
    }
    int d = deg[v], off = doff[v];
    const unsigned* mr = (const unsigned*)m;
    for (int e = 0; e < d; ++e) {
        unsigned w = mr[(size_t)(off + e) * 64 + lane];
        a0 += b2f((unsigned short)(w & 0xFFFF));
        a1 += b2f((unsigned short)(w >> 16));
    }
    ((unsigned*)abf)[(size_t)v * 64 + lane] = pk(a0, a1);
}

// ---------------- merged MFMA GRU: r,z,n in-register, h updated in place ----------------
// M-tile 64 nodes, N = 128; 4 gate accumulators live simultaneously (no rz buffer).

__launch_bounds__(256, 2)
__global__ void k_gru(const unsigned short* __restrict__ abf, float* __restrict__ h,
                      unsigned short* __restrict__ hbf,
                      const unsigned short* __restrict__ wihb, const unsigned short* __restrict__ whhb,
                      const float* __restrict__ bih, const float* __restrict__ bhh)
{
    __shared__ __align__(16) unsigned short Xs[64 * 128];
    __shared__ __align__(16) unsigned short Ws2[128 * 128];
    int m0 = blockIdx.x * 64;
    int tid = threadIdx.x;
    int lane = tid & 63, wv = tid >> 6;
    int wm = (wv >> 1) * 32, wn = (wv & 1) * 64;
    int lr = lane & 15, lk = lane >> 4;
    f32x4 aR[2][4], aZ[2][4], aI[2][4], aH[2][4];
#pragma unroll
    for (int i = 0; i < 2; ++i)
#pragma unroll
        for (int j = 0; j < 4; ++j) {
            aR[i][j] = (f32x4){0.f, 0.f, 0.f, 0.f};
            aZ[i][j] = (f32x4){0.f, 0.f, 0.f, 0.f};
            aI[i][j] = (f32x4){0.f, 0.f, 0.f, 0.f};
            aH[i][j] = (f32x4){0.f, 0.f, 0.f, 0.f};
        }
    int rx = tid >> 2, qx = tid & 3;
    unsigned bx = rx * 256 + qx * 64, swx = (rx & 7) << 4;
    int r2 = tid >> 1, h2 = tid & 1;
    unsigned bw = r2 * 256 + h2 * 128, sww = (r2 & 7) << 4;
#pragma unroll
    for (int pass = 0; pass < 2; ++pass) {
        const unsigned short* X = pass ? hbf : abf;
        const unsigned short* W = pass ? whhb : wihb;
#pragma unroll
        for (int g = 0; g < 3; ++g) {
            __syncthreads();                 // WAR: prior reads of Xs/Ws2 done
            if (g == 0) {
                const uint4* sp = (const uint4*)(X + (size_t)(m0 + rx) * DD + qx * 32);
#pragma unroll
                for (int c = 0; c < 4; ++c)
                    *(uint4*)((char*)Xs + ((bx + c * 16) ^ swx)) = sp[c];
            }
            const uint4* wp = (const uint4*)(W + (size_t)(g * DD + r2) * DD + h2 * 64);
#pragma unroll
            for (int c = 0; c < 8; ++c)
                *(uint4*)((char*)Ws2 + ((bw + c * 16) ^ sww)) = wp[c];
            __syncthreads();
#pragma unroll
            for (int kc = 0; kc < 4; ++kc) {
                int cb = kc * 64 + lk * 16;
                bf16x8 af[2], bfv[4];
#pragma unroll
                for (int mi = 0; mi < 2; ++mi) {
                    int row = wm + mi * 16 + lr;
                    af[mi] = *(const bf16x8*)((const char*)Xs + ((row * 256 + cb) ^ ((row & 7) << 4)));
                }
#pragma unroll
                for (int ni = 0; ni < 4; ++ni) {
                    int row = wn + ni * 16 + lr;
                    bfv[ni] = *(const bf16x8*)((const char*)Ws2 + ((row * 256 + cb) ^ ((row & 7) << 4)));
                }
#pragma unroll
                for (int mi = 0; mi < 2; ++mi)
#pragma unroll
                    for (int ni = 0; ni < 4; ++ni) {
                        if (g == 0)
                            aR[mi][ni] = __builtin_amdgcn_mfma_f32_16x16x32_bf16(af[mi], bfv[ni], aR[mi][ni], 0, 0, 0);
                        else if (g == 1)
                            aZ[mi][ni] = __builtin_amdgcn_mfma_f32_16x16x32_bf16(af[mi], bfv[ni], aZ[mi][ni], 0, 0, 0);
                        else if (pass == 0)
                            aI[mi][ni] = __builtin_amdgcn_mfma_f32_16x16x32_bf16(af[mi], bfv[ni], aI[mi][ni], 0, 0, 0);
                        else
                            aH[mi][ni] = __builtin_amdgcn_mfma_f32_16x16x32_bf16(af[mi], bfv[ni], aH[mi][ni], 0, 0, 0);
                    }
            }
        }
    }
    // epilogue: full GRU combine in-register
#pragma unroll
    for (int ni = 0; ni < 4; ++ni) {
        int col = wn + ni * 16 + lr;
        float br_ = bih[col] + bhh[col];
        float bz_ = bih[DD + col] + bhh[DD + col];
        float bin_ = bih[2 * DD + col], bhn_ = bhh[2 * DD + col];
#pragma unroll
        for (int mi = 0; mi < 2; ++mi)
#pragma unroll
            for (int rg = 0; rg < 4; ++rg) {
                int v = m0 + wm + mi * 16 + lk * 4 + rg;
                float rr = sigmoidf_(aR[mi][ni][rg] + br_);
                float zz = sigmoidf_(aZ[mi][ni][rg] + bz_);
                float nn = tanhf(aI[mi][ni][rg] + bin_ + rr * (aH[mi][ni][rg] + bhn_));
                float hold = h[(size_t)v * DD + col];
                float hnew = (1.f - zz) * nn + zz * hold;
                h[(size_t)v * DD + col] = hnew;
                hbf[(size_t)v * DD + col] = (unsigned short)f2b(hnew);
            }
    }
}

// ---------------- MFMA conv1(k=3): U1[b][pos][co] = relu(conv+b), unpooled, bf16 ----------------

template <int CIN>
__launch_bounds__(256, 2)
__global__ void k_conv1m(const unsigned short* __restrict__ hbf, const float* __restrict__ h0,
                         const unsigned short* __restrict__ w1p, const float* __restrict__ bias,
                         unsigned short* __restrict__ U1)
{
    __shared__ __align__(16) unsigned short As[128 * 64];
    __shared__ __align__(16) unsigned short Ws[128 * 64];
    int p0 = blockIdx.x * 128, b = blockIdx.y, n0 = blockIdx.z * 128;
    int tid = threadIdx.x;
    int lane = tid & 63, wv = tid >> 6;
    int wm = (wv >> 1) * 64, wn = (wv & 1) * 64;
    int lr = lane & 15, lk = lane >> 4;
    f32x4 acc[4][4];
#pragma unroll
    for (int i = 0; i < 4; ++i)
#pragma unroll
        for (int j = 0; j < 4; ++j) acc[i][j] = (f32x4){0.f, 0.f, 0.f, 0.f};

    int r = tid >> 1, halfc = tid & 1;
    unsigned boff = r * 128 + halfc * 64;
    unsigned sw = (r & 7) << 4;
#pragma unroll
    for (int k = 0; k < 3; ++k) {
        for (int c0 = 0; c0 < CIN; c0 += 64) {
            __syncthreads();
            {
                int row = p0 + k + r; if (row > NNODE - 1) row = NNODE - 1;
                int ci = c0 + halfc * 32;
                if (CIN == 128 || ci < 128) {
                    const uint4* sp = (const uint4*)(hbf + ((size_t)(b * NNODE + row)) * DD + ci);
#pragma unroll
                    for (int c = 0; c < 4; ++c)
                        *(uint4*)((char*)As + ((boff + c * 16) ^ sw)) = sp[c];
                } else {
                    const float4* sp = (const float4*)(h0 + ((size_t)(b * NNODE + row)) * DD + (ci - 128));
#pragma unroll
                    for (int c = 0; c < 4; ++c) {
                        float4 v0 = sp[2 * c], v1 = sp[2 * c + 1];
                        *(uint4*)((char*)As + ((boff + c * 16) ^ sw)) =
                            make_uint4(pk(v0.x, v0.y), pk(v0.z, v0.w), pk(v1.x, v1.y), pk(v1.z, v1.w));
                    }
                }
            }
            {
                const uint4* wp = (const uint4*)(w1p + ((size_t)k * CIN + n0 + r) * CIN + c0 + halfc * 32);
#pragma unroll
                for (int c = 0; c < 4; ++c)
                    *(uint4*)((char*)Ws + ((boff + c * 16) ^ sw)) = wp[c];
            }
            __syncthreads();
#pragma unroll
            for (int kc = 0; kc < 2; ++kc) {
                int cb = kc * 64 + lk * 16;
                bf16x8 af[4], bfv[4];
#pragma unroll
                for (int mi = 0; mi < 4; ++mi) {
                    int row = wm + mi * 16 + lr;
                    af[mi] = *(const bf16x8*)((const char*)As + ((row * 128 + cb) ^ ((row & 7) << 4)));
                }
#pragma unroll
                for (int ni = 0; ni < 4; ++ni) {
                    int row = wn + ni * 16 + lr;
                    bfv[ni] = *(const bf16x8*)((const char*)Ws + ((row * 128 + cb) ^ ((row & 7) << 4)));
                }
#pragma unroll
                for (int mi = 0; mi < 4; ++mi)
#pragma unroll
                    for (int ni = 0; ni < 4; ++ni)
                        acc[mi][ni] = __builtin_amdgcn_mfma_f32_16x16x32_bf16(af[mi], bfv[ni], acc[mi][ni], 0, 0, 0);
            }
        }
    }
#pragma unroll
    for (int ni = 0; ni < 4; ++ni) {
        int co = n0 + wn + ni * 16 + lr;
        float bs = bias[co];
#pragma unroll
        for (int mi = 0; mi < 4; ++mi)
#pragma unroll
            for (int rg = 0; rg < 4; ++rg) {
                int pos = p0 + wm + mi * 16 + lk * 4 + rg;
                if (pos < NNODE - 2) {
                    float v = fmaxf(0.f, acc[mi][ni][rg] + bs);
                    U1[((size_t)b * NNODE + pos) * CIN + co] = (unsigned short)f2b(v);
                }
            }
    }
}

// ---------------- MFMA conv2(k=1): A = pool3(U1) on the fly; epilogue pool2 ----------------

template <int CIN>
__launch_bounds__(256, 2)
__global__ void k_conv2m(const unsigned short* __restrict__ U1, const unsigned short* __restrict__ w2b,
                         const float* __restrict__ bias, float* __restrict__ Q)
{
    __shared__ __align__(16) unsigned short As[128 * 64];
    __shared__ __align__(16) unsigned short Ws[128 * 64];
    int m0 = blockIdx.x * 128, b = blockIdx.y, n0 = blockIdx.z * 128;
    int tid = threadIdx.x;
    int lane = tid & 63, wv = tid >> 6;
    int wm = (wv >> 1) * 64, wn = (wv & 1) * 64;
    int lr = lane & 15, lk = lane >> 4;
    f32x4 acc[4][4];
#pragma unroll
    for (int i = 0; i < 4; ++i)
#pragma unroll
        for (int j = 0; j < 4; ++j) acc[i][j] = (f32x4){0.f, 0.f, 0.f, 0.f};

    int r = tid >> 1, halfc = tid & 1;
    unsigned boff = r * 128 + halfc * 64;
    unsigned sw = (r & 7) << 4;
    for (int c0 = 0; c0 < CIN; c0 += 64) {
        __syncthreads();
        {
            int pr = 2 * (m0 + r);
            int r0 = pr, r1 = pr + 1, r2v = pr + 2;
            if (r2v > NNODE - 1) r2v = NNODE - 1;
            if (r1 > NNODE - 1) r1 = NNODE - 1;
            int ci = c0 + halfc * 32;
            const unsigned short* bp = U1 + (size_t)b * NNODE * CIN + ci;
            const uint4* p0q = (const uint4*)(bp + (size_t)r0 * CIN);
            const uint4* p1q = (const uint4*)(bp + (size_t)r1 * CIN);
            const uint4* p2q = (const uint4*)(bp + (size_t)r2v * CIN);
#pragma unroll
            for (int c = 0; c < 4; ++c) {
                uint4 mm = bmax4(bmax4(p0q[c], p1q[c]), p2q[c]);
                *(uint4*)((char*)As + ((boff + c * 16) ^ sw)) = mm;
            }
        }
        {
            const uint4* wp = (const uint4*)(w2b + (size_t)(n0 + r) * CIN + c0 + halfc * 32);
#pragma unroll
            for (int c = 0; c < 4; ++c)
                *(uint4*)((char*)Ws + ((boff + c * 16) ^ sw)) = wp[c];
        }
        __syncthreads();
#pragma unroll
        for (int kc = 0; kc < 2; ++kc) {
            int cb = kc * 64 + lk * 16;
            bf16x8 af[4], bfv[4];
#pragma unroll
            for (int mi = 0; mi < 4; ++mi) {
                int row = wm + mi * 16 + lr;
                af[mi] = *(const bf16x8*)((const char*)As + ((row * 128 + cb) ^ ((row & 7) << 4)));
            }
#pragma unroll
            for (int ni = 0; ni < 4; ++ni) {
                int row = wn + ni * 16 + lr;
                bfv[ni] = *(const bf16x8*)((const char*)Ws + ((row * 128 + cb) ^ ((row & 7) << 4)));
            }
#pragma unroll
            for (int mi = 0; mi < 4; ++mi)
#pragma unroll
                for (int ni = 0; ni < 4; ++ni)
                    acc[mi][ni] = __builtin_amdgcn_mfma_f32_16x16x32_bf16(af[mi], bfv[ni], acc[mi][ni], 0, 0, 0);
        }
    }
#pragma unroll
    for (int ni = 0; ni < 4; ++ni) {
        int co = n0 + wn + ni * 16 + lr;
        float bs = bias[co];
#pragma unroll
        for (int mi = 0; mi < 4; ++mi) {
            int l0 = m0 + wm + mi * 16 + lk * 4;
            float v0 = fmaxf(0.f, acc[mi][ni][0] + bs);
            float v1 = fmaxf(0.f, acc[mi][ni][1] + bs);
            float v2 = fmaxf(0.f, acc[mi][ni][2] + bs);
            float v3 = fmaxf(0.f, acc[mi][ni][3] + bs);
            int jq = l0 >> 1;
            if (jq < 255)     Q[((size_t)b * 255 + jq) * CIN + co]     = fmaxf(v0, v1);
            if (jq + 1 < 255) Q[((size_t)b * 255 + jq + 1) * CIN + co] = fmaxf(v2, v3);
        }
    }
}

// ---------------- final reduction ----------------

__launch_bounds__(256)
__global__ void k_final(const float* __restrict__ QY, const float* __restrict__ QZ,
                        const float* __restrict__ wy, const float* __restrict__ by,
                        const float* __restrict__ wz, const float* __restrict__ bz,
                        float* __restrict__ out)
{
    int b = blockIdx.x, tid = threadIdx.x;
    float p = 0.f;
    if (tid < 255) {
        const float* qy = QY + ((size_t)(b * 255 + tid)) * 128;
        const float* qz = QZ + ((size_t)(b * 255 + tid)) * 256;
        float dy = 0.f, dz = 0.f;
        for (int c = 0; c < 128; c += 4) {
            float4 q = ld4(qy + c), wv = ld4(wy + c);
            dy += q.x * wv.x + q.y * wv.y + q.z * wv.z + q.w * wv.w;
        }
        for (int c = 0; c < 256; c += 4) {
            float4 q = ld4(qz + c), wv = ld4(wz + c);
            dz += q.x * wv.x + q.y * wv.y + q.z * wv.z + q.w * wv.w;
        }
        p = (dy + by[0]) * (dz + bz[0]);
    }
    __shared__ float red[4];
    for (int off = 32; off > 0; off >>= 1) p += __shfl_down(p, off);
    if ((tid & 63) == 0) red[tid >> 6] = p;
    __syncthreads();
    if (tid == 0) {
        float s = red[0] + red[1] + red[2] + red[3];
        out[b] = 1.f / (1.f + expf(-s / 255.f));
    }
}

// ---------------- launch ----------------

extern "C" void kernel_launch(void* const* d_in, const int* in_sizes, int n_in,
                              void* d_out, int out_size, void* d_ws, size_t ws_size,
                              hipStream_t stream)
{
    const float* h_in = (const float*)d_in[0];
    const int* src = (const int*)d_in[1];
    const int* dst = (const int*)d_in[2];
    const int* et  = (const int*)d_in[3];
    const float* Wmsg = (const float*)d_in[4];
    const float* bmsg = (const float*)d_in[5];
    const float* wih = (const float*)d_in[6];
    const float* whh = (const float*)d_in[7];
    const float* bih = (const float*)d_in[8];
    const float* bhh = (const float*)d_in[9];
    const float* c1w = (const float*)d_in[10];
    const float* c1b = (const float*)d_in[11];
    const float* c2w = (const float*)d_in[12];
    const float* c2b = (const float*)d_in[13];
    const float* z1w = (const float*)d_in[14];
    const float* z1b = (const float*)d_in[15];
    const float* z2w = (const float*)d_in[16];
    const float* z2b = (const float*)d_in[17];
    const float* wy  = (const float*)d_in[18];
    const float* by  = (const float*)d_in[19];
    const float* wz  = (const float*)d_in[20];
    const float* bz  = (const float*)d_in[21];
    float* out = (float*)d_out;

    if (ws_size < WS_NEED) return;   // loud failure: output stays poisoned

    char* ws = (char*)d_ws;
    float* hcur = (float*)(ws + OFF_HCUR);
    unsigned short* hbf  = (unsigned short*)(ws + OFF_HBF);
    int*   cnt  = (int*)(ws + OFF_CNT);
    int*   deg  = (int*)(ws + OFF_DEG);
    int*   doff = (int*)(ws + OFF_DOFF);
    int*   dcur = (int*)(ws + OFF_DCUR);
    int*   dblk = (int*)(ws + OFF_DBLK);
    int*   hb   = (int*)(ws + OFF_HB);
    int*   ssrc = (int*)(ws + OFF_SSRC);
    int*   sdst = (int*)(ws + OFF_SDST);
    int*   sq   = (int*)(ws + OFF_SQ);
    unsigned short* wmb  = (unsigned short*)(ws + OFF_WMB);
    unsigned short* wihb = (unsigned short*)(ws + OFF_WIHB);
    unsigned short* whhb = (unsigned short*)(ws + OFF_WHHB);
    unsigned short* w1py = (unsigned short*)(ws + OFF_W1PY);
    unsigned short* w1pz = (unsigned short*)(ws + OFF_W1PZ);
    unsigned short* w2yb = (unsigned short*)(ws + OFF_W2YB);
    unsigned short* w2zb = (unsigned short*)(ws + OFF_W2ZB);
    unsigned short* abf  = (unsigned short*)(ws + OFF_ABF);
    unsigned short* mbuf = (unsigned short*)(ws + OFF_M);
    unsigned short* U1Y  = (unsigned short*)(ws + OFF_U1Y);
    unsigned short* U1Z  = (unsigned short*)(ws + OFF_U1Z);
    float* QY   = (float*)(ws + OFF_QY);
    float* QZ   = (float*)(ws + OFF_QZ);

    k_prep<<<PREP_BLOCKS, 256, 0, stream>>>(h_in, hcur, hbf, Wmsg, wmb, wih, wihb, whh, whhb,
                                            c2w, w2yb, z2w, w2zb, c1w, w1py, z1w, w1pz,
                                            cnt, hb, ssrc, sdst);

    k_hist<<<256, 256, 0, stream>>>(et, dst, hb, cnt);
    k_degA<<<128, 256, 0, stream>>>(cnt, deg, doff, dblk);
    k_scan2<<<1, 128, 0, stream>>>(hb, dblk);
    k_degB<<<128, 256, 0, stream>>>(doff, dcur, dblk);
    k_scatter<<<256, 256, 0, stream>>>(src, dst, et, hb, dcur, ssrc, sdst, sq);

    for (int s = 0; s < NSTEPS; ++s) {
        for (int half = 0; half < 2; ++half) {
            k_msg<<<NTILES_H, 256, 0, stream>>>(ssrc, sdst, sq, hb, hbf, wmb, mbuf, half);
            k_agg<<<BN / 2 / 4, 256, 0, stream>>>(mbuf, deg, doff, cnt, bmsg, abf, half);
        }
        k_gru<<<BN / 64, 256, 0, stream>>>(abf, hcur, hbf, wihb, whhb, bih, bhh);
    }

    k_conv1m<128><<<dim3(8, 32, 1), 256, 0, stream>>>(hbf, h_in, w1py, c1b, U1Y);
    k_conv2m<128><<<dim3(4, 32, 1), 256, 0, stream>>>(U1Y, w2yb, c2b, QY);
    k_conv1m<256><<<dim3(8, 32, 2), 256, 0, stream>>>(hbf, h_in, w1pz, z1b, U1Z);
    k_conv2m<256><<<dim3(4, 32, 2), 256, 0, stream>>>(U1Z, w2zb, z2b, QZ);
    k_final<<<32, 256, 0, stream>>>(QY, QZ, wy, by, wz, bz, out);
}

// Round 7
// 564.767 us; speedup vs baseline: 18.1995x; 1.2847x over previous
//
#include <hip/hip_runtime.h>
#include <math.h>

#define BB 32
#define NNODE 1024
#define BN 32768
#define NE 262144
#define DD 128
#define NT 8
#define NSTEPS 6
#define NBIN 16                      // (dst-half)*8 + etype (bins kept; sq is global now)
#define SORT_CAP (NE + 2048)         // bins padded to 128-edge tiles
#define NTILES_F 2064                // >= total padded tiles (2048 + 16)
#define M_CAP (NE + 2048)            // rows in message buffer (full E)

typedef __attribute__((ext_vector_type(8))) short bf16x8;
typedef __attribute__((ext_vector_type(4))) float f32x4;

static __device__ __forceinline__ float4 ld4(const float* p) { return *(const float4*)p; }
static __device__ __forceinline__ float sigmoidf_(float x) { return 1.f / (1.f + expf(-x)); }
// f32 -> bf16 round-to-nearest-even
static __device__ __forceinline__ unsigned f2b(float f) {
    unsigned u = __float_as_uint(f);
    return (u + 0x7FFFu + ((u >> 16) & 1u)) >> 16;
}
static __device__ __forceinline__ float b2f(unsigned short b) {
    return __uint_as_float(((unsigned)b) << 16);
}
static __device__ __forceinline__ unsigned pk(float a, float b) {
    return f2b(a) | (f2b(b) << 16);
}
// elementwise u16 max of packed pairs (valid ordering for non-negative bf16)
static __device__ __forceinline__ unsigned bmax2(unsigned a, unsigned b) {
    unsigned ah = a & 0xFFFF0000u, bh = b & 0xFFFF0000u;
    unsigned al = a & 0x0000FFFFu, bl = b & 0x0000FFFFu;
    return (ah > bh ? ah : bh) | (al > bl ? al : bl);
}
static __device__ __forceinline__ uint4 bmax4(uint4 a, uint4 b) {
    return make_uint4(bmax2(a.x, b.x), bmax2(a.y, b.y), bmax2(a.z, b.z), bmax2(a.w, b.w));
}

// ---------------- workspace layout (bytes) ----------------
static constexpr size_t OFF_HCUR = 0;                                   // BN*DD f32
static constexpr size_t OFF_HBF  = OFF_HCUR + (size_t)BN * DD * 4;      // BN*DD bf16
static constexpr size_t OFF_CNT  = OFF_HBF  + (size_t)BN * DD * 2;      // BN*NT i32
static constexpr size_t OFF_DEG  = OFF_CNT  + (size_t)BN * NT * 4;      // BN i32
static constexpr size_t OFF_DOFF = OFF_DEG  + (size_t)BN * 4;           // BN i32
static constexpr size_t OFF_DCUR = OFF_DOFF + (size_t)BN * 4;           // BN i32
static constexpr size_t OFF_DBLK = OFF_DCUR + (size_t)BN * 4;           // 512 B
static constexpr size_t OFF_HB   = OFF_DBLK + 512;                      // 256 B
static constexpr size_t OFF_SSRC = OFF_HB   + 256;                      // SORT_CAP i32
static constexpr size_t OFF_SDST = OFF_SSRC + (size_t)SORT_CAP * 4;
static constexpr size_t OFF_SQ   = OFF_SDST + (size_t)SORT_CAP * 4;
static constexpr size_t OFF_WMB  = OFF_SQ   + (size_t)SORT_CAP * 4;     // 8*128*128 bf16
static constexpr size_t OFF_WIHB = OFF_WMB  + (size_t)NT * DD * DD * 2;
static constexpr size_t OFF_WHHB = OFF_WIHB + (size_t)3 * DD * DD * 2;
static constexpr size_t OFF_W1PY = OFF_WHHB + (size_t)3 * DD * DD * 2;  // 3*128*128 bf16
static constexpr size_t OFF_W1PZ = OFF_W1PY + (size_t)3 * 128 * 128 * 2;// 3*256*256 bf16
static constexpr size_t OFF_W2YB = OFF_W1PZ + (size_t)3 * 256 * 256 * 2;// 128*128 bf16
static constexpr size_t OFF_W2ZB = OFF_W2YB + (size_t)128 * 128 * 2;    // 256*256 bf16
static constexpr size_t OFF_ABF  = OFF_W2ZB + (size_t)256 * 256 * 2;    // BN*DD bf16
static constexpr size_t OFF_UN   = OFF_ABF  + (size_t)BN * DD * 2;      // union region
// GGNN phase:   m[M_CAP][128] bf16 (67.6 MB)
static constexpr size_t OFF_M    = OFF_UN;
// conv phase (after GGNN; aliases m):
static constexpr size_t OFF_U1Y  = OFF_UN;                                 // 32*1024*128 bf16
static constexpr size_t OFF_U1Z  = OFF_U1Y + (size_t)32 * 1024 * 128 * 2;  // 32*1024*256 bf16
static constexpr size_t OFF_QY   = OFF_U1Z + (size_t)32 * 1024 * 256 * 2;  // 32*255*128 f32
static constexpr size_t OFF_QZ   = OFF_QY  + (size_t)32 * 255 * 128 * 4;   // 32*255*256 f32
static constexpr size_t CONV_SZ  = (size_t)32 * 1024 * 128 * 2 + (size_t)32 * 1024 * 256 * 2
                                 + (size_t)32 * 255 * 128 * 4 + (size_t)32 * 255 * 256 * 4;
static constexpr size_t M_SZ     = (size_t)M_CAP * 128 * 2;
static constexpr size_t UN_SZ    = (M_SZ > CONV_SZ ? M_SZ : CONV_SZ);
static constexpr size_t WS_NEED  = OFF_UN + UN_SZ;                         // ~108 MiB (ws = 256 MiB per fill evidence)

// ---------------- mega prep kernel: copies/converts/zeros everything ----------------
#define PREP_BLOCKS 6133
__global__ void k_prep(const float* __restrict__ h_in, float* __restrict__ hcur,
                       unsigned short* __restrict__ hbf,
                       const float* __restrict__ Wmsg, unsigned short* __restrict__ wmb,
                       const float* __restrict__ wih, unsigned short* __restrict__ wihb,
                       const float* __restrict__ whh, unsigned short* __restrict__ whhb,
                       const float* __restrict__ c2w, unsigned short* __restrict__ w2yb,
                       const float* __restrict__ z2w, unsigned short* __restrict__ w2zb,
                       const float* __restrict__ c1w, unsigned short* __restrict__ w1py,
                       const float* __restrict__ z1w, unsigned short* __restrict__ w1pz,
                       int* __restrict__ cnt, int* __restrict__ hb,
                       int* __restrict__ ssrc, int* __restrict__ sdst)
{
    int blk = blockIdx.x, tid = threadIdx.x;
    if (blk < 4096) {
        int i = blk * 256 + tid;
        float4 v = ((const float4*)h_in)[i];
        ((float4*)hcur)[i] = v;
        ((uint2*)hbf)[i] = make_uint2(pk(v.x, v.y), pk(v.z, v.w));
    } else if (blk < 4224) {
        int i = (blk - 4096) * 256 + tid;
        float4 v = ((const float4*)Wmsg)[i];
        ((uint2*)wmb)[i] = make_uint2(pk(v.x, v.y), pk(v.z, v.w));
    } else if (blk < 4272) {
        int i = (blk - 4224) * 256 + tid;
        float4 v = ((const float4*)wih)[i];
        ((uint2*)wihb)[i] = make_uint2(pk(v.x, v.y), pk(v.z, v.w));
    } else if (blk < 4320) {
        int i = (blk - 4272) * 256 + tid;
        float4 v = ((const float4*)whh)[i];
        ((uint2*)whhb)[i] = make_uint2(pk(v.x, v.y), pk(v.z, v.w));
    } else if (blk < 4336) {
        int i = (blk - 4320) * 256 + tid;
        float4 v = ((const float4*)c2w)[i];
        ((uint2*)w2yb)[i] = make_uint2(pk(v.x, v.y), pk(v.z, v.w));
    } else if (blk < 4400) {
        int i = (blk - 4336) * 256 + tid;
        float4 v = ((const float4*)z2w)[i];
        ((uint2*)w2zb)[i] = make_uint2(pk(v.x, v.y), pk(v.z, v.w));
    } else if (blk < 4592) {
        int g = (blk - 4400) * 256 + tid;          // < 3*128*128
        int k = g >> 14, rem = g & 16383;
        w1py[g] = (unsigned short)f2b(c1w[(size_t)rem * 3 + k]);
    } else if (blk < 5360) {
        int g = (blk - 4592) * 256 + tid;          // < 3*256*256
        int k = g >> 16, rem = g & 65535;
        w1pz[g] = (unsigned short)f2b(z1w[(size_t)rem * 3 + k]);
    } else if (blk < 5616) {
        ((uint4*)cnt)[(blk - 5360) * 256 + tid] = make_uint4(0, 0, 0, 0);
    } else if (blk < 5617) {
        if (tid < 64) hb[tid] = 0;
    } else if (blk < 5875) {
        ((uint4*)ssrc)[(blk - 5617) * 256 + tid] = make_uint4(0, 0, 0, 0);
    } else {
        ((uint4*)sdst)[(blk - 5875) * 256 + tid] = make_uint4(~0u, ~0u, ~0u, ~0u);
    }
}

// ---------------- graph preprocessing ----------------
// hb layout: [0..15] hist, [16..32] aoff (17 entries), [33..48] cur

__global__ void k_hist(const int* __restrict__ et, const int* __restrict__ dst,
                       int* __restrict__ hb, int* __restrict__ cnt)
{
    __shared__ int lh[NBIN];
    int tid = threadIdx.x;
    if (tid < NBIN) lh[tid] = 0;
    __syncthreads();
    int base = blockIdx.x * 1024;
    for (int k = 0; k < 4; ++k) {
        int e = base + tid + k * 256;
        int t = et[e], d = dst[e];
        atomicAdd(&lh[((d >> 14) << 3) | t], 1);
        atomicAdd(&cnt[d * NT + t], 1);
    }
    __syncthreads();
    if (tid < NBIN) atomicAdd(&hb[tid], lh[tid]);
}

// per-node degree + block-local exclusive scan; dblk[blk] = block total
__global__ void k_degA(const int* __restrict__ cnt, int* __restrict__ deg,
                       int* __restrict__ doff, int* __restrict__ dblk)
{
    __shared__ int ps[256];
    int tid = threadIdx.x;
    int v = blockIdx.x * 256 + tid;
    const int* cv = cnt + (size_t)v * NT;
    int d = 0;
#pragma unroll
    for (int t = 0; t < NT; ++t) d += cv[t];
    deg[v] = d;
    ps[tid] = d;
    __syncthreads();
    for (int off = 1; off < 256; off <<= 1) {
        int x = 0;
        if (tid >= off) x = ps[tid - off];
        __syncthreads();
        ps[tid] += x;
        __syncthreads();
    }
    doff[v] = ps[tid] - d;
    if (tid == 255) dblk[blockIdx.x] = ps[255];
}

// 1 small block: bin-offset scan (16 bins) + global block-base scan (128 blocks)
__global__ void k_scan2(int* __restrict__ hb, int* __restrict__ dblk)
{
    __shared__ int s[128];
    int tid = threadIdx.x;            // 128 threads
    s[tid] = dblk[tid];
    __syncthreads();
    if (tid == 0) {
        int acc = 0;
        for (int t = 0; t < NBIN; ++t) {
            hb[16 + t] = acc;
            hb[33 + t] = acc;
            acc += ((hb[t] + 127) >> 7) << 7;
        }
        hb[32] = acc;
        int run = 0;
        for (int i = 0; i < 128; ++i) {
            int x = s[i]; s[i] = run; run += x;
        }
    }
    __syncthreads();
    dblk[tid] = s[tid];
}

__global__ void k_degB(int* __restrict__ doff, int* __restrict__ dcur,
                       const int* __restrict__ dblk)
{
    int v = blockIdx.x * 256 + threadIdx.x;
    int o = doff[v] + dblk[blockIdx.x];
    doff[v] = o;
    dcur[v] = o;
}

__global__ void k_scatter(const int* __restrict__ src, const int* __restrict__ dst,
                          const int* __restrict__ et, int* __restrict__ hb,
                          int* __restrict__ dcur,
                          int* __restrict__ ssrc, int* __restrict__ sdst, int* __restrict__ sq)
{
    __shared__ int lc[NBIN], lbase[NBIN];
    int tid = threadIdx.x;
    if (tid < NBIN) lc[tid] = 0;
    __syncthreads();
    int base = blockIdx.x * 1024;
    int myk[4], myr[4];
    for (int k = 0; k < 4; ++k) {
        int e = base + tid * 4 + k;
        int kk = ((dst[e] >> 14) << 3) | et[e];
        myk[k] = kk;
        myr[k] = atomicAdd(&lc[kk], 1);
    }
    __syncthreads();
    if (tid < NBIN) lbase[tid] = atomicAdd(&hb[33 + tid], lc[tid]);
    __syncthreads();
    for (int k = 0; k < 4; ++k) {
        int e = base + tid * 4 + k;
        int p = lbase[myk[k]] + myr[k];
        int d = dst[e];
        ssrc[p] = src[e];
        sdst[p] = d;
        sq[p] = atomicAdd(&dcur[d], 1);       // global dst-sorted position
    }
}

// ---------------- MFMA message pass: 128 same-etype edges -> m rows (no atomics) ----------------
// K-chunked [128][64] staging, 3 blocks/CU; pack epilogue splits cols across As/Ws.

__launch_bounds__(256, 3)
__global__ void k_msg(const int* __restrict__ ssrc, const int* __restrict__ sdst,
                      const int* __restrict__ sq, const int* __restrict__ hb,
                      const unsigned short* __restrict__ hbf,
                      const unsigned short* __restrict__ wmb,
                      unsigned short* __restrict__ m)
{
    __shared__ __align__(16) unsigned short As[128 * 64];
    __shared__ __align__(16) unsigned short Ws[128 * 64];
    __shared__ int sdl[128], ssl[128], sql[128];
    int base = blockIdx.x * 128;
    if (base >= hb[32]) return;               // uniform
    int bin = 0;
#pragma unroll
    for (int i = 1; i < NBIN; ++i) if (base >= hb[16 + i]) bin = i;
    int t = bin & 7;
    int tid = threadIdx.x;
    if (tid < 128) { sdl[tid] = sdst[base + tid]; ssl[tid] = ssrc[base + tid]; sql[tid] = sq[base + tid]; }
    __syncthreads();
    int lane = tid & 63, wvv = tid >> 6;
    int wm = (wvv >> 1) * 64, wn = (wvv & 1) * 64;
    int lr = lane & 15, lk = lane >> 4;
    f32x4 acc[4][4];
#pragma unroll
    for (int i = 0; i < 4; ++i)
#pragma unroll
        for (int j = 0; j < 4; ++j) acc[i][j] = (f32x4){0.f, 0.f, 0.f, 0.f};

    int r = tid >> 1, halfc = tid & 1;
    unsigned boff = r * 128 + halfc * 64;     // bytes, 128B rows
    unsigned sw = (r & 7) << 4;
    for (int c0 = 0; c0 < DD; c0 += 64) {
        if (c0) __syncthreads();              // WAR before restage
        {
            const uint4* hp = (const uint4*)(hbf + (size_t)ssl[r] * DD + c0 + halfc * 32);
            const uint4* wp = (const uint4*)(wmb + (size_t)t * DD * DD + (size_t)r * DD + c0 + halfc * 32);
#pragma unroll
            for (int c = 0; c < 4; ++c) {
                unsigned byte = (boff + c * 16) ^ sw;
                *(uint4*)((char*)As + byte) = hp[c];
                *(uint4*)((char*)Ws + byte) = wp[c];
            }
        }
        __syncthreads();
#pragma unroll
        for (int kc = 0; kc < 2; ++kc) {
            int cb = kc * 64 + lk * 16;
            bf16x8 af[4], bfv[4];
#pragma unroll
            for (int mi = 0; mi < 4; ++mi) {
                int row = wm + mi * 16 + lr;
                af[mi] = *(const bf16x8*)((const char*)As + ((row * 128 + cb) ^ ((row & 7) << 4)));
            }
#pragma unroll
            for (int ni = 0; ni < 4; ++ni) {
                int row = wn + ni * 16 + lr;
                bfv[ni] = *(const bf16x8*)((const char*)Ws + ((row * 128 + cb) ^ ((row & 7) << 4)));
            }
#pragma unroll
            for (int mi = 0; mi < 4; ++mi)
#pragma unroll
                for (int ni = 0; ni < 4; ++ni)
                    acc[mi][ni] = __builtin_amdgcn_mfma_f32_16x16x32_bf16(af[mi], bfv[ni], acc[mi][ni], 0, 0, 0);
        }
    }
    // pack epilogue: cols 0-63 -> As, 64-127 -> Ws (wave-disjoint by wn)
    __syncthreads();
    {
        unsigned short* tgt = wn ? Ws : As;
#pragma unroll
        for (int mi = 0; mi < 4; ++mi)
#pragma unroll
            for (int ni = 0; ni < 4; ++ni)
#pragma unroll
                for (int rg = 0; rg < 4; ++rg) {
                    int er = wm + mi * 16 + lk * 4 + rg;
                    int col = (wn + ni * 16 + lr) & 63;
                    unsigned byte = ((unsigned)(er * 128 + col * 2)) ^ ((er & 7) << 4);
                    *(unsigned short*)((char*)tgt + byte) = (unsigned short)f2b(acc[mi][ni][rg]);
                }
    }
    __syncthreads();
    int orow = tid >> 4, ochunk = tid & 15;
#pragma unroll
    for (int p = 0; p < 8; ++p) {
        int row = p * 16 + orow;
        if (sdl[row] >= 0) {
            const char* srcb = (ochunk < 8) ? (const char*)As : (const char*)Ws;
            unsigned byte = ((unsigned)(row * 128 + (ochunk & 7) * 16)) ^ ((row & 7) << 4);
            uint4 v = *(const uint4*)(srcb + byte);
            *(uint4*)(m + (size_t)sql[row] * 128 + ochunk * 8) = v;
        }
    }
}

// ---------------- segment-sum: abf[v] = bf16( bias_seed(v) + sum of its message rows ) ----------------
// lanes 0-31: even rows + bias; lanes 32-63: odd rows; shfl_xor(32) combine.

__launch_bounds__(256)
__global__ void k_agg(const unsigned short* __restrict__ m, const int* __restrict__ deg,
                      const int* __restrict__ doff, const int* __restrict__ cnt,
                      const float* __restrict__ bmsg, unsigned short* __restrict__ abf)
{
    __shared__ float bm[NT * DD];
    int tid = threadIdx.x;
    *(float4*)&bm[tid * 4] = ld4(bmsg + tid * 4);   // 256*4 = 1024 = 8*128
    __syncthreads();
    int wv = tid >> 6, lane = tid & 63;
    int v = blockIdx.x * 4 + wv;
    int lh = lane >> 5;          // 0: even rows (+bias), 1: odd rows
    int lc = lane & 31;          // cols [4*lc, 4*lc+4)
    float a0 = 0.f, a1 = 0.f, a2 = 0.f, a3 = 0.f;
    if (lh == 0) {
        const int* cv = cnt + (size_t)v * NT;
        int c0 = lc * 4;
#pragma unroll
        for (int t = 0; t < NT; ++t) {
            float c = (float)cv[t];
            a0 += c * bm[t * DD + c0];
            a1 += c * bm[t * DD + c0 + 1];
            a2 += c * bm[t * DD + c0 + 2];
            a3 += c * bm[t * DD + c0 + 3];
        }
    }
    int d = deg[v], off = doff[v];
    const uint2* mr = (const uint2*)m;   // 8B granules, 32 per row
    int npair = d >> 1;
    for (int i = 0; i < npair; ++i) {
        uint2 w = mr[(size_t)(off + 2 * i + lh) * 32 + lc];
        a0 += b2f((unsigned short)(w.x & 0xFFFF));
        a1 += b2f((unsigned short)(w.x >> 16));
        a2 += b2f((unsigned short)(w.y & 0xFFFF));
        a3 += b2f((unsigned short)(w.y >> 16));
    }
    if ((d & 1) && lh == 0) {
        uint2 w = mr[(size_t)(off + d - 1) * 32 + lc];
        a0 += b2f((unsigned short)(w.x & 0xFFFF));
        a1 += b2f((unsigned short)(w.x >> 16));
        a2 += b2f((unsigned short)(w.y & 0xFFFF));
        a3 += b2f((unsigned short)(w.y >> 16));
    }
    a0 += __shfl_xor(a0, 32);
    a1 += __shfl_xor(a1, 32);
    a2 += __shfl_xor(a2, 32);
    a3 += __shfl_xor(a3, 32);
    if (lh == 0)
        ((uint2*)abf)[(size_t)v * 32 + lc] = make_uint2(pk(a0, a1), pk(a2, a3));
}

// ---------------- merged MFMA GRU: M=128 tile, 512 threads, all gates in-register ----------------

__launch_bounds__(512, 2)
__global__ void k_gru(const unsigned short* __restrict__ abf, float* __restrict__ h,
                      unsigned short* __restrict__ hbf,
                      const unsigned short* __restrict__ wihb, const unsigned short* __restrict__ whhb,
                      const float* __restrict__ bih, const float* __restrict__ bhh)
{
    __shared__ __align__(16) unsigned short Xs[128 * 128];
    __shared__ __align__(16) unsigned short Ws2[128 * 128];
    int m0 = blockIdx.x * 128;
    int tid = threadIdx.x;
    int lane = tid & 63, wv = tid >> 6;      // 8 waves
    int wm = (wv >> 1) * 32, wn = (wv & 1) * 64;
    int lr = lane & 15, lk = lane >> 4;
    f32x4 aR[2][4], aZ[2][4], aI[2][4], aH[2][4];
#pragma unroll
    for (int i = 0; i < 2; ++i)
#pragma unroll
        for (int j = 0; j < 4; ++j) {
            aR[i][j] = (f32x4){0.f, 0.f, 0.f, 0.f};
            aZ[i][j] = (f32x4){0.f, 0.f, 0.f, 0.f};
            aI[i][j] = (f32x4){0.f, 0.f, 0.f, 0.f};
            aH[i][j] = (f32x4){0.f, 0.f, 0.f, 0.f};
        }
    int rx = tid >> 2, qx = tid & 3;         // 128 rows x 4 quads (512 threads)
    unsigned bx = rx * 256 + qx * 64, swx = (rx & 7) << 4;
#pragma unroll
    for (int pass = 0; pass < 2; ++pass) {
        const unsigned short* X = pass ? hbf : abf;
        const unsigned short* W = pass ? whhb : wihb;
#pragma unroll
        for (int g = 0; g < 3; ++g) {
            __syncthreads();                 // WAR: prior reads of Xs/Ws2 done
            if (g == 0) {
                const uint4* sp = (const uint4*)(X + (size_t)(m0 + rx) * DD + qx * 32);
#pragma unroll
                for (int c = 0; c < 4; ++c)
                    *(uint4*)((char*)Xs + ((bx + c * 16) ^ swx)) = sp[c];
            }
            {
                const uint4* wp = (const uint4*)(W + (size_t)(g * DD + rx) * DD + qx * 32);
#pragma unroll
                for (int c = 0; c < 4; ++c)
                    *(uint4*)((char*)Ws2 + ((bx + c * 16) ^ swx)) = wp[c];
            }
            __syncthreads();
#pragma unroll
            for (int kc = 0; kc < 4; ++kc) {
                int cb = kc * 64 + lk * 16;
                bf16x8 af[2], bfv[4];
#pragma unroll
                for (int mi = 0; mi < 2; ++mi) {
                    int row = wm + mi * 16 + lr;
                    af[mi] = *(const bf16x8*)((const char*)Xs + ((row * 256 + cb) ^ ((row & 7) << 4)));
                }
#pragma unroll
                for (int ni = 0; ni < 4; ++ni) {
                    int row = wn + ni * 16 + lr;
                    bfv[ni] = *(const bf16x8*)((const char*)Ws2 + ((row * 256 + cb) ^ ((row & 7) << 4)));
                }
#pragma unroll
                for (int mi = 0; mi < 2; ++mi)
#pragma unroll
                    for (int ni = 0; ni < 4; ++ni) {
                        if (g == 0)
                            aR[mi][ni] = __builtin_amdgcn_mfma_f32_16x16x32_bf16(af[mi], bfv[ni], aR[mi][ni], 0, 0, 0);
                        else if (g == 1)
                            aZ[mi][ni] = __builtin_amdgcn_mfma_f32_16x16x32_bf16(af[mi], bfv[ni], aZ[mi][ni], 0, 0, 0);
                        else if (pass == 0)
                            aI[mi][ni] = __builtin_amdgcn_mfma_f32_16x16x32_bf16(af[mi], bfv[ni], aI[mi][ni], 0, 0, 0);
                        else
                            aH[mi][ni] = __builtin_amdgcn_mfma_f32_16x16x32_bf16(af[mi], bfv[ni], aH[mi][ni], 0, 0, 0);
                    }
            }
        }
    }
    // epilogue: full GRU combine in-register
#pragma unroll
    for (int ni = 0; ni < 4; ++ni) {
        int col = wn + ni * 16 + lr;
        float br_ = bih[col] + bhh[col];
        float bz_ = bih[DD + col] + bhh[DD + col];
        float bin_ = bih[2 * DD + col], bhn_ = bhh[2 * DD + col];
#pragma unroll
        for (int mi = 0; mi < 2; ++mi)
#pragma unroll
            for (int rg = 0; rg < 4; ++rg) {
                int v = m0 + wm + mi * 16 + lk * 4 + rg;
                float rr = sigmoidf_(aR[mi][ni][rg] + br_);
                float zz = sigmoidf_(aZ[mi][ni][rg] + bz_);
                float nn = tanhf(aI[mi][ni][rg] + bin_ + rr * (aH[mi][ni][rg] + bhn_));
                float hold = h[(size_t)v * DD + col];
                float hnew = (1.f - zz) * nn + zz * hold;
                h[(size_t)v * DD + col] = hnew;
                hbf[(size_t)v * DD + col] = (unsigned short)f2b(hnew);
            }
    }
}

// ---------------- MFMA conv1(k=3): U1[b][pos][co] = relu(conv+b), unpooled, bf16 ----------------

template <int CIN>
__launch_bounds__(256, 2)
__global__ void k_conv1m(const unsigned short* __restrict__ hbf, const float* __restrict__ h0,
                         const unsigned short* __restrict__ w1p, const float* __restrict__ bias,
                         unsigned short* __restrict__ U1)
{
    __shared__ __align__(16) unsigned short As[128 * 64];
    __shared__ __align__(16) unsigned short Ws[128 * 64];
    int p0 = blockIdx.x * 128, b = blockIdx.y, n0 = blockIdx.z * 128;
    int tid = threadIdx.x;
    int lane = tid & 63, wv = tid >> 6;
    int wm = (wv >> 1) * 64, wn = (wv & 1) * 64;
    int lr = lane & 15, lk = lane >> 4;
    f32x4 acc[4][4];
#pragma unroll
    for (int i = 0; i < 4; ++i)
#pragma unroll
        for (int j = 0; j < 4; ++j) acc[i][j] = (f32x4){0.f, 0.f, 0.f, 0.f};

    int r = tid >> 1, halfc = tid & 1;
    unsigned boff = r * 128 + halfc * 64;
    unsigned sw = (r & 7) << 4;
#pragma unroll
    for (int k = 0; k < 3; ++k) {
        for (int c0 = 0; c0 < CIN; c0 += 64) {
            __syncthreads();
            {
                int row = p0 + k + r; if (row > NNODE - 1) row = NNODE - 1;
                int ci = c0 + halfc * 32;
                if (CIN == 128 || ci < 128) {
                    const uint4* sp = (const uint4*)(hbf + ((size_t)(b * NNODE + row)) * DD + ci);
#pragma unroll
                    for (int c = 0; c < 4; ++c)
                        *(uint4*)((char*)As + ((boff + c * 16) ^ sw)) = sp[c];
                } else {
                    const float4* sp = (const float4*)(h0 + ((size_t)(b * NNODE + row)) * DD + (ci - 128));
#pragma unroll
                    for (int c = 0; c < 4; ++c) {
                        float4 v0 = sp[2 * c], v1 = sp[2 * c + 1];
                        *(uint4*)((char*)As + ((boff + c * 16) ^ sw)) =
                            make_uint4(pk(v0.x, v0.y), pk(v0.z, v0.w), pk(v1.x, v1.y), pk(v1.z, v1.w));
                    }
                }
            }
            {
                const uint4* wp = (const uint4*)(w1p + ((size_t)k * CIN + n0 + r) * CIN + c0 + halfc * 32);
#pragma unroll
                for (int c = 0; c < 4; ++c)
                    *(uint4*)((char*)Ws + ((boff + c * 16) ^ sw)) = wp[c];
            }
            __syncthreads();
#pragma unroll
            for (int kc = 0; kc < 2; ++kc) {
                int cb = kc * 64 + lk * 16;
                bf16x8 af[4], bfv[4];
#pragma unroll
                for (int mi = 0; mi < 4; ++mi) {
                    int row = wm + mi * 16 + lr;
                    af[mi] = *(const bf16x8*)((const char*)As + ((row * 128 + cb) ^ ((row & 7) << 4)));
                }
#pragma unroll
                for (int ni = 0; ni < 4; ++ni) {
                    int row = wn + ni * 16 + lr;
                    bfv[ni] = *(const bf16x8*)((const char*)Ws + ((row * 128 + cb) ^ ((row & 7) << 4)));
                }
#pragma unroll
                for (int mi = 0; mi < 4; ++mi)
#pragma unroll
                    for (int ni = 0; ni < 4; ++ni)
                        acc[mi][ni] = __builtin_amdgcn_mfma_f32_16x16x32_bf16(af[mi], bfv[ni], acc[mi][ni], 0, 0, 0);
            }
        }
    }
#pragma unroll
    for (int ni = 0; ni < 4; ++ni) {
        int co = n0 + wn + ni * 16 + lr;
        float bs = bias[co];
#pragma unroll
        for (int mi = 0; mi < 4; ++mi)
#pragma unroll
            for (int rg = 0; rg < 4; ++rg) {
                int pos = p0 + wm + mi * 16 + lk * 4 + rg;
                if (pos < NNODE - 2) {
                    float v = fmaxf(0.f, acc[mi][ni][rg] + bs);
                    U1[((size_t)b * NNODE + pos) * CIN + co] = (unsigned short)f2b(v);
                }
            }
    }
}

// ---------------- MFMA conv2(k=1): A = pool3(U1) on the fly; epilogue pool2 ----------------

template <int CIN>
__launch_bounds__(256, 2)
__global__ void k_conv2m(const unsigned short* __restrict__ U1, const unsigned short* __restrict__ w2b,
                         const float* __restrict__ bias, float* __restrict__ Q)
{
    __shared__ __align__(16) unsigned short As[128 * 64];
    __shared__ __align__(16) unsigned short Ws[128 * 64];
    int m0 = blockIdx.x * 128, b = blockIdx.y, n0 = blockIdx.z * 128;
    int tid = threadIdx.x;
    int lane = tid & 63, wv = tid >> 6;
    int wm = (wv >> 1) * 64, wn = (wv & 1) * 64;
    int lr = lane & 15, lk = lane >> 4;
    f32x4 acc[4][4];
#pragma unroll
    for (int i = 0; i < 4; ++i)
#pragma unroll
        for (int j = 0; j < 4; ++j) acc[i][j] = (f32x4){0.f, 0.f, 0.f, 0.f};

    int r = tid >> 1, halfc = tid & 1;
    unsigned boff = r * 128 + halfc * 64;
    unsigned sw = (r & 7) << 4;
    for (int c0 = 0; c0 < CIN; c0 += 64) {
        __syncthreads();
        {
            int pr = 2 * (m0 + r);
            int r0 = pr, r1 = pr + 1, r2v = pr + 2;
            if (r2v > NNODE - 1) r2v = NNODE - 1;
            if (r1 > NNODE - 1) r1 = NNODE - 1;
            int ci = c0 + halfc * 32;
            const unsigned short* bp = U1 + (size_t)b * NNODE * CIN + ci;
            const uint4* p0q = (const uint4*)(bp + (size_t)r0 * CIN);
            const uint4* p1q = (const uint4*)(bp + (size_t)r1 * CIN);
            const uint4* p2q = (const uint4*)(bp + (size_t)r2v * CIN);
#pragma unroll
            for (int c = 0; c < 4; ++c) {
                uint4 mm = bmax4(bmax4(p0q[c], p1q[c]), p2q[c]);
                *(uint4*)((char*)As + ((boff + c * 16) ^ sw)) = mm;
            }
        }
        {
            const uint4* wp = (const uint4*)(w2b + (size_t)(n0 + r) * CIN + c0 + halfc * 32);
#pragma unroll
            for (int c = 0; c < 4; ++c)
                *(uint4*)((char*)Ws + ((boff + c * 16) ^ sw)) = wp[c];
        }
        __syncthreads();
#pragma unroll
        for (int kc = 0; kc < 2; ++kc) {
            int cb = kc * 64 + lk * 16;
            bf16x8 af[4], bfv[4];
#pragma unroll
            for (int mi = 0; mi < 4; ++mi) {
                int row = wm + mi * 16 + lr;
                af[mi] = *(const bf16x8*)((const char*)As + ((row * 128 + cb) ^ ((row & 7) << 4)));
            }
#pragma unroll
            for (int ni = 0; ni < 4; ++ni) {
                int row = wn + ni * 16 + lr;
                bfv[ni] = *(const bf16x8*)((const char*)Ws + ((row * 128 + cb) ^ ((row & 7) << 4)));
            }
#pragma unroll
            for (int mi = 0; mi < 4; ++mi)
#pragma unroll
                for (int ni = 0; ni < 4; ++ni)
                    acc[mi][ni] = __builtin_amdgcn_mfma_f32_16x16x32_bf16(af[mi], bfv[ni], acc[mi][ni], 0, 0, 0);
        }
    }
#pragma unroll
    for (int ni = 0; ni < 4; ++ni) {
        int co = n0 + wn + ni * 16 + lr;
        float bs = bias[co];
#pragma unroll
        for (int mi = 0; mi < 4; ++mi) {
            int l0 = m0 + wm + mi * 16 + lk * 4;
            float v0 = fmaxf(0.f, acc[mi][ni][0] + bs);
            float v1 = fmaxf(0.f, acc[mi][ni][1] + bs);
            float v2 = fmaxf(0.f, acc[mi][ni][2] + bs);
            float v3 = fmaxf(0.f, acc[mi][ni][3] + bs);
            int jq = l0 >> 1;
            if (jq < 255)     Q[((size_t)b * 255 + jq) * CIN + co]     = fmaxf(v0, v1);
            if (jq + 1 < 255) Q[((size_t)b * 255 + jq + 1) * CIN + co] = fmaxf(v2, v3);
        }
    }
}

// ---------------- final reduction ----------------

__launch_bounds__(256)
__global__ void k_final(const float* __restrict__ QY, const float* __restrict__ QZ,
                        const float* __restrict__ wy, const float* __restrict__ by,
                        const float* __restrict__ wz, const float* __restrict__ bz,
                        float* __restrict__ out)
{
    int b = blockIdx.x, tid = threadIdx.x;
    float p = 0.f;
    if (tid < 255) {
        const float* qy = QY + ((size_t)(b * 255 + tid)) * 128;
        const float* qz = QZ + ((size_t)(b * 255 + tid)) * 256;
        float dy = 0.f, dz = 0.f;
        for (int c = 0; c < 128; c += 4) {
            float4 q = ld4(qy + c), wv = ld4(wy + c);
            dy += q.x * wv.x + q.y * wv.y + q.z * wv.z + q.w * wv.w;
        }
        for (int c = 0; c < 256; c += 4) {
            float4 q = ld4(qz + c), wv = ld4(wz + c);
            dz += q.x * wv.x + q.y * wv.y + q.z * wv.z + q.w * wv.w;
        }
        p = (dy + by[0]) * (dz + bz[0]);
    }
    __shared__ float red[4];
    for (int off = 32; off > 0; off >>= 1) p += __shfl_down(p, off);
    if ((tid & 63) == 0) red[tid >> 6] = p;
    __syncthreads();
    if (tid == 0) {
        float s = red[0] + red[1] + red[2] + red[3];
        out[b] = 1.f / (1.f + expf(-s / 255.f));
    }
}

// ---------------- launch ----------------

extern "C" void kernel_launch(void* const* d_in, const int* in_sizes, int n_in,
                              void* d_out, int out_size, void* d_ws, size_t ws_size,
                              hipStream_t stream)
{
    const float* h_in = (const float*)d_in[0];
    const int* src = (const int*)d_in[1];
    const int* dst = (const int*)d_in[2];
    const int* et  = (const int*)d_in[3];
    const float* Wmsg = (const float*)d_in[4];
    const float* bmsg = (const float*)d_in[5];
    const float* wih = (const float*)d_in[6];
    const float* whh = (const float*)d_in[7];
    const float* bih = (const float*)d_in[8];
    const float* bhh = (const float*)d_in[9];
    const float* c1w = (const float*)d_in[10];
    const float* c1b = (const float*)d_in[11];
    const float* c2w = (const float*)d_in[12];
    const float* c2b = (const float*)d_in[13];
    const float* z1w = (const float*)d_in[14];
    const float* z1b = (const float*)d_in[15];
    const float* z2w = (const float*)d_in[16];
    const float* z2b = (const float*)d_in[17];
    const float* wy  = (const float*)d_in[18];
    const float* by  = (const float*)d_in[19];
    const float* wz  = (const float*)d_in[20];
    const float* bz  = (const float*)d_in[21];
    float* out = (float*)d_out;

    if (ws_size < WS_NEED) return;   // loud failure: output stays poisoned

    char* ws = (char*)d_ws;
    float* hcur = (float*)(ws + OFF_HCUR);
    unsigned short* hbf  = (unsigned short*)(ws + OFF_HBF);
    int*   cnt  = (int*)(ws + OFF_CNT);
    int*   deg  = (int*)(ws + OFF_DEG);
    int*   doff = (int*)(ws + OFF_DOFF);
    int*   dcur = (int*)(ws + OFF_DCUR);
    int*   dblk = (int*)(ws + OFF_DBLK);
    int*   hb   = (int*)(ws + OFF_HB);
    int*   ssrc = (int*)(ws + OFF_SSRC);
    int*   sdst = (int*)(ws + OFF_SDST);
    int*   sq   = (int*)(ws + OFF_SQ);
    unsigned short* wmb  = (unsigned short*)(ws + OFF_WMB);
    unsigned short* wihb = (unsigned short*)(ws + OFF_WIHB);
    unsigned short* whhb = (unsigned short*)(ws + OFF_WHHB);
    unsigned short* w1py = (unsigned short*)(ws + OFF_W1PY);
    unsigned short* w1pz = (unsigned short*)(ws + OFF_W1PZ);
    unsigned short* w2yb = (unsigned short*)(ws + OFF_W2YB);
    unsigned short* w2zb = (unsigned short*)(ws + OFF_W2ZB);
    unsigned short* abf  = (unsigned short*)(ws + OFF_ABF);
    unsigned short* mbuf = (unsigned short*)(ws + OFF_M);
    unsigned short* U1Y  = (unsigned short*)(ws + OFF_U1Y);
    unsigned short* U1Z  = (unsigned short*)(ws + OFF_U1Z);
    float* QY   = (float*)(ws + OFF_QY);
    float* QZ   = (float*)(ws + OFF_QZ);

    k_prep<<<PREP_BLOCKS, 256, 0, stream>>>(h_in, hcur, hbf, Wmsg, wmb, wih, wihb, whh, whhb,
                                            c2w, w2yb, z2w, w2zb, c1w, w1py, z1w, w1pz,
                                            cnt, hb, ssrc, sdst);

    k_hist<<<256, 256, 0, stream>>>(et, dst, hb, cnt);
    k_degA<<<128, 256, 0, stream>>>(cnt, deg, doff, dblk);
    k_scan2<<<1, 128, 0, stream>>>(hb, dblk);
    k_degB<<<128, 256, 0, stream>>>(doff, dcur, dblk);
    k_scatter<<<256, 256, 0, stream>>>(src, dst, et, hb, dcur, ssrc, sdst, sq);

    for (int s = 0; s < NSTEPS; ++s) {
        k_msg<<<NTILES_F, 256, 0, stream>>>(ssrc, sdst, sq, hb, hbf, wmb, mbuf);
        k_agg<<<BN / 4, 256, 0, stream>>>(mbuf, deg, doff, cnt, bmsg, abf);
        k_gru<<<BN / 128, 512, 0, stream>>>(abf, hcur, hbf, wihb, whhb, bih, bhh);
    }

    k_conv1m<128><<<dim3(8, 32, 1), 256, 0, stream>>>(hbf, h_in, w1py, c1b, U1Y);
    k_conv2m<128><<<dim3(4, 32, 1), 256, 0, stream>>>(U1Y, w2yb, c2b, QY);
    k_conv1m<256><<<dim3(8, 32, 2), 256, 0, stream>>>(hbf, h_in, w1pz, z1b, U1Z);
    k_conv2m<256><<<dim3(4, 32, 2), 256, 0, stream>>>(U1Z, w2zb, z2b, QZ);
    k_final<<<32, 256, 0, stream>>>(QY, QZ, wy, by, wz, bz, out);
}